// Round 2
// baseline (421.347 us; speedup 1.0000x reference)
//
#include <hip/hip_runtime.h>
#include <hip/hip_bf16.h>

#define B 4
#define H 480
#define W 640
#define HW (H*W)
#define BHW (B*H*W)
#define NKP 1024
#define THRESH 0.005f
#define CAP 16384
#define NCOL (B*NKP)
#define KTOT 704
#define RBAND 9

typedef __attribute__((ext_vector_type(8))) short s8v;
typedef __attribute__((ext_vector_type(4))) float f4v;

__device__ __forceinline__ short f2bf(float f) {
    __hip_bfloat16 h = __float2bfloat16(f);
    return *(short*)&h;
}

// ================= fused weights + bias + counter zero (Mw bf16) =================
__global__ void fuse_all(const float* __restrict__ merge_w, const float* __restrict__ merge_b,
                         const float* __restrict__ lin0_w, const float* __restrict__ lin0_b,
                         const float* __restrict__ lin1_w, const float* __restrict__ lin1_b,
                         const float* __restrict__ lin2_w, const float* __restrict__ lin2_b,
                         short* __restrict__ Mw, float* __restrict__ biasf, int* __restrict__ cnt) {
    if (blockIdx.x == 704) {
        int o = threadIdx.x;
        if (o < 4) cnt[o * 64] = 0;
        float acc = merge_b[o];
        for (int k = 0; k < 64; ++k)  acc += merge_w[o * KTOT + k] * lin2_b[k];
        for (int k = 0; k < 128; ++k) acc += merge_w[o * KTOT + 64 + k] * lin1_b[k];
        for (int k = 0; k < 256; ++k) acc += merge_w[o * KTOT + 448 + k] * lin0_b[k];
        biasf[o] = acc;
        return;
    }
    int e = blockIdx.x * 256 + threadIdx.x;
    int o = e / KTOT;
    int j = e - o * KTOT;
    float acc = 0.0f;
    if (j < 64) {
        for (int k = 0; k < 64; ++k) acc += merge_w[o * KTOT + k] * lin2_w[k * 64 + j];
    } else if (j < 192) {
        int jj = j - 64;
        for (int k = 0; k < 128; ++k) acc += merge_w[o * KTOT + 64 + k] * lin1_w[k * 128 + jj];
    } else if (j < 448) {
        acc = merge_w[o * KTOT + j];
    } else {
        int jj = j - 448;
        for (int k = 0; k < 256; ++k) acc += merge_w[o * KTOT + 448 + k] * lin0_w[k * 256 + jj];
    }
    Mw[o * KTOT + j] = f2bf(acc);
}

// ================= NMS stage 1: mask0 = (S == pool9(S)) =================
__global__ __launch_bounds__(256) void nms1(const float* __restrict__ scores,
                                            float* __restrict__ mask) {
    __shared__ float tile[40][40];
    __shared__ float hm[40][32];
    int bz = blockIdx.z;
    int x0 = blockIdx.x * 32, y0 = blockIdx.y * 32;
    const float* sp = scores + bz * HW;
    for (int t = threadIdx.x; t < 1600; t += 256) {
        int ly = t / 40, lx = t - ly * 40;
        int gy = y0 - 4 + ly, gx = x0 - 4 + lx;
        tile[ly][lx] = (gy >= 0 && gy < H && gx >= 0 && gx < W) ? sp[gy * W + gx] : -INFINITY;
    }
    __syncthreads();
    for (int t = threadIdx.x; t < 1280; t += 256) {
        int ly = t >> 5, lx = t & 31;
        float m = tile[ly][lx];
        #pragma unroll
        for (int d = 1; d < 9; ++d) m = fmaxf(m, tile[ly][lx + d]);
        hm[ly][lx] = m;
    }
    __syncthreads();
    for (int t = threadIdx.x; t < 1024; t += 256) {
        int ly = t >> 5, lx = t & 31;
        float m = hm[ly][lx];
        #pragma unroll
        for (int d = 1; d < 9; ++d) m = fmaxf(m, hm[ly + d][lx]);
        float s = tile[ly + 4][lx + 4];
        mask[bz * HW + (y0 + ly) * W + x0 + lx] = (s == m) ? 1.0f : 0.0f;
    }
}

// ===== NMS stage 2: remaining 4 pools (2 NMS iterations) fused in LDS + compaction =====
__global__ __launch_bounds__(256) void nms2_compact(const float* __restrict__ scores,
                                                    const float* __restrict__ mask0,
                                                    unsigned long long* __restrict__ cand,
                                                    int* __restrict__ cnt) {
    __shared__ float Sm[56 * 56];   // S on local [4,60)
    __shared__ float Mm[64 * 64];   // mask on local [0,64)
    __shared__ float Zm[56 * 56];   // Z on local [4,60)
    __shared__ float Tm[64 * 56];   // h-pass temp
    __shared__ int lcnt, gbase;
    int bz = blockIdx.z;
    int x0 = blockIdx.x * 32, y0 = blockIdx.y * 32;
    const float* sp = scores + bz * HW;
    const float* mp = mask0 + bz * HW;
    if (threadIdx.x == 0) lcnt = 0;
    for (int t = threadIdx.x; t < 4096; t += 256) {
        int ly = t >> 6, lx = t & 63;
        int gy = y0 - 16 + ly, gx = x0 - 16 + lx;
        Mm[t] = (gy >= 0 && gy < H && gx >= 0 && gx < W) ? mp[gy * W + gx] : 0.0f;
    }
    for (int t = threadIdx.x; t < 3136; t += 256) {
        int i = t / 56, j = t - i * 56;
        int gy = y0 - 12 + i, gx = x0 - 12 + j;
        Sm[t] = (gy >= 0 && gy < H && gx >= 0 && gx < W) ? sp[gy * W + gx] : -1.0f;
    }
    __syncthreads();
    for (int t = threadIdx.x; t < 3584; t += 256) {
        int i = t / 56, c = t - i * 56;
        float m = Mm[i * 64 + c];
        #pragma unroll
        for (int d = 1; d < 9; ++d) m = fmaxf(m, Mm[i * 64 + c + d]);
        Tm[i * 56 + c] = m;
    }
    __syncthreads();
    for (int t = threadIdx.x; t < 3136; t += 256) {
        int i = t / 56, c = t - i * 56;
        float m = Tm[i * 56 + c];
        #pragma unroll
        for (int d = 1; d < 9; ++d) m = fmaxf(m, Tm[(i + d) * 56 + c]);
        Zm[t] = (m > 0.0f) ? -1.0f : Sm[t];
    }
    __syncthreads();
    for (int t = threadIdx.x; t < 2688; t += 256) {
        int i = t / 48, c = t - i * 48;
        float m = Zm[i * 56 + c];
        #pragma unroll
        for (int d = 1; d < 9; ++d) m = fmaxf(m, Zm[i * 56 + c + d]);
        Tm[i * 56 + c] = m;
    }
    __syncthreads();
    for (int t = threadIdx.x; t < 2304; t += 256) {
        int r = t / 48, c = t - r * 48;
        float m = Tm[r * 56 + c];
        #pragma unroll
        for (int d = 1; d < 9; ++d) m = fmaxf(m, Tm[(r + d) * 56 + c]);
        float Zc = Zm[(r + 4) * 56 + c + 4];
        int mi = (r + 8) * 64 + c + 8;
        bool nm = (Zc == m) && (Zc >= 0.0f);
        Mm[mi] = (Mm[mi] != 0.0f || nm) ? 1.0f : 0.0f;
    }
    __syncthreads();
    for (int t = threadIdx.x; t < 1920; t += 256) {
        int r = t / 40, c = t - r * 40;
        float m = Mm[(r + 8) * 64 + c + 8];
        #pragma unroll
        for (int d = 1; d < 9; ++d) m = fmaxf(m, Mm[(r + 8) * 64 + c + 8 + d]);
        Tm[r * 56 + c] = m;
    }
    __syncthreads();
    for (int t = threadIdx.x; t < 1600; t += 256) {
        int r = t / 40, c = t - r * 40;
        float m = Tm[r * 56 + c];
        #pragma unroll
        for (int d = 1; d < 9; ++d) m = fmaxf(m, Tm[(r + d) * 56 + c]);
        int zi = (r + 8) * 56 + c + 8;
        Zm[zi] = (m > 0.0f) ? -1.0f : Sm[zi];
    }
    __syncthreads();
    for (int t = threadIdx.x; t < 1280; t += 256) {
        int r = t / 32, c = t & 31;
        float m = Zm[(r + 8) * 56 + c + 8];
        #pragma unroll
        for (int d = 1; d < 9; ++d) m = fmaxf(m, Zm[(r + 8) * 56 + c + 8 + d]);
        Tm[r * 56 + c] = m;
    }
    __syncthreads();
    unsigned long long keys[4];
    int nl = 0;
    #pragma unroll
    for (int q = 0; q < 4; ++q) {
        int t = threadIdx.x + q * 256;
        int r3 = t >> 5, c = t & 31;
        float m = Tm[r3 * 56 + c];
        #pragma unroll
        for (int d = 1; d < 9; ++d) m = fmaxf(m, Tm[(r3 + d) * 56 + c]);
        float Zc = Zm[(r3 + 12) * 56 + c + 12];
        bool fin = (Mm[(r3 + 16) * 64 + c + 16] != 0.0f) || ((Zc == m) && (Zc >= 0.0f));
        int gy = y0 + r3, gx = x0 + c;
        float sc = Sm[(r3 + 12) * 56 + c + 12];
        if (fin && gy >= 4 && gy < H - 4 && gx >= 4 && gx < W - 4 && sc > THRESH) {
            unsigned r = (unsigned)(gy * W + gx);
            unsigned bits = __float_as_uint(sc) | 0x80000000u;
            keys[nl++] = ((unsigned long long)bits << 32) |
                         (unsigned long long)(0xFFFFFFFFu - r);
        }
    }
    int lpos = 0;
    if (nl) lpos = atomicAdd(&lcnt, nl);
    __syncthreads();
    if (threadIdx.x == 0) gbase = (lcnt > 0) ? atomicAdd(&cnt[bz * 64], lcnt) : 0;
    __syncthreads();
    for (int j = 0; j < nl; ++j) {
        int p = gbase + lpos + j;
        if (p < CAP) cand[(size_t)bz * CAP + p] = keys[j];
    }
}

// ===== topk: TWO-LEVEL histogram select (22-bit prefix) + bitonic; emits spatial perm =====
__global__ __launch_bounds__(1024) void topk(const unsigned long long* __restrict__ cand,
                                             const int* __restrict__ cnt,
                                             float* __restrict__ out, int* __restrict__ fidx,
                                             int* __restrict__ perm) {
    __shared__ int hist[2048];
    __shared__ unsigned long long buf[4096];
    __shared__ int scnt, spiv1, spiv2, sabove;
    int b = blockIdx.x, tid = threadIdx.x;
    int m = cnt[b * 64]; if (m > CAP) m = CAP;
    const unsigned long long* cb = cand + (size_t)b * CAP;
    int target = (m < 1024) ? m : 1024;

    hist[tid] = 0; hist[tid + 1024] = 0;
    if (tid == 0) { scnt = 0; spiv1 = 2048; spiv2 = 0; sabove = 0; }
    __syncthreads();
    for (int i = tid; i < m; i += 1024)
        atomicAdd(&hist[(int)(cb[i] >> 53) & 0x7FF], 1);
    __syncthreads();
    for (int d = 1; d < 2048; d <<= 1) {
        int v0 = hist[tid] + ((tid + d < 2048) ? hist[tid + d] : 0);
        int v1 = hist[tid + 1024] + ((tid + 1024 + d < 2048) ? hist[tid + 1024 + d] : 0);
        __syncthreads();
        hist[tid] = v0; hist[tid + 1024] = v1;
        __syncthreads();
    }
    if (target > 0) {
        for (int t = tid; t < 2048; t += 1024) {
            int c = hist[t];
            int cn = (t < 2047) ? hist[t + 1] : 0;
            if (c >= target && cn < target) { spiv1 = t; sabove = cn; }
        }
    }
    __syncthreads();
    int piv1 = spiv1;
    int target2 = target - sabove;
    hist[tid] = 0; hist[tid + 1024] = 0;
    __syncthreads();
    for (int i = tid; i < m; i += 1024) {
        unsigned long long k = cb[i];
        if (((int)(k >> 53) & 0x7FF) == piv1)
            atomicAdd(&hist[(int)(k >> 42) & 0x7FF], 1);
    }
    __syncthreads();
    for (int d = 1; d < 2048; d <<= 1) {
        int v0 = hist[tid] + ((tid + d < 2048) ? hist[tid + d] : 0);
        int v1 = hist[tid + 1024] + ((tid + 1024 + d < 2048) ? hist[tid + 1024 + d] : 0);
        __syncthreads();
        hist[tid] = v0; hist[tid + 1024] = v1;
        __syncthreads();
    }
    if (target > 0) {
        for (int t = tid; t < 2048; t += 1024) {
            int c = hist[t];
            int cn = (t < 2047) ? hist[t + 1] : 0;
            if (c >= target2 && cn < target2) spiv2 = t;
        }
    }
    __syncthreads();
    int piv2 = spiv2;
    for (int i = tid; i < m; i += 1024) {
        unsigned long long k = cb[i];
        int b1 = (int)(k >> 53) & 0x7FF;
        bool sel = (target > 0) &&
                   (b1 > piv1 || (b1 == piv1 && (((int)(k >> 42) & 0x7FF) >= piv2)));
        if (sel) {
            int p = atomicAdd(&scnt, 1);
            if (p < 4096) buf[p] = k;
        }
    }
    __syncthreads();
    int sc_ = scnt; if (sc_ > 4096) sc_ = 4096;
    int ns = 1024; while (ns < sc_) ns <<= 1;
    for (int t = tid; t < ns; t += 1024) if (t >= sc_) buf[t] = 0ULL;
    __syncthreads();
    for (int k = 2; k <= ns; k <<= 1)
        for (int j = k >> 1; j > 0; j >>= 1) {
            __syncthreads();
            for (int t = tid; t < ns; t += 1024) {
                int ixj = t ^ j;
                if (ixj > t) {
                    unsigned long long a = buf[t], bb = buf[ixj];
                    if (((t & k) == 0) ? (a < bb) : (a > bb)) { buf[t] = bb; buf[ixj] = a; }
                }
            }
        }
    __syncthreads();
    unsigned long long key = buf[tid];
    float kx, ky, sc;
    unsigned idx;
    if (key != 0ULL) {
        unsigned ord = (unsigned)(key >> 32);
        sc = __uint_as_float(ord ^ 0x80000000u);
        idx = 0xFFFFFFFFu - (unsigned)(key & 0xFFFFFFFFu);
        kx = (float)(idx % W);
        ky = (float)(idx / W);
    } else {
        sc = -1.0f; idx = 0; kx = 0.0f; ky = 0.0f;
    }
    int bn = b * NKP + tid;
    out[bn * 2 + 0] = kx;
    out[bn * 2 + 1] = ky;
    out[B * NKP * 2 + bn] = sc;
    fidx[bn] = (int)idx;
    __syncthreads();
    unsigned* b32 = (unsigned*)buf;
    b32[tid] = (idx << 10) | (unsigned)tid;
    for (int k = 2; k <= 1024; k <<= 1)
        for (int j = k >> 1; j > 0; j >>= 1) {
            __syncthreads();
            int ixj = tid ^ j;
            if (ixj > tid) {
                unsigned a = b32[tid], bb = b32[ixj];
                if (((tid & k) == 0) ? (a > bb) : (a < bb)) { b32[tid] = bb; b32[ixj] = a; }
            }
        }
    __syncthreads();
    perm[b * NKP + tid] = (int)(b32[tid] & 1023u);
}

// ===== sample_stage: LDS row-band staging (coalesced) + in-LDS bilinear gather =====
// grid.x = 56 channel-chunks (16xd1/4ch, 16xd2/8ch, 16xcDa/16ch, 8xd4/32ch)
// grid.y = 16 kp-chunks of 64 (spatially sorted via perm), grid.z = batch
__global__ __launch_bounds__(256) void sample_stage(const float* __restrict__ d1,
                                                    const float* __restrict__ d2,
                                                    const float* __restrict__ cDa,
                                                    const float* __restrict__ d4,
                                                    const int* __restrict__ fidx,
                                                    const int* __restrict__ perm,
                                                    float* __restrict__ X) {
    __shared__ __align__(16) float L[12928];   // max: d4 32ch * (10*40+4)
    __shared__ int   s_col[64];
    __shared__ short s_x0[64], s_x1[64], s_y0[64], s_y1[64];
    __shared__ float s_w[64][4];
    __shared__ int s_mn, s_mx;

    int cx = blockIdx.x, q = blockIdx.y, b = blockIdx.z;
    int tid = threadIdx.x;

    const float* map; int Cs, l2c, cb, Cc, h, w, s, seg;
    if (cx < 16)      { map = d1;  Cs = 4;  l2c = 2; cb = cx << 2;        Cc = 64;  h = 240; w = 320; s = 2;  seg = 0; }
    else if (cx < 32) { map = d2;  Cs = 8;  l2c = 3; cb = (cx - 16) << 3; Cc = 128; h = 120; w = 160; s = 4;  seg = 64; }
    else if (cx < 48) { map = cDa; Cs = 16; l2c = 4; cb = (cx - 32) << 4; Cc = 256; h = 60;  w = 80;  s = 8;  seg = 192; }
    else              { map = d4;  Cs = 32; l2c = 5; cb = (cx - 48) << 5; Cc = 256; h = 30;  w = 40;  s = 16; seg = 448; }

    if (tid < 64) {
        int col = (b << 10) | perm[(b << 10) + (q << 6) + tid];
        int idx = fidx[col];
        float kx = (float)(idx % W);
        float ky = (float)(idx / W);
        float kxs = kx - (float)s * 0.5f + 0.5f;
        float kys = ky - (float)s * 0.5f + 0.5f;
        float gx = kxs / (float)(w * s - 1) * 2.0f - 1.0f;
        float gy = kys / (float)(h * s - 1) * 2.0f - 1.0f;
        float x = (gx + 1.0f) * 0.5f * (float)(w - 1);
        float y = (gy + 1.0f) * 0.5f * (float)(h - 1);
        float x0f = floorf(x), y0f = floorf(y);
        int x0 = (int)x0f, y0 = (int)y0f;
        float wx1 = x - x0f, wy1 = y - y0f;
        float wx0 = 1.0f - wx1, wy0 = 1.0f - wy1;
        bool vx0 = (x0 >= 0) && (x0 < w);
        bool vx1 = (x0 + 1 >= 0) && (x0 + 1 < w);
        bool vy0 = (y0 >= 0) && (y0 < h);
        bool vy1 = (y0 + 1 >= 0) && (y0 + 1 < h);
        int xc0 = min(max(x0, 0), w - 1), xc1 = min(max(x0 + 1, 0), w - 1);
        int yc0 = min(max(y0, 0), h - 1), yc1 = min(max(y0 + 1, 0), h - 1);
        s_col[tid] = col;
        s_x0[tid] = (short)xc0; s_x1[tid] = (short)xc1;
        s_y0[tid] = (short)yc0; s_y1[tid] = (short)yc1;
        s_w[tid][0] = (vx0 && vy0) ? wx0 * wy0 : 0.0f;
        s_w[tid][1] = (vx1 && vy0) ? wx1 * wy0 : 0.0f;
        s_w[tid][2] = (vx0 && vy1) ? wx0 * wy1 : 0.0f;
        s_w[tid][3] = (vx1 && vy1) ? wx1 * wy1 : 0.0f;
        int mn = yc0, mx = yc0;
        #pragma unroll
        for (int off = 32; off > 0; off >>= 1) {
            mn = min(mn, __shfl_xor(mn, off, 64));
            mx = max(mx, __shfl_xor(mx, off, 64));
        }
        if (tid == 0) { s_mn = mn; s_mx = mx; }
    }
    __syncthreads();
    int mn = s_mn, mx = s_mx;
    int pitch = (RBAND + 1) * w + 4;
    const float* pb = map + (size_t)(b * Cc + cb) * (h * w);
    int nouts = 64 << l2c;

    for (int r0 = mn; r0 <= mx; r0 += RBAND) {
        int rN = min(RBAND + 1, h - r0);
        rN = min(rN, mx + 2 - r0);
        int nf4 = (rN * w) >> 2;
        for (int i = 0; i < Cs; ++i) {
            const float4* src = (const float4*)(pb + (size_t)i * (h * w) + r0 * w);
            float* dst = &L[i * pitch];
            for (int e = tid; e < nf4; e += 256) {
                float4 v = src[e];
                *(float4*)&dst[e << 2] = v;
            }
        }
        __syncthreads();
        for (int o = tid; o < nouts; o += 256) {
            int i = o & (Cs - 1), kp = o >> l2c;
            int y0l = s_y0[kp];
            if (y0l >= r0 && y0l < r0 + RBAND) {
                int y1l = s_y1[kp];
                int xa = s_x0[kp], xb = s_x1[kp];
                const float* Lp = &L[i * pitch - r0 * w];
                float v = Lp[y0l * w + xa] * s_w[kp][0]
                        + Lp[y0l * w + xb] * s_w[kp][1]
                        + Lp[y1l * w + xa] * s_w[kp][2]
                        + Lp[y1l * w + xb] * s_w[kp][3];
                X[(size_t)s_col[kp] * KTOT + seg + cb + i] = v;
            }
        }
        __syncthreads();
    }
}

// ===== rownorm: per-keypoint inverse L2 norm over the 704-dim descriptor =====
__global__ __launch_bounds__(256) void rownorm(const float* __restrict__ X,
                                               float* __restrict__ nv) {
    int wid = threadIdx.x >> 6, lane = threadIdx.x & 63;
    int col = blockIdx.x * 4 + wid;
    const float4* p = (const float4*)(X + (size_t)col * KTOT);
    float acc = 0.0f;
    for (int e = lane; e < 176; e += 64) {
        float4 v = p[e];
        acc += v.x * v.x + v.y * v.y + v.z * v.z + v.w * v.w;
    }
    #pragma unroll
    for (int off = 32; off > 0; off >>= 1) acc += __shfl_xor(acc, off, 64);
    if (lane == 0) nv[col] = 1.0f / fmaxf(sqrtf(acc), 1e-12f);
}

// ===== GEMM (bf16 MFMA): out[256,4096] = Mw[256,704] * (X*nv)^T + bias =====
__global__ __launch_bounds__(256) void gemm_mfma(const short* __restrict__ Mw,
                                                 const float* __restrict__ X,
                                                 const float* __restrict__ nv,
                                                 const float* __restrict__ biasf,
                                                 float* __restrict__ out) {
    __shared__ short As[64 * 72];
    __shared__ short Bs[64 * 72];
    int tid = threadIdx.x;
    int lane = tid & 63, w = tid >> 6;
    int r = lane & 15, quad = lane >> 4;
    int rowBase = blockIdx.y * 64, colBase = blockIdx.x * 64;
    int sm = tid >> 2, skq = (tid & 3) << 4;

    const short* pa = Mw + (size_t)(rowBase + sm) * KTOT + skq;
    const float* pbx = X + (size_t)(colBase + sm) * KTOT + skq;
    float nvv = nv[colBase + sm];
    s8v a0 = *(const s8v*)(pa), a1 = *(const s8v*)(pa + 8);
    float4 b0 = *(const float4*)(pbx + 0), b1 = *(const float4*)(pbx + 4);
    float4 b2 = *(const float4*)(pbx + 8), b3 = *(const float4*)(pbx + 12);

    f4v acc[4];
    #pragma unroll
    for (int t = 0; t < 4; ++t) acc[t] = (f4v)0.0f;

    for (int kt = 0; kt < 11; ++kt) {
        __syncthreads();
        *(s8v*)&As[sm * 72 + skq + 0] = a0;
        *(s8v*)&As[sm * 72 + skq + 8] = a1;
        {
            s8v u0, u1;
            u0[0] = f2bf(b0.x * nvv); u0[1] = f2bf(b0.y * nvv);
            u0[2] = f2bf(b0.z * nvv); u0[3] = f2bf(b0.w * nvv);
            u0[4] = f2bf(b1.x * nvv); u0[5] = f2bf(b1.y * nvv);
            u0[6] = f2bf(b1.z * nvv); u0[7] = f2bf(b1.w * nvv);
            u1[0] = f2bf(b2.x * nvv); u1[1] = f2bf(b2.y * nvv);
            u1[2] = f2bf(b2.z * nvv); u1[3] = f2bf(b2.w * nvv);
            u1[4] = f2bf(b3.x * nvv); u1[5] = f2bf(b3.y * nvv);
            u1[6] = f2bf(b3.z * nvv); u1[7] = f2bf(b3.w * nvv);
            *(s8v*)&Bs[sm * 72 + skq + 0] = u0;
            *(s8v*)&Bs[sm * 72 + skq + 8] = u1;
        }
        __syncthreads();
        if (kt < 10) {
            pa += 64; pbx += 64;
            a0 = *(const s8v*)(pa); a1 = *(const s8v*)(pa + 8);
            b0 = *(const float4*)(pbx + 0); b1 = *(const float4*)(pbx + 4);
            b2 = *(const float4*)(pbx + 8); b3 = *(const float4*)(pbx + 12);
        }
        #pragma unroll
        for (int kk = 0; kk < 2; ++kk) {
            int aoff = (w * 16 + r) * 72 + kk * 32 + quad * 8;
            s8v af = *(const s8v*)&As[aoff];
            #pragma unroll
            for (int t = 0; t < 4; ++t) {
                int boff = (t * 16 + r) * 72 + kk * 32 + quad * 8;
                s8v bf = *(const s8v*)&Bs[boff];
                acc[t] = __builtin_amdgcn_mfma_f32_16x16x32_bf16(af, bf, acc[t], 0, 0, 0);
            }
        }
    }
    #pragma unroll
    for (int t = 0; t < 4; ++t) {
        int colg = colBase + t * 16 + r;
        size_t obase = (size_t)(colg >> 10) * (256 * NKP) + (size_t)(colg & 1023);
        #pragma unroll
        for (int reg = 0; reg < 4; ++reg) {
            int row = rowBase + w * 16 + quad * 4 + reg;
            out[obase + (size_t)row * NKP] = acc[t][reg] + biasf[row];
        }
    }
}

// ================= launch =================
extern "C" void kernel_launch(void* const* d_in, const int* in_sizes, int n_in,
                              void* d_out, int out_size, void* d_ws, size_t ws_size,
                              hipStream_t stream) {
    const float* scores  = (const float*)d_in[0];
    const float* d1      = (const float*)d_in[1];
    const float* d2      = (const float*)d_in[2];
    const float* cDa     = (const float*)d_in[3];
    const float* d4      = (const float*)d_in[4];
    const float* lin0_w  = (const float*)d_in[5];
    const float* lin0_b  = (const float*)d_in[6];
    const float* lin1_w  = (const float*)d_in[7];
    const float* lin1_b  = (const float*)d_in[8];
    const float* lin2_w  = (const float*)d_in[9];
    const float* lin2_b  = (const float*)d_in[10];
    const float* merge_w = (const float*)d_in[11];
    const float* merge_b = (const float*)d_in[12];
    float* out = (float*)d_out;

    char* ws = (char*)d_ws;
    float* MASK = (float*)ws;                                          // 4.9 MB (nms phase)
    float* Xf32 = (float*)ws;                                          // 11.54 MB (post-topk, aliases MASK)
    unsigned long long* cand  = (unsigned long long*)(ws + 14745600);  // 524,288 B
    int* cnt                  = (int*)(ws + 15269888);                 // 1,024 B
    float* normv              = (float*)(ws + 15271936);               // 16,384 B
    int* fidx                 = (int*)(ws + 15401984);                 // 16,384 B
    short* Mw                 = (short*)(ws + 15418368);               // 360,448 B (bf16)
    float* biasf              = (float*)(ws + 16139264);               // 1,024 B
    int* perm                 = (int*)(ws + 16140288);                 // 16,384 B

    dim3 tgrid(W / 32, H / 32, B);   // (20,15,4)

    fuse_all<<<705, 256, 0, stream>>>(merge_w, merge_b, lin0_w, lin0_b, lin1_w, lin1_b,
                                      lin2_w, lin2_b, Mw, biasf, cnt);
    nms1<<<tgrid, 256, 0, stream>>>(scores, MASK);
    nms2_compact<<<tgrid, 256, 0, stream>>>(scores, MASK, cand, cnt);
    topk<<<B, 1024, 0, stream>>>(cand, cnt, out, fidx, perm);
    sample_stage<<<dim3(56, 16, 4), 256, 0, stream>>>(d1, d2, cDa, d4, fidx, perm, Xf32);
    rownorm<<<1024, 256, 0, stream>>>(Xf32, normv);
    gemm_mfma<<<dim3(NCOL / 64, 256 / 64), 256, 0, stream>>>(Mw, Xf32, normv, biasf,
                                                             out + B * NKP * 3);
}

// Round 3
// 381.477 us; speedup vs baseline: 1.1045x; 1.1045x over previous
//
#include <hip/hip_runtime.h>
#include <hip/hip_bf16.h>

#define B 4
#define H 480
#define W 640
#define HW (H*W)
#define BHW (B*H*W)
#define NKP 1024
#define THRESH 0.005f
#define CAP 16384
#define NCOL (B*NKP)
#define KTOT 704
#define KPB 4

typedef __attribute__((ext_vector_type(8))) short s8v;
typedef __attribute__((ext_vector_type(4))) float f4v;
typedef struct { float x, y; } __attribute__((aligned(4))) f2u;   // 4B-aligned pair load

__device__ __forceinline__ short f2bf(float f) {
    __hip_bfloat16 h = __float2bfloat16(f);
    return *(short*)&h;
}

// ================= fused weights + bias + counter zero (Mw bf16) =================
__global__ void fuse_all(const float* __restrict__ merge_w, const float* __restrict__ merge_b,
                         const float* __restrict__ lin0_w, const float* __restrict__ lin0_b,
                         const float* __restrict__ lin1_w, const float* __restrict__ lin1_b,
                         const float* __restrict__ lin2_w, const float* __restrict__ lin2_b,
                         short* __restrict__ Mw, float* __restrict__ biasf, int* __restrict__ cnt) {
    if (blockIdx.x == 704) {
        int o = threadIdx.x;
        if (o < 4) cnt[o * 64] = 0;
        float acc = merge_b[o];
        for (int k = 0; k < 64; ++k)  acc += merge_w[o * KTOT + k] * lin2_b[k];
        for (int k = 0; k < 128; ++k) acc += merge_w[o * KTOT + 64 + k] * lin1_b[k];
        for (int k = 0; k < 256; ++k) acc += merge_w[o * KTOT + 448 + k] * lin0_b[k];
        biasf[o] = acc;
        return;
    }
    int e = blockIdx.x * 256 + threadIdx.x;
    int o = e / KTOT;
    int j = e - o * KTOT;
    float acc = 0.0f;
    if (j < 64) {
        for (int k = 0; k < 64; ++k) acc += merge_w[o * KTOT + k] * lin2_w[k * 64 + j];
    } else if (j < 192) {
        int jj = j - 64;
        for (int k = 0; k < 128; ++k) acc += merge_w[o * KTOT + 64 + k] * lin1_w[k * 128 + jj];
    } else if (j < 448) {
        acc = merge_w[o * KTOT + j];
    } else {
        int jj = j - 448;
        for (int k = 0; k < 256; ++k) acc += merge_w[o * KTOT + 448 + k] * lin0_w[k * 256 + jj];
    }
    Mw[o * KTOT + j] = f2bf(acc);
}

// ================= NMS stage 1: mask0 = (S == pool9(S)) =================
__global__ __launch_bounds__(256) void nms1(const float* __restrict__ scores,
                                            float* __restrict__ mask) {
    __shared__ float tile[40][40];
    __shared__ float hm[40][32];
    int bz = blockIdx.z;
    int x0 = blockIdx.x * 32, y0 = blockIdx.y * 32;
    const float* sp = scores + bz * HW;
    for (int t = threadIdx.x; t < 1600; t += 256) {
        int ly = t / 40, lx = t - ly * 40;
        int gy = y0 - 4 + ly, gx = x0 - 4 + lx;
        tile[ly][lx] = (gy >= 0 && gy < H && gx >= 0 && gx < W) ? sp[gy * W + gx] : -INFINITY;
    }
    __syncthreads();
    for (int t = threadIdx.x; t < 1280; t += 256) {
        int ly = t >> 5, lx = t & 31;
        float m = tile[ly][lx];
        #pragma unroll
        for (int d = 1; d < 9; ++d) m = fmaxf(m, tile[ly][lx + d]);
        hm[ly][lx] = m;
    }
    __syncthreads();
    for (int t = threadIdx.x; t < 1024; t += 256) {
        int ly = t >> 5, lx = t & 31;
        float m = hm[ly][lx];
        #pragma unroll
        for (int d = 1; d < 9; ++d) m = fmaxf(m, hm[ly + d][lx]);
        float s = tile[ly + 4][lx + 4];
        mask[bz * HW + (y0 + ly) * W + x0 + lx] = (s == m) ? 1.0f : 0.0f;
    }
}

// ===== NMS stage 2: remaining 4 pools (2 NMS iterations) fused in LDS + compaction =====
__global__ __launch_bounds__(256) void nms2_compact(const float* __restrict__ scores,
                                                    const float* __restrict__ mask0,
                                                    unsigned long long* __restrict__ cand,
                                                    int* __restrict__ cnt) {
    __shared__ float Sm[56 * 56];   // S on local [4,60)
    __shared__ float Mm[64 * 64];   // mask on local [0,64)
    __shared__ float Zm[56 * 56];   // Z on local [4,60)
    __shared__ float Tm[64 * 56];   // h-pass temp
    __shared__ int lcnt, gbase;
    int bz = blockIdx.z;
    int x0 = blockIdx.x * 32, y0 = blockIdx.y * 32;
    const float* sp = scores + bz * HW;
    const float* mp = mask0 + bz * HW;
    if (threadIdx.x == 0) lcnt = 0;
    for (int t = threadIdx.x; t < 4096; t += 256) {
        int ly = t >> 6, lx = t & 63;
        int gy = y0 - 16 + ly, gx = x0 - 16 + lx;
        Mm[t] = (gy >= 0 && gy < H && gx >= 0 && gx < W) ? mp[gy * W + gx] : 0.0f;
    }
    for (int t = threadIdx.x; t < 3136; t += 256) {
        int i = t / 56, j = t - i * 56;
        int gy = y0 - 12 + i, gx = x0 - 12 + j;
        Sm[t] = (gy >= 0 && gy < H && gx >= 0 && gx < W) ? sp[gy * W + gx] : -1.0f;
    }
    __syncthreads();
    for (int t = threadIdx.x; t < 3584; t += 256) {
        int i = t / 56, c = t - i * 56;
        float m = Mm[i * 64 + c];
        #pragma unroll
        for (int d = 1; d < 9; ++d) m = fmaxf(m, Mm[i * 64 + c + d]);
        Tm[i * 56 + c] = m;
    }
    __syncthreads();
    for (int t = threadIdx.x; t < 3136; t += 256) {
        int i = t / 56, c = t - i * 56;
        float m = Tm[i * 56 + c];
        #pragma unroll
        for (int d = 1; d < 9; ++d) m = fmaxf(m, Tm[(i + d) * 56 + c]);
        Zm[t] = (m > 0.0f) ? -1.0f : Sm[t];
    }
    __syncthreads();
    for (int t = threadIdx.x; t < 2688; t += 256) {
        int i = t / 48, c = t - i * 48;
        float m = Zm[i * 56 + c];
        #pragma unroll
        for (int d = 1; d < 9; ++d) m = fmaxf(m, Zm[i * 56 + c + d]);
        Tm[i * 56 + c] = m;
    }
    __syncthreads();
    for (int t = threadIdx.x; t < 2304; t += 256) {
        int r = t / 48, c = t - r * 48;
        float m = Tm[r * 56 + c];
        #pragma unroll
        for (int d = 1; d < 9; ++d) m = fmaxf(m, Tm[(r + d) * 56 + c]);
        float Zc = Zm[(r + 4) * 56 + c + 4];
        int mi = (r + 8) * 64 + c + 8;
        bool nm = (Zc == m) && (Zc >= 0.0f);
        Mm[mi] = (Mm[mi] != 0.0f || nm) ? 1.0f : 0.0f;
    }
    __syncthreads();
    for (int t = threadIdx.x; t < 1920; t += 256) {
        int r = t / 40, c = t - r * 40;
        float m = Mm[(r + 8) * 64 + c + 8];
        #pragma unroll
        for (int d = 1; d < 9; ++d) m = fmaxf(m, Mm[(r + 8) * 64 + c + 8 + d]);
        Tm[r * 56 + c] = m;
    }
    __syncthreads();
    for (int t = threadIdx.x; t < 1600; t += 256) {
        int r = t / 40, c = t - r * 40;
        float m = Tm[r * 56 + c];
        #pragma unroll
        for (int d = 1; d < 9; ++d) m = fmaxf(m, Tm[(r + d) * 56 + c]);
        int zi = (r + 8) * 56 + c + 8;
        Zm[zi] = (m > 0.0f) ? -1.0f : Sm[zi];
    }
    __syncthreads();
    for (int t = threadIdx.x; t < 1280; t += 256) {
        int r = t / 32, c = t & 31;
        float m = Zm[(r + 8) * 56 + c + 8];
        #pragma unroll
        for (int d = 1; d < 9; ++d) m = fmaxf(m, Zm[(r + 8) * 56 + c + 8 + d]);
        Tm[r * 56 + c] = m;
    }
    __syncthreads();
    unsigned long long keys[4];
    int nl = 0;
    #pragma unroll
    for (int q = 0; q < 4; ++q) {
        int t = threadIdx.x + q * 256;
        int r3 = t >> 5, c = t & 31;
        float m = Tm[r3 * 56 + c];
        #pragma unroll
        for (int d = 1; d < 9; ++d) m = fmaxf(m, Tm[(r3 + d) * 56 + c]);
        float Zc = Zm[(r3 + 12) * 56 + c + 12];
        bool fin = (Mm[(r3 + 16) * 64 + c + 16] != 0.0f) || ((Zc == m) && (Zc >= 0.0f));
        int gy = y0 + r3, gx = x0 + c;
        float sc = Sm[(r3 + 12) * 56 + c + 12];
        if (fin && gy >= 4 && gy < H - 4 && gx >= 4 && gx < W - 4 && sc > THRESH) {
            unsigned r = (unsigned)(gy * W + gx);
            unsigned bits = __float_as_uint(sc) | 0x80000000u;
            keys[nl++] = ((unsigned long long)bits << 32) |
                         (unsigned long long)(0xFFFFFFFFu - r);
        }
    }
    int lpos = 0;
    if (nl) lpos = atomicAdd(&lcnt, nl);
    __syncthreads();
    if (threadIdx.x == 0) gbase = (lcnt > 0) ? atomicAdd(&cnt[bz * 64], lcnt) : 0;
    __syncthreads();
    for (int j = 0; j < nl; ++j) {
        int p = gbase + lpos + j;
        if (p < CAP) cand[(size_t)bz * CAP + p] = keys[j];
    }
}

// ===== topk: TWO-LEVEL histogram select (22-bit prefix) + bitonic; emits spatial perm =====
__global__ __launch_bounds__(1024) void topk(const unsigned long long* __restrict__ cand,
                                             const int* __restrict__ cnt,
                                             float* __restrict__ out, int* __restrict__ fidx,
                                             int* __restrict__ perm) {
    __shared__ int hist[2048];
    __shared__ unsigned long long buf[4096];
    __shared__ int scnt, spiv1, spiv2, sabove;
    int b = blockIdx.x, tid = threadIdx.x;
    int m = cnt[b * 64]; if (m > CAP) m = CAP;
    const unsigned long long* cb = cand + (size_t)b * CAP;
    int target = (m < 1024) ? m : 1024;

    hist[tid] = 0; hist[tid + 1024] = 0;
    if (tid == 0) { scnt = 0; spiv1 = 2048; spiv2 = 0; sabove = 0; }
    __syncthreads();
    for (int i = tid; i < m; i += 1024)
        atomicAdd(&hist[(int)(cb[i] >> 53) & 0x7FF], 1);
    __syncthreads();
    for (int d = 1; d < 2048; d <<= 1) {
        int v0 = hist[tid] + ((tid + d < 2048) ? hist[tid + d] : 0);
        int v1 = hist[tid + 1024] + ((tid + 1024 + d < 2048) ? hist[tid + 1024 + d] : 0);
        __syncthreads();
        hist[tid] = v0; hist[tid + 1024] = v1;
        __syncthreads();
    }
    if (target > 0) {
        for (int t = tid; t < 2048; t += 1024) {
            int c = hist[t];
            int cn = (t < 2047) ? hist[t + 1] : 0;
            if (c >= target && cn < target) { spiv1 = t; sabove = cn; }
        }
    }
    __syncthreads();
    int piv1 = spiv1;
    int target2 = target - sabove;
    hist[tid] = 0; hist[tid + 1024] = 0;
    __syncthreads();
    for (int i = tid; i < m; i += 1024) {
        unsigned long long k = cb[i];
        if (((int)(k >> 53) & 0x7FF) == piv1)
            atomicAdd(&hist[(int)(k >> 42) & 0x7FF], 1);
    }
    __syncthreads();
    for (int d = 1; d < 2048; d <<= 1) {
        int v0 = hist[tid] + ((tid + d < 2048) ? hist[tid + d] : 0);
        int v1 = hist[tid + 1024] + ((tid + 1024 + d < 2048) ? hist[tid + 1024 + d] : 0);
        __syncthreads();
        hist[tid] = v0; hist[tid + 1024] = v1;
        __syncthreads();
    }
    if (target > 0) {
        for (int t = tid; t < 2048; t += 1024) {
            int c = hist[t];
            int cn = (t < 2047) ? hist[t + 1] : 0;
            if (c >= target2 && cn < target2) spiv2 = t;
        }
    }
    __syncthreads();
    int piv2 = spiv2;
    for (int i = tid; i < m; i += 1024) {
        unsigned long long k = cb[i];
        int b1 = (int)(k >> 53) & 0x7FF;
        bool sel = (target > 0) &&
                   (b1 > piv1 || (b1 == piv1 && (((int)(k >> 42) & 0x7FF) >= piv2)));
        if (sel) {
            int p = atomicAdd(&scnt, 1);
            if (p < 4096) buf[p] = k;
        }
    }
    __syncthreads();
    int sc_ = scnt; if (sc_ > 4096) sc_ = 4096;
    int ns = 1024; while (ns < sc_) ns <<= 1;
    for (int t = tid; t < ns; t += 1024) if (t >= sc_) buf[t] = 0ULL;
    __syncthreads();
    for (int k = 2; k <= ns; k <<= 1)
        for (int j = k >> 1; j > 0; j >>= 1) {
            __syncthreads();
            for (int t = tid; t < ns; t += 1024) {
                int ixj = t ^ j;
                if (ixj > t) {
                    unsigned long long a = buf[t], bb = buf[ixj];
                    if (((t & k) == 0) ? (a < bb) : (a > bb)) { buf[t] = bb; buf[ixj] = a; }
                }
            }
        }
    __syncthreads();
    unsigned long long key = buf[tid];
    float kx, ky, sc;
    unsigned idx;
    if (key != 0ULL) {
        unsigned ord = (unsigned)(key >> 32);
        sc = __uint_as_float(ord ^ 0x80000000u);
        idx = 0xFFFFFFFFu - (unsigned)(key & 0xFFFFFFFFu);
        kx = (float)(idx % W);
        ky = (float)(idx / W);
    } else {
        sc = -1.0f; idx = 0; kx = 0.0f; ky = 0.0f;
    }
    int bn = b * NKP + tid;
    out[bn * 2 + 0] = kx;
    out[bn * 2 + 1] = ky;
    out[B * NKP * 2 + bn] = sc;
    fidx[bn] = (int)idx;
    __syncthreads();
    unsigned* b32 = (unsigned*)buf;
    b32[tid] = (idx << 10) | (unsigned)tid;
    for (int k = 2; k <= 1024; k <<= 1)
        for (int j = k >> 1; j > 0; j >>= 1) {
            __syncthreads();
            int ixj = tid ^ j;
            if (ixj > tid) {
                unsigned a = b32[tid], bb = b32[ixj];
                if (((tid & k) == 0) ? (a > bb) : (a < bb)) { b32[tid] = bb; b32[ixj] = a; }
            }
        }
    __syncthreads();
    perm[b * NKP + tid] = (int)(b32[tid] & 1023u);
}

// ===== fused descriptor sampling; KPB kp/block; paired-x dwordx2 taps; bf16 X out =====
__global__ __launch_bounds__(704) void sample_all(const float* __restrict__ d1,
                                                  const float* __restrict__ d2,
                                                  const float* __restrict__ cDa,
                                                  const float* __restrict__ d4,
                                                  const int* __restrict__ fidx,
                                                  const int* __restrict__ perm,
                                                  short* __restrict__ X) {
    __shared__ float ssum[KPB][12];
    int c = threadIdx.x;
    int wid = c >> 6, lane = c & 63;
    int b = blockIdx.x >> 8;                 // 256 blocks per batch (1024 kp / KPB)
    int g0 = (blockIdx.x & 255) * KPB;

    const float* map; int h, w, s, C, cl;
    if (c < 64)       { map = d1;  h = 240; w = 320; s = 2;  cl = c;       C = 64; }
    else if (c < 192) { map = d2;  h = 120; w = 160; s = 4;  cl = c - 64;  C = 128; }
    else if (c < 448) { map = cDa; h = 60;  w = 80;  s = 8;  cl = c - 192; C = 256; }
    else              { map = d4;  h = 30;  w = 40;  s = 16; cl = c - 448; C = 256; }
    const float* plane = map + ((size_t)(b * C + cl)) * (h * w);

    int cols[KPB];
    float vals[KPB];
    float q0x[KPB], q0y[KPB], q1x[KPB], q1y[KPB];
    float ax[KPB], ay[KPB], bx[KPB], by[KPB];

    #pragma unroll
    for (int k = 0; k < KPB; ++k) {
        int col = (b << 10) | perm[(b << 10) + g0 + k];
        cols[k] = col;
        int idx = fidx[col];
        float kx = (float)(idx % W);
        float ky = (float)(idx / W);
        float kxs = kx - (float)s * 0.5f + 0.5f;
        float kys = ky - (float)s * 0.5f + 0.5f;
        float gx = kxs / (float)(w * s - 1) * 2.0f - 1.0f;
        float gy = kys / (float)(h * s - 1) * 2.0f - 1.0f;
        float x = (gx + 1.0f) * 0.5f * (float)(w - 1);
        float y = (gy + 1.0f) * 0.5f * (float)(h - 1);
        float x0f = floorf(x), y0f = floorf(y);
        int x0 = (int)x0f, y0 = (int)y0f;
        float wx1 = x - x0f, wy1 = y - y0f;
        float wx0 = 1.0f - wx1, wy0 = 1.0f - wy1;
        bool vx0 = (x0 >= 0) && (x0 < w);
        bool vx1 = (x0 + 1 >= 0) && (x0 + 1 < w);
        bool vy0 = (y0 >= 0) && (y0 < h);
        bool vy1 = (y0 + 1 >= 0) && (y0 + 1 < h);
        int xc0 = min(max(x0, 0), w - 1), xc1 = min(max(x0 + 1, 0), w - 1);
        int yc0 = min(max(y0, 0), h - 1), yc1 = min(max(y0 + 1, 0), h - 1);
        float w00 = (vx0 && vy0) ? wx0 * wy0 : 0.0f;
        float w01 = (vx1 && vy0) ? wx1 * wy0 : 0.0f;
        float w10 = (vx0 && vy1) ? wx0 * wy1 : 0.0f;
        float w11 = (vx1 && vy1) ? wx1 * wy1 : 0.0f;
        int xb = min(xc0, w - 2);
        float s0 = (xc0 == xb) ? 1.0f : 0.0f;   // xc0's value is .x (else .y)
        float s1 = (xc1 == xb) ? 1.0f : 0.0f;   // xc1's value is .x (else .y)
        ax[k] = w00 * s0 + w01 * s1;
        ay[k] = w00 * (1.0f - s0) + w01 * (1.0f - s1);
        bx[k] = w10 * s0 + w11 * s1;
        by[k] = w10 * (1.0f - s0) + w11 * (1.0f - s1);
        f2u q0 = *(const f2u*)(plane + yc0 * w + xb);
        f2u q1 = *(const f2u*)(plane + yc1 * w + xb);
        q0x[k] = q0.x; q0y[k] = q0.y;
        q1x[k] = q1.x; q1y[k] = q1.y;
    }
    #pragma unroll
    for (int k = 0; k < KPB; ++k)
        vals[k] = q0x[k] * ax[k] + q0y[k] * ay[k] + q1x[k] * bx[k] + q1y[k] * by[k];

    // per-wave reduction of squares (segments are wave-aligned: 1/2/4/4 waves)
    #pragma unroll
    for (int k = 0; k < KPB; ++k) {
        float r = vals[k] * vals[k];
        #pragma unroll
        for (int off = 32; off > 0; off >>= 1) r += __shfl_xor(r, off, 64);
        if (lane == 0) ssum[k][wid] = r;
    }
    __syncthreads();
    int wbeg, wcnt;
    if (c < 64)       { wbeg = 0; wcnt = 1; }
    else if (c < 192) { wbeg = 1; wcnt = 2; }
    else if (c < 448) { wbeg = 3; wcnt = 4; }
    else              { wbeg = 7; wcnt = 4; }
    #pragma unroll
    for (int k = 0; k < KPB; ++k) {
        float sum = 0.0f;
        for (int t = 0; t < wcnt; ++t) sum += ssum[k][wbeg + t];
        float denom = fmaxf(sqrtf(sum), 1e-12f);
        X[(size_t)cols[k] * KTOT + c] = f2bf(vals[k] / denom);
    }
}

// ===== GEMM (bf16 MFMA): out[256,4096] = Mw[256,704] * X^T + bias; bf16 inputs =====
__global__ __launch_bounds__(256) void gemm_mfma(const short* __restrict__ Mw,
                                                 const short* __restrict__ X,
                                                 const float* __restrict__ biasf,
                                                 float* __restrict__ out) {
    __shared__ short As[64 * 72];
    __shared__ short Bs[64 * 72];
    int tid = threadIdx.x;
    int lane = tid & 63, w = tid >> 6;
    int r = lane & 15, quad = lane >> 4;
    int rowBase = blockIdx.y * 64, colBase = blockIdx.x * 64;
    int sm = tid >> 2, skq = (tid & 3) << 4;   // 16 shorts (32B) per thread per tile

    const short* pa = Mw + (size_t)(rowBase + sm) * KTOT + skq;
    const short* pb = X + (size_t)(colBase + sm) * KTOT + skq;
    s8v a0 = *(const s8v*)(pa), a1 = *(const s8v*)(pa + 8);
    s8v b0 = *(const s8v*)(pb), b1 = *(const s8v*)(pb + 8);

    f4v acc[4];
    #pragma unroll
    for (int t = 0; t < 4; ++t) acc[t] = (f4v)0.0f;

    for (int kt = 0; kt < 11; ++kt) {
        __syncthreads();
        *(s8v*)&As[sm * 72 + skq + 0] = a0;
        *(s8v*)&As[sm * 72 + skq + 8] = a1;
        *(s8v*)&Bs[sm * 72 + skq + 0] = b0;
        *(s8v*)&Bs[sm * 72 + skq + 8] = b1;
        __syncthreads();
        if (kt < 10) {
            pa += 64; pb += 64;
            a0 = *(const s8v*)(pa); a1 = *(const s8v*)(pa + 8);
            b0 = *(const s8v*)(pb); b1 = *(const s8v*)(pb + 8);
        }
        #pragma unroll
        for (int kk = 0; kk < 2; ++kk) {
            int aoff = (w * 16 + r) * 72 + kk * 32 + quad * 8;
            s8v af = *(const s8v*)&As[aoff];
            #pragma unroll
            for (int t = 0; t < 4; ++t) {
                int boff = (t * 16 + r) * 72 + kk * 32 + quad * 8;
                s8v bf = *(const s8v*)&Bs[boff];
                acc[t] = __builtin_amdgcn_mfma_f32_16x16x32_bf16(af, bf, acc[t], 0, 0, 0);
            }
        }
    }
    #pragma unroll
    for (int t = 0; t < 4; ++t) {
        int colg = colBase + t * 16 + r;
        size_t obase = (size_t)(colg >> 10) * (256 * NKP) + (size_t)(colg & 1023);
        #pragma unroll
        for (int reg = 0; reg < 4; ++reg) {
            int row = rowBase + w * 16 + quad * 4 + reg;
            out[obase + (size_t)row * NKP] = acc[t][reg] + biasf[row];
        }
    }
}

// ================= launch =================
extern "C" void kernel_launch(void* const* d_in, const int* in_sizes, int n_in,
                              void* d_out, int out_size, void* d_ws, size_t ws_size,
                              hipStream_t stream) {
    const float* scores  = (const float*)d_in[0];
    const float* d1      = (const float*)d_in[1];
    const float* d2      = (const float*)d_in[2];
    const float* cDa     = (const float*)d_in[3];
    const float* d4      = (const float*)d_in[4];
    const float* lin0_w  = (const float*)d_in[5];
    const float* lin0_b  = (const float*)d_in[6];
    const float* lin1_w  = (const float*)d_in[7];
    const float* lin1_b  = (const float*)d_in[8];
    const float* lin2_w  = (const float*)d_in[9];
    const float* lin2_b  = (const float*)d_in[10];
    const float* merge_w = (const float*)d_in[11];
    const float* merge_b = (const float*)d_in[12];
    float* out = (float*)d_out;

    char* ws = (char*)d_ws;
    float* MASK = (float*)ws;                                          // BHW floats (nms phase)
    short* Xbuf = (short*)ws;                                          // aliases (post-topk); 5.77 MB
    unsigned long long* cand  = (unsigned long long*)(ws + 14745600);  // 524,288 B
    int* cnt                  = (int*)(ws + 15269888);                 // 1,024 B
    int* fidx                 = (int*)(ws + 15401984);                 // 16,384 B
    short* Mw                 = (short*)(ws + 15418368);               // 360,448 B (bf16)
    float* biasf              = (float*)(ws + 16139264);               // 1,024 B
    int* perm                 = (int*)(ws + 16140288);                 // 16,384 B

    dim3 tgrid(W / 32, H / 32, B);   // (20,15,4)

    fuse_all<<<705, 256, 0, stream>>>(merge_w, merge_b, lin0_w, lin0_b, lin1_w, lin1_b,
                                      lin2_w, lin2_b, Mw, biasf, cnt);
    nms1<<<tgrid, 256, 0, stream>>>(scores, MASK);
    nms2_compact<<<tgrid, 256, 0, stream>>>(scores, MASK, cand, cnt);
    topk<<<B, 1024, 0, stream>>>(cand, cnt, out, fidx, perm);
    sample_all<<<(B * NKP) / KPB, KTOT, 0, stream>>>(d1, d2, cDa, d4, fidx, perm, Xbuf);
    gemm_mfma<<<dim3(NCOL / 64, 256 / 64), 256, 0, stream>>>(Mw, Xbuf, biasf, out + B * NKP * 3);
}

// Round 4
// 375.601 us; speedup vs baseline: 1.1218x; 1.0156x over previous
//
#include <hip/hip_runtime.h>
#include <hip/hip_bf16.h>

#define B 4
#define H 480
#define W 640
#define HW (H*W)
#define BHW (B*H*W)
#define NKP 1024
#define THRESH 0.005f
#define CAP 16384
#define NCOL (B*NKP)
#define KTOT 704
#define KPB 4

typedef __attribute__((ext_vector_type(8))) short s8v;
typedef __attribute__((ext_vector_type(4))) float f4v;
typedef struct { float x, y; } __attribute__((aligned(4))) f2u;   // 4B-aligned pair load

__device__ __forceinline__ short f2bf(float f) {
    __hip_bfloat16 h = __float2bfloat16(f);
    return *(short*)&h;
}

// ================= fused weights + bias + counter zero (Mw bf16) =================
__global__ void fuse_all(const float* __restrict__ merge_w, const float* __restrict__ merge_b,
                         const float* __restrict__ lin0_w, const float* __restrict__ lin0_b,
                         const float* __restrict__ lin1_w, const float* __restrict__ lin1_b,
                         const float* __restrict__ lin2_w, const float* __restrict__ lin2_b,
                         short* __restrict__ Mw, float* __restrict__ biasf, int* __restrict__ cnt) {
    if (blockIdx.x == 704) {
        int o = threadIdx.x;
        if (o < 4) cnt[o * 64] = 0;
        float acc = merge_b[o];
        for (int k = 0; k < 64; ++k)  acc += merge_w[o * KTOT + k] * lin2_b[k];
        for (int k = 0; k < 128; ++k) acc += merge_w[o * KTOT + 64 + k] * lin1_b[k];
        for (int k = 0; k < 256; ++k) acc += merge_w[o * KTOT + 448 + k] * lin0_b[k];
        biasf[o] = acc;
        return;
    }
    int e = blockIdx.x * 256 + threadIdx.x;
    int o = e / KTOT;
    int j = e - o * KTOT;
    float acc = 0.0f;
    if (j < 64) {
        for (int k = 0; k < 64; ++k) acc += merge_w[o * KTOT + k] * lin2_w[k * 64 + j];
    } else if (j < 192) {
        int jj = j - 64;
        for (int k = 0; k < 128; ++k) acc += merge_w[o * KTOT + 64 + k] * lin1_w[k * 128 + jj];
    } else if (j < 448) {
        acc = merge_w[o * KTOT + j];
    } else {
        int jj = j - 448;
        for (int k = 0; k < 256; ++k) acc += merge_w[o * KTOT + 448 + k] * lin0_w[k * 256 + jj];
    }
    Mw[o * KTOT + j] = f2bf(acc);
}

// ================= NMS stage 1: mask0 = (S == pool9(S)) =================
__global__ __launch_bounds__(256) void nms1(const float* __restrict__ scores,
                                            float* __restrict__ mask) {
    __shared__ float tile[40][40];
    __shared__ float hm[40][32];
    int bz = blockIdx.z;
    int x0 = blockIdx.x * 32, y0 = blockIdx.y * 32;
    const float* sp = scores + bz * HW;
    for (int t = threadIdx.x; t < 1600; t += 256) {
        int ly = t / 40, lx = t - ly * 40;
        int gy = y0 - 4 + ly, gx = x0 - 4 + lx;
        tile[ly][lx] = (gy >= 0 && gy < H && gx >= 0 && gx < W) ? sp[gy * W + gx] : -INFINITY;
    }
    __syncthreads();
    for (int t = threadIdx.x; t < 1280; t += 256) {
        int ly = t >> 5, lx = t & 31;
        float m = tile[ly][lx];
        #pragma unroll
        for (int d = 1; d < 9; ++d) m = fmaxf(m, tile[ly][lx + d]);
        hm[ly][lx] = m;
    }
    __syncthreads();
    for (int t = threadIdx.x; t < 1024; t += 256) {
        int ly = t >> 5, lx = t & 31;
        float m = hm[ly][lx];
        #pragma unroll
        for (int d = 1; d < 9; ++d) m = fmaxf(m, hm[ly + d][lx]);
        float s = tile[ly + 4][lx + 4];
        mask[bz * HW + (y0 + ly) * W + x0 + lx] = (s == m) ? 1.0f : 0.0f;
    }
}

// ===== NMS stage 2: remaining 4 pools (2 NMS iterations) fused in LDS + compaction =====
__global__ __launch_bounds__(256) void nms2_compact(const float* __restrict__ scores,
                                                    const float* __restrict__ mask0,
                                                    unsigned long long* __restrict__ cand,
                                                    int* __restrict__ cnt) {
    __shared__ float Sm[56 * 56];   // S on local [4,60)
    __shared__ float Mm[64 * 64];   // mask on local [0,64)
    __shared__ float Zm[56 * 56];   // Z on local [4,60)
    __shared__ float Tm[64 * 56];   // h-pass temp
    __shared__ int lcnt, gbase;
    int bz = blockIdx.z;
    int x0 = blockIdx.x * 32, y0 = blockIdx.y * 32;
    const float* sp = scores + bz * HW;
    const float* mp = mask0 + bz * HW;
    if (threadIdx.x == 0) lcnt = 0;
    for (int t = threadIdx.x; t < 4096; t += 256) {
        int ly = t >> 6, lx = t & 63;
        int gy = y0 - 16 + ly, gx = x0 - 16 + lx;
        Mm[t] = (gy >= 0 && gy < H && gx >= 0 && gx < W) ? mp[gy * W + gx] : 0.0f;
    }
    for (int t = threadIdx.x; t < 3136; t += 256) {
        int i = t / 56, j = t - i * 56;
        int gy = y0 - 12 + i, gx = x0 - 12 + j;
        Sm[t] = (gy >= 0 && gy < H && gx >= 0 && gx < W) ? sp[gy * W + gx] : -1.0f;
    }
    __syncthreads();
    for (int t = threadIdx.x; t < 3584; t += 256) {
        int i = t / 56, c = t - i * 56;
        float m = Mm[i * 64 + c];
        #pragma unroll
        for (int d = 1; d < 9; ++d) m = fmaxf(m, Mm[i * 64 + c + d]);
        Tm[i * 56 + c] = m;
    }
    __syncthreads();
    for (int t = threadIdx.x; t < 3136; t += 256) {
        int i = t / 56, c = t - i * 56;
        float m = Tm[i * 56 + c];
        #pragma unroll
        for (int d = 1; d < 9; ++d) m = fmaxf(m, Tm[(i + d) * 56 + c]);
        Zm[t] = (m > 0.0f) ? -1.0f : Sm[t];
    }
    __syncthreads();
    for (int t = threadIdx.x; t < 2688; t += 256) {
        int i = t / 48, c = t - i * 48;
        float m = Zm[i * 56 + c];
        #pragma unroll
        for (int d = 1; d < 9; ++d) m = fmaxf(m, Zm[i * 56 + c + d]);
        Tm[i * 56 + c] = m;
    }
    __syncthreads();
    for (int t = threadIdx.x; t < 2304; t += 256) {
        int r = t / 48, c = t - r * 48;
        float m = Tm[r * 56 + c];
        #pragma unroll
        for (int d = 1; d < 9; ++d) m = fmaxf(m, Tm[(r + d) * 56 + c]);
        float Zc = Zm[(r + 4) * 56 + c + 4];
        int mi = (r + 8) * 64 + c + 8;
        bool nm = (Zc == m) && (Zc >= 0.0f);
        Mm[mi] = (Mm[mi] != 0.0f || nm) ? 1.0f : 0.0f;
    }
    __syncthreads();
    for (int t = threadIdx.x; t < 1920; t += 256) {
        int r = t / 40, c = t - r * 40;
        float m = Mm[(r + 8) * 64 + c + 8];
        #pragma unroll
        for (int d = 1; d < 9; ++d) m = fmaxf(m, Mm[(r + 8) * 64 + c + 8 + d]);
        Tm[r * 56 + c] = m;
    }
    __syncthreads();
    for (int t = threadIdx.x; t < 1600; t += 256) {
        int r = t / 40, c = t - r * 40;
        float m = Tm[r * 56 + c];
        #pragma unroll
        for (int d = 1; d < 9; ++d) m = fmaxf(m, Tm[(r + d) * 56 + c]);
        int zi = (r + 8) * 56 + c + 8;
        Zm[zi] = (m > 0.0f) ? -1.0f : Sm[zi];
    }
    __syncthreads();
    for (int t = threadIdx.x; t < 1280; t += 256) {
        int r = t / 32, c = t & 31;
        float m = Zm[(r + 8) * 56 + c + 8];
        #pragma unroll
        for (int d = 1; d < 9; ++d) m = fmaxf(m, Zm[(r + 8) * 56 + c + 8 + d]);
        Tm[r * 56 + c] = m;
    }
    __syncthreads();
    unsigned long long keys[4];
    int nl = 0;
    #pragma unroll
    for (int q = 0; q < 4; ++q) {
        int t = threadIdx.x + q * 256;
        int r3 = t >> 5, c = t & 31;
        float m = Tm[r3 * 56 + c];
        #pragma unroll
        for (int d = 1; d < 9; ++d) m = fmaxf(m, Tm[(r3 + d) * 56 + c]);
        float Zc = Zm[(r3 + 12) * 56 + c + 12];
        bool fin = (Mm[(r3 + 16) * 64 + c + 16] != 0.0f) || ((Zc == m) && (Zc >= 0.0f));
        int gy = y0 + r3, gx = x0 + c;
        float sc = Sm[(r3 + 12) * 56 + c + 12];
        if (fin && gy >= 4 && gy < H - 4 && gx >= 4 && gx < W - 4 && sc > THRESH) {
            unsigned r = (unsigned)(gy * W + gx);
            unsigned bits = __float_as_uint(sc) | 0x80000000u;
            keys[nl++] = ((unsigned long long)bits << 32) |
                         (unsigned long long)(0xFFFFFFFFu - r);
        }
    }
    int lpos = 0;
    if (nl) lpos = atomicAdd(&lcnt, nl);
    __syncthreads();
    if (threadIdx.x == 0) gbase = (lcnt > 0) ? atomicAdd(&cnt[bz * 64], lcnt) : 0;
    __syncthreads();
    for (int j = 0; j < nl; ++j) {
        int p = gbase + lpos + j;
        if (p < CAP) cand[(size_t)bz * CAP + p] = keys[j];
    }
}

// ===== topk: TWO-LEVEL histogram select (22-bit prefix) + bitonic; emits spatial perm =====
__global__ __launch_bounds__(1024) void topk(const unsigned long long* __restrict__ cand,
                                             const int* __restrict__ cnt,
                                             float* __restrict__ out, int* __restrict__ fidx,
                                             int* __restrict__ perm) {
    __shared__ int hist[2048];
    __shared__ unsigned long long buf[4096];
    __shared__ int scnt, spiv1, spiv2, sabove;
    int b = blockIdx.x, tid = threadIdx.x;
    int m = cnt[b * 64]; if (m > CAP) m = CAP;
    const unsigned long long* cb = cand + (size_t)b * CAP;
    int target = (m < 1024) ? m : 1024;

    hist[tid] = 0; hist[tid + 1024] = 0;
    if (tid == 0) { scnt = 0; spiv1 = 2048; spiv2 = 0; sabove = 0; }
    __syncthreads();
    for (int i = tid; i < m; i += 1024)
        atomicAdd(&hist[(int)(cb[i] >> 53) & 0x7FF], 1);
    __syncthreads();
    for (int d = 1; d < 2048; d <<= 1) {
        int v0 = hist[tid] + ((tid + d < 2048) ? hist[tid + d] : 0);
        int v1 = hist[tid + 1024] + ((tid + 1024 + d < 2048) ? hist[tid + 1024 + d] : 0);
        __syncthreads();
        hist[tid] = v0; hist[tid + 1024] = v1;
        __syncthreads();
    }
    if (target > 0) {
        for (int t = tid; t < 2048; t += 1024) {
            int c = hist[t];
            int cn = (t < 2047) ? hist[t + 1] : 0;
            if (c >= target && cn < target) { spiv1 = t; sabove = cn; }
        }
    }
    __syncthreads();
    int piv1 = spiv1;
    int target2 = target - sabove;
    hist[tid] = 0; hist[tid + 1024] = 0;
    __syncthreads();
    for (int i = tid; i < m; i += 1024) {
        unsigned long long k = cb[i];
        if (((int)(k >> 53) & 0x7FF) == piv1)
            atomicAdd(&hist[(int)(k >> 42) & 0x7FF], 1);
    }
    __syncthreads();
    for (int d = 1; d < 2048; d <<= 1) {
        int v0 = hist[tid] + ((tid + d < 2048) ? hist[tid + d] : 0);
        int v1 = hist[tid + 1024] + ((tid + 1024 + d < 2048) ? hist[tid + 1024 + d] : 0);
        __syncthreads();
        hist[tid] = v0; hist[tid + 1024] = v1;
        __syncthreads();
    }
    if (target > 0) {
        for (int t = tid; t < 2048; t += 1024) {
            int c = hist[t];
            int cn = (t < 2047) ? hist[t + 1] : 0;
            if (c >= target2 && cn < target2) spiv2 = t;
        }
    }
    __syncthreads();
    int piv2 = spiv2;
    for (int i = tid; i < m; i += 1024) {
        unsigned long long k = cb[i];
        int b1 = (int)(k >> 53) & 0x7FF;
        bool sel = (target > 0) &&
                   (b1 > piv1 || (b1 == piv1 && (((int)(k >> 42) & 0x7FF) >= piv2)));
        if (sel) {
            int p = atomicAdd(&scnt, 1);
            if (p < 4096) buf[p] = k;
        }
    }
    __syncthreads();
    int sc_ = scnt; if (sc_ > 4096) sc_ = 4096;
    int ns = 1024; while (ns < sc_) ns <<= 1;
    for (int t = tid; t < ns; t += 1024) if (t >= sc_) buf[t] = 0ULL;
    __syncthreads();
    for (int k = 2; k <= ns; k <<= 1)
        for (int j = k >> 1; j > 0; j >>= 1) {
            __syncthreads();
            for (int t = tid; t < ns; t += 1024) {
                int ixj = t ^ j;
                if (ixj > t) {
                    unsigned long long a = buf[t], bb = buf[ixj];
                    if (((t & k) == 0) ? (a < bb) : (a > bb)) { buf[t] = bb; buf[ixj] = a; }
                }
            }
        }
    __syncthreads();
    unsigned long long key = buf[tid];
    float kx, ky, sc;
    unsigned idx;
    if (key != 0ULL) {
        unsigned ord = (unsigned)(key >> 32);
        sc = __uint_as_float(ord ^ 0x80000000u);
        idx = 0xFFFFFFFFu - (unsigned)(key & 0xFFFFFFFFu);
        kx = (float)(idx % W);
        ky = (float)(idx / W);
    } else {
        sc = -1.0f; idx = 0; kx = 0.0f; ky = 0.0f;
    }
    int bn = b * NKP + tid;
    out[bn * 2 + 0] = kx;
    out[bn * 2 + 1] = ky;
    out[B * NKP * 2 + bn] = sc;
    fidx[bn] = (int)idx;
    __syncthreads();
    unsigned* b32 = (unsigned*)buf;
    b32[tid] = (idx << 10) | (unsigned)tid;
    for (int k = 2; k <= 1024; k <<= 1)
        for (int j = k >> 1; j > 0; j >>= 1) {
            __syncthreads();
            int ixj = tid ^ j;
            if (ixj > tid) {
                unsigned a = b32[tid], bb = b32[ixj];
                if (((tid & k) == 0) ? (a > bb) : (a < bb)) { b32[tid] = bb; b32[ixj] = a; }
            }
        }
    __syncthreads();
    perm[b * NKP + tid] = (int)(b32[tid] & 1023u);
}

// ===== fused descriptor sampling; KPB kp/block; XCD-swizzled block order =====
__global__ __launch_bounds__(704) void sample_all(const float* __restrict__ d1,
                                                  const float* __restrict__ d2,
                                                  const float* __restrict__ cDa,
                                                  const float* __restrict__ d4,
                                                  const int* __restrict__ fidx,
                                                  const int* __restrict__ perm,
                                                  short* __restrict__ X) {
    __shared__ float ssum[KPB][12];
    int c = threadIdx.x;
    int wid = c >> 6, lane = c & 63;
    // XCD-aware swizzle: 1024 blocks, 8 XCDs -> each XCD owns 128 CONTIGUOUS
    // spatially-sorted 4-kp chunks, so row-line reuse stays inside one L2
    // instead of being replicated across all 8 private L2s.
    int bid = blockIdx.x;
    int swz = ((bid & 7) << 7) | (bid >> 3);
    int b = swz >> 8;                 // 256 chunks per batch
    int g0 = (swz & 255) * KPB;

    const float* map; int h, w, s, C, cl;
    if (c < 64)       { map = d1;  h = 240; w = 320; s = 2;  cl = c;       C = 64; }
    else if (c < 192) { map = d2;  h = 120; w = 160; s = 4;  cl = c - 64;  C = 128; }
    else if (c < 448) { map = cDa; h = 60;  w = 80;  s = 8;  cl = c - 192; C = 256; }
    else              { map = d4;  h = 30;  w = 40;  s = 16; cl = c - 448; C = 256; }
    const float* plane = map + ((size_t)(b * C + cl)) * (h * w);

    int cols[KPB];
    float vals[KPB];
    float q0x[KPB], q0y[KPB], q1x[KPB], q1y[KPB];
    float ax[KPB], ay[KPB], bx[KPB], by[KPB];

    #pragma unroll
    for (int k = 0; k < KPB; ++k) {
        int col = (b << 10) | perm[(b << 10) + g0 + k];
        cols[k] = col;
        int idx = fidx[col];
        float kx = (float)(idx % W);
        float ky = (float)(idx / W);
        float kxs = kx - (float)s * 0.5f + 0.5f;
        float kys = ky - (float)s * 0.5f + 0.5f;
        float gx = kxs / (float)(w * s - 1) * 2.0f - 1.0f;
        float gy = kys / (float)(h * s - 1) * 2.0f - 1.0f;
        float x = (gx + 1.0f) * 0.5f * (float)(w - 1);
        float y = (gy + 1.0f) * 0.5f * (float)(h - 1);
        float x0f = floorf(x), y0f = floorf(y);
        int x0 = (int)x0f, y0 = (int)y0f;
        float wx1 = x - x0f, wy1 = y - y0f;
        float wx0 = 1.0f - wx1, wy0 = 1.0f - wy1;
        bool vx0 = (x0 >= 0) && (x0 < w);
        bool vx1 = (x0 + 1 >= 0) && (x0 + 1 < w);
        bool vy0 = (y0 >= 0) && (y0 < h);
        bool vy1 = (y0 + 1 >= 0) && (y0 + 1 < h);
        int xc0 = min(max(x0, 0), w - 1), xc1 = min(max(x0 + 1, 0), w - 1);
        int yc0 = min(max(y0, 0), h - 1), yc1 = min(max(y0 + 1, 0), h - 1);
        float w00 = (vx0 && vy0) ? wx0 * wy0 : 0.0f;
        float w01 = (vx1 && vy0) ? wx1 * wy0 : 0.0f;
        float w10 = (vx0 && vy1) ? wx0 * wy1 : 0.0f;
        float w11 = (vx1 && vy1) ? wx1 * wy1 : 0.0f;
        int xb = min(xc0, w - 2);
        float s0 = (xc0 == xb) ? 1.0f : 0.0f;   // xc0's value is .x (else .y)
        float s1 = (xc1 == xb) ? 1.0f : 0.0f;   // xc1's value is .x (else .y)
        ax[k] = w00 * s0 + w01 * s1;
        ay[k] = w00 * (1.0f - s0) + w01 * (1.0f - s1);
        bx[k] = w10 * s0 + w11 * s1;
        by[k] = w10 * (1.0f - s0) + w11 * (1.0f - s1);
        f2u q0 = *(const f2u*)(plane + yc0 * w + xb);
        f2u q1 = *(const f2u*)(plane + yc1 * w + xb);
        q0x[k] = q0.x; q0y[k] = q0.y;
        q1x[k] = q1.x; q1y[k] = q1.y;
    }
    #pragma unroll
    for (int k = 0; k < KPB; ++k)
        vals[k] = q0x[k] * ax[k] + q0y[k] * ay[k] + q1x[k] * bx[k] + q1y[k] * by[k];

    // per-wave reduction of squares (segments are wave-aligned: 1/2/4/4 waves)
    #pragma unroll
    for (int k = 0; k < KPB; ++k) {
        float r = vals[k] * vals[k];
        #pragma unroll
        for (int off = 32; off > 0; off >>= 1) r += __shfl_xor(r, off, 64);
        if (lane == 0) ssum[k][wid] = r;
    }
    __syncthreads();
    int wbeg, wcnt;
    if (c < 64)       { wbeg = 0; wcnt = 1; }
    else if (c < 192) { wbeg = 1; wcnt = 2; }
    else if (c < 448) { wbeg = 3; wcnt = 4; }
    else              { wbeg = 7; wcnt = 4; }
    #pragma unroll
    for (int k = 0; k < KPB; ++k) {
        float sum = 0.0f;
        for (int t = 0; t < wcnt; ++t) sum += ssum[k][wbeg + t];
        float denom = fmaxf(sqrtf(sum), 1e-12f);
        X[(size_t)cols[k] * KTOT + c] = f2bf(vals[k] / denom);
    }
}

// ===== GEMM (bf16 MFMA): out[256,4096] = Mw[256,704] * X^T + bias; bf16 inputs =====
__global__ __launch_bounds__(256) void gemm_mfma(const short* __restrict__ Mw,
                                                 const short* __restrict__ X,
                                                 const float* __restrict__ biasf,
                                                 float* __restrict__ out) {
    __shared__ short As[64 * 72];
    __shared__ short Bs[64 * 72];
    int tid = threadIdx.x;
    int lane = tid & 63, w = tid >> 6;
    int r = lane & 15, quad = lane >> 4;
    int rowBase = blockIdx.y * 64, colBase = blockIdx.x * 64;
    int sm = tid >> 2, skq = (tid & 3) << 4;   // 16 shorts (32B) per thread per tile

    const short* pa = Mw + (size_t)(rowBase + sm) * KTOT + skq;
    const short* pb = X + (size_t)(colBase + sm) * KTOT + skq;
    s8v a0 = *(const s8v*)(pa), a1 = *(const s8v*)(pa + 8);
    s8v b0 = *(const s8v*)(pb), b1 = *(const s8v*)(pb + 8);

    f4v acc[4];
    #pragma unroll
    for (int t = 0; t < 4; ++t) acc[t] = (f4v)0.0f;

    for (int kt = 0; kt < 11; ++kt) {
        __syncthreads();
        *(s8v*)&As[sm * 72 + skq + 0] = a0;
        *(s8v*)&As[sm * 72 + skq + 8] = a1;
        *(s8v*)&Bs[sm * 72 + skq + 0] = b0;
        *(s8v*)&Bs[sm * 72 + skq + 8] = b1;
        __syncthreads();
        if (kt < 10) {
            pa += 64; pb += 64;
            a0 = *(const s8v*)(pa); a1 = *(const s8v*)(pa + 8);
            b0 = *(const s8v*)(pb); b1 = *(const s8v*)(pb + 8);
        }
        #pragma unroll
        for (int kk = 0; kk < 2; ++kk) {
            int aoff = (w * 16 + r) * 72 + kk * 32 + quad * 8;
            s8v af = *(const s8v*)&As[aoff];
            #pragma unroll
            for (int t = 0; t < 4; ++t) {
                int boff = (t * 16 + r) * 72 + kk * 32 + quad * 8;
                s8v bf = *(const s8v*)&Bs[boff];
                acc[t] = __builtin_amdgcn_mfma_f32_16x16x32_bf16(af, bf, acc[t], 0, 0, 0);
            }
        }
    }
    #pragma unroll
    for (int t = 0; t < 4; ++t) {
        int colg = colBase + t * 16 + r;
        size_t obase = (size_t)(colg >> 10) * (256 * NKP) + (size_t)(colg & 1023);
        #pragma unroll
        for (int reg = 0; reg < 4; ++reg) {
            int row = rowBase + w * 16 + quad * 4 + reg;
            out[obase + (size_t)row * NKP] = acc[t][reg] + biasf[row];
        }
    }
}

// ================= launch =================
extern "C" void kernel_launch(void* const* d_in, const int* in_sizes, int n_in,
                              void* d_out, int out_size, void* d_ws, size_t ws_size,
                              hipStream_t stream) {
    const float* scores  = (const float*)d_in[0];
    const float* d1      = (const float*)d_in[1];
    const float* d2      = (const float*)d_in[2];
    const float* cDa     = (const float*)d_in[3];
    const float* d4      = (const float*)d_in[4];
    const float* lin0_w  = (const float*)d_in[5];
    const float* lin0_b  = (const float*)d_in[6];
    const float* lin1_w  = (const float*)d_in[7];
    const float* lin1_b  = (const float*)d_in[8];
    const float* lin2_w  = (const float*)d_in[9];
    const float* lin2_b  = (const float*)d_in[10];
    const float* merge_w = (const float*)d_in[11];
    const float* merge_b = (const float*)d_in[12];
    float* out = (float*)d_out;

    char* ws = (char*)d_ws;
    float* MASK = (float*)ws;                                          // BHW floats (nms phase)
    short* Xbuf = (short*)ws;                                          // aliases (post-topk); 5.77 MB
    unsigned long long* cand  = (unsigned long long*)(ws + 14745600);  // 524,288 B
    int* cnt                  = (int*)(ws + 15269888);                 // 1,024 B
    int* fidx                 = (int*)(ws + 15401984);                 // 16,384 B
    short* Mw                 = (short*)(ws + 15418368);               // 360,448 B (bf16)
    float* biasf              = (float*)(ws + 16139264);               // 1,024 B
    int* perm                 = (int*)(ws + 16140288);                 // 16,384 B

    dim3 tgrid(W / 32, H / 32, B);   // (20,15,4)

    fuse_all<<<705, 256, 0, stream>>>(merge_w, merge_b, lin0_w, lin0_b, lin1_w, lin1_b,
                                      lin2_w, lin2_b, Mw, biasf, cnt);
    nms1<<<tgrid, 256, 0, stream>>>(scores, MASK);
    nms2_compact<<<tgrid, 256, 0, stream>>>(scores, MASK, cand, cnt);
    topk<<<B, 1024, 0, stream>>>(cand, cnt, out, fidx, perm);
    sample_all<<<(B * NKP) / KPB, KTOT, 0, stream>>>(d1, d2, cDa, d4, fidx, perm, Xbuf);
    gemm_mfma<<<dim3(NCOL / 64, 256 / 64), 256, 0, stream>>>(Mw, Xbuf, biasf, out + B * NKP * 3);
}

// Round 5
// 354.661 us; speedup vs baseline: 1.1880x; 1.0590x over previous
//
#include <hip/hip_runtime.h>
#include <hip/hip_bf16.h>

#define B 4
#define H 480
#define W 640
#define HW (H*W)
#define BHW (B*H*W)
#define NKP 1024
#define THRESH 0.005f
#define CAP 16384
#define NCOL (B*NKP)
#define KTOT 704
#define KPB 4

typedef __attribute__((ext_vector_type(8))) short s8v;
typedef __attribute__((ext_vector_type(4))) float f4v;
typedef struct { float x, y; } __attribute__((aligned(4))) f2u;   // 4B-aligned pair load

__device__ __forceinline__ short f2bf(float f) {
    __hip_bfloat16 h = __float2bfloat16(f);
    return *(short*)&h;
}

__device__ __forceinline__ float max3f(float a, float b, float c) {
    return fmaxf(fmaxf(a, b), c);     // clang fuses to v_max3_f32
}
// 9-wide max as a depth-2 tree of v_max3_f32 (4 instrs vs 8-deep chain)
#define MAX9(A, base, str) \
    max3f(max3f((A)[(base)], (A)[(base)+(str)], (A)[(base)+2*(str)]), \
          max3f((A)[(base)+3*(str)], (A)[(base)+4*(str)], (A)[(base)+5*(str)]), \
          max3f((A)[(base)+6*(str)], (A)[(base)+7*(str)], (A)[(base)+8*(str)]))

// ================= fused weights + bias + counter zero (Mw bf16) =================
__global__ void fuse_all(const float* __restrict__ merge_w, const float* __restrict__ merge_b,
                         const float* __restrict__ lin0_w, const float* __restrict__ lin0_b,
                         const float* __restrict__ lin1_w, const float* __restrict__ lin1_b,
                         const float* __restrict__ lin2_w, const float* __restrict__ lin2_b,
                         short* __restrict__ Mw, float* __restrict__ biasf, int* __restrict__ cnt) {
    if (blockIdx.x == 704) {
        int o = threadIdx.x;
        if (o < 4) cnt[o * 64] = 0;
        float acc = merge_b[o];
        for (int k = 0; k < 64; ++k)  acc += merge_w[o * KTOT + k] * lin2_b[k];
        for (int k = 0; k < 128; ++k) acc += merge_w[o * KTOT + 64 + k] * lin1_b[k];
        for (int k = 0; k < 256; ++k) acc += merge_w[o * KTOT + 448 + k] * lin0_b[k];
        biasf[o] = acc;
        return;
    }
    int e = blockIdx.x * 256 + threadIdx.x;
    int o = e / KTOT;
    int j = e - o * KTOT;
    float acc = 0.0f;
    if (j < 64) {
        for (int k = 0; k < 64; ++k) acc += merge_w[o * KTOT + k] * lin2_w[k * 64 + j];
    } else if (j < 192) {
        int jj = j - 64;
        for (int k = 0; k < 128; ++k) acc += merge_w[o * KTOT + 64 + k] * lin1_w[k * 128 + jj];
    } else if (j < 448) {
        acc = merge_w[o * KTOT + j];
    } else {
        int jj = j - 448;
        for (int k = 0; k < 256; ++k) acc += merge_w[o * KTOT + 448 + k] * lin0_w[k * 256 + jj];
    }
    Mw[o * KTOT + j] = f2bf(acc);
}

// ================= NMS stage 1: mask0 = (S == pool9(S)) =================
__global__ __launch_bounds__(256) void nms1(const float* __restrict__ scores,
                                            float* __restrict__ mask) {
    __shared__ float tile[40][40];
    __shared__ float hm[40][32];
    int bz = blockIdx.z;
    int x0 = blockIdx.x * 32, y0 = blockIdx.y * 32;
    const float* sp = scores + bz * HW;
    for (int t = threadIdx.x; t < 1600; t += 256) {
        int ly = t / 40, lx = t - ly * 40;
        int gy = y0 - 4 + ly, gx = x0 - 4 + lx;
        tile[ly][lx] = (gy >= 0 && gy < H && gx >= 0 && gx < W) ? sp[gy * W + gx] : -INFINITY;
    }
    __syncthreads();
    for (int t = threadIdx.x; t < 1280; t += 256) {
        int ly = t >> 5, lx = t & 31;
        hm[ly][lx] = MAX9(&tile[ly][0], lx, 1);
    }
    __syncthreads();
    for (int t = threadIdx.x; t < 1024; t += 256) {
        int ly = t >> 5, lx = t & 31;
        float m = MAX9(&hm[0][0], ly * 32 + lx, 32);
        float s = tile[ly + 4][lx + 4];
        mask[bz * HW + (y0 + ly) * W + x0 + lx] = (s == m) ? 1.0f : 0.0f;
    }
}

// ===== NMS stage 2: remaining 4 pools (2 NMS iterations) fused in LDS + compaction =====
// 512 threads: LDS-limited at 2 blocks/CU either way -> doubles resident waves (8->16/CU)
__global__ __launch_bounds__(512) void nms2_compact(const float* __restrict__ scores,
                                                    const float* __restrict__ mask0,
                                                    unsigned long long* __restrict__ cand,
                                                    int* __restrict__ cnt) {
    __shared__ float Sm[56 * 56];   // S on local [4,60)
    __shared__ float Mm[64 * 64];   // mask on local [0,64)
    __shared__ float Zm[56 * 56];   // Z on local [4,60)
    __shared__ float Tm[64 * 56];   // h-pass temp
    __shared__ int lcnt, gbase;
    int bz = blockIdx.z;
    int x0 = blockIdx.x * 32, y0 = blockIdx.y * 32;
    const float* sp = scores + bz * HW;
    const float* mp = mask0 + bz * HW;
    if (threadIdx.x == 0) lcnt = 0;
    for (int t = threadIdx.x; t < 4096; t += 512) {
        int ly = t >> 6, lx = t & 63;
        int gy = y0 - 16 + ly, gx = x0 - 16 + lx;
        Mm[t] = (gy >= 0 && gy < H && gx >= 0 && gx < W) ? mp[gy * W + gx] : 0.0f;
    }
    for (int t = threadIdx.x; t < 3136; t += 512) {
        int i = t / 56, j = t - i * 56;
        int gy = y0 - 12 + i, gx = x0 - 12 + j;
        Sm[t] = (gy >= 0 && gy < H && gx >= 0 && gx < W) ? sp[gy * W + gx] : -1.0f;
    }
    __syncthreads();
    for (int t = threadIdx.x; t < 3584; t += 512) {
        int i = t / 56, c = t - i * 56;
        Tm[i * 56 + c] = MAX9(Mm, i * 64 + c, 1);
    }
    __syncthreads();
    for (int t = threadIdx.x; t < 3136; t += 512) {
        int i = t / 56, c = t - i * 56;
        float m = MAX9(Tm, i * 56 + c, 56);
        Zm[t] = (m > 0.0f) ? -1.0f : Sm[t];
    }
    __syncthreads();
    for (int t = threadIdx.x; t < 2688; t += 512) {
        int i = t / 48, c = t - i * 48;
        Tm[i * 56 + c] = MAX9(Zm, i * 56 + c, 1);
    }
    __syncthreads();
    for (int t = threadIdx.x; t < 2304; t += 512) {
        int r = t / 48, c = t - r * 48;
        float m = MAX9(Tm, r * 56 + c, 56);
        float Zc = Zm[(r + 4) * 56 + c + 4];
        int mi = (r + 8) * 64 + c + 8;
        bool nm = (Zc == m) && (Zc >= 0.0f);
        Mm[mi] = (Mm[mi] != 0.0f || nm) ? 1.0f : 0.0f;
    }
    __syncthreads();
    for (int t = threadIdx.x; t < 1920; t += 512) {
        int r = t / 40, c = t - r * 40;
        Tm[r * 56 + c] = MAX9(Mm, (r + 8) * 64 + c + 8, 1);
    }
    __syncthreads();
    for (int t = threadIdx.x; t < 1600; t += 512) {
        int r = t / 40, c = t - r * 40;
        float m = MAX9(Tm, r * 56 + c, 56);
        int zi = (r + 8) * 56 + c + 8;
        Zm[zi] = (m > 0.0f) ? -1.0f : Sm[zi];
    }
    __syncthreads();
    for (int t = threadIdx.x; t < 1280; t += 512) {
        int r = t / 32, c = t & 31;
        Tm[r * 56 + c] = MAX9(Zm, (r + 8) * 56 + c + 8, 1);
    }
    __syncthreads();
    unsigned long long keys[2];
    int nl = 0;
    #pragma unroll
    for (int q = 0; q < 2; ++q) {
        int t = threadIdx.x + q * 512;
        int r3 = t >> 5, c = t & 31;
        float m = MAX9(Tm, r3 * 56 + c, 56);
        float Zc = Zm[(r3 + 12) * 56 + c + 12];
        bool fin = (Mm[(r3 + 16) * 64 + c + 16] != 0.0f) || ((Zc == m) && (Zc >= 0.0f));
        int gy = y0 + r3, gx = x0 + c;
        float sc = Sm[(r3 + 12) * 56 + c + 12];
        if (fin && gy >= 4 && gy < H - 4 && gx >= 4 && gx < W - 4 && sc > THRESH) {
            unsigned r = (unsigned)(gy * W + gx);
            unsigned bits = __float_as_uint(sc) | 0x80000000u;
            keys[nl++] = ((unsigned long long)bits << 32) |
                         (unsigned long long)(0xFFFFFFFFu - r);
        }
    }
    int lpos = 0;
    if (nl) lpos = atomicAdd(&lcnt, nl);
    __syncthreads();
    if (threadIdx.x == 0) gbase = (lcnt > 0) ? atomicAdd(&cnt[bz * 64], lcnt) : 0;
    __syncthreads();
    for (int j = 0; j < nl; ++j) {
        int p = gbase + lpos + j;
        if (p < CAP) cand[(size_t)bz * CAP + p] = keys[j];
    }
}

// ===== topk: TWO-LEVEL histogram select (22-bit prefix) + bitonic; emits spatial perm =====
__global__ __launch_bounds__(1024) void topk(const unsigned long long* __restrict__ cand,
                                             const int* __restrict__ cnt,
                                             float* __restrict__ out, int* __restrict__ fidx,
                                             int* __restrict__ perm) {
    __shared__ int hist[2048];
    __shared__ unsigned long long buf[4096];
    __shared__ int scnt, spiv1, spiv2, sabove;
    int b = blockIdx.x, tid = threadIdx.x;
    int m = cnt[b * 64]; if (m > CAP) m = CAP;
    const unsigned long long* cb = cand + (size_t)b * CAP;
    int target = (m < 1024) ? m : 1024;

    hist[tid] = 0; hist[tid + 1024] = 0;
    if (tid == 0) { scnt = 0; spiv1 = 2048; spiv2 = 0; sabove = 0; }
    __syncthreads();
    for (int i = tid; i < m; i += 1024)
        atomicAdd(&hist[(int)(cb[i] >> 53) & 0x7FF], 1);
    __syncthreads();
    for (int d = 1; d < 2048; d <<= 1) {
        int v0 = hist[tid] + ((tid + d < 2048) ? hist[tid + d] : 0);
        int v1 = hist[tid + 1024] + ((tid + 1024 + d < 2048) ? hist[tid + 1024 + d] : 0);
        __syncthreads();
        hist[tid] = v0; hist[tid + 1024] = v1;
        __syncthreads();
    }
    if (target > 0) {
        for (int t = tid; t < 2048; t += 1024) {
            int c = hist[t];
            int cn = (t < 2047) ? hist[t + 1] : 0;
            if (c >= target && cn < target) { spiv1 = t; sabove = cn; }
        }
    }
    __syncthreads();
    int piv1 = spiv1;
    int target2 = target - sabove;
    hist[tid] = 0; hist[tid + 1024] = 0;
    __syncthreads();
    for (int i = tid; i < m; i += 1024) {
        unsigned long long k = cb[i];
        if (((int)(k >> 53) & 0x7FF) == piv1)
            atomicAdd(&hist[(int)(k >> 42) & 0x7FF], 1);
    }
    __syncthreads();
    for (int d = 1; d < 2048; d <<= 1) {
        int v0 = hist[tid] + ((tid + d < 2048) ? hist[tid + d] : 0);
        int v1 = hist[tid + 1024] + ((tid + 1024 + d < 2048) ? hist[tid + 1024 + d] : 0);
        __syncthreads();
        hist[tid] = v0; hist[tid + 1024] = v1;
        __syncthreads();
    }
    if (target > 0) {
        for (int t = tid; t < 2048; t += 1024) {
            int c = hist[t];
            int cn = (t < 2047) ? hist[t + 1] : 0;
            if (c >= target2 && cn < target2) spiv2 = t;
        }
    }
    __syncthreads();
    int piv2 = spiv2;
    for (int i = tid; i < m; i += 1024) {
        unsigned long long k = cb[i];
        int b1 = (int)(k >> 53) & 0x7FF;
        bool sel = (target > 0) &&
                   (b1 > piv1 || (b1 == piv1 && (((int)(k >> 42) & 0x7FF) >= piv2)));
        if (sel) {
            int p = atomicAdd(&scnt, 1);
            if (p < 4096) buf[p] = k;
        }
    }
    __syncthreads();
    int sc_ = scnt; if (sc_ > 4096) sc_ = 4096;
    int ns = 1024; while (ns < sc_) ns <<= 1;
    for (int t = tid; t < ns; t += 1024) if (t >= sc_) buf[t] = 0ULL;
    __syncthreads();
    for (int k = 2; k <= ns; k <<= 1)
        for (int j = k >> 1; j > 0; j >>= 1) {
            __syncthreads();
            for (int t = tid; t < ns; t += 1024) {
                int ixj = t ^ j;
                if (ixj > t) {
                    unsigned long long a = buf[t], bb = buf[ixj];
                    if (((t & k) == 0) ? (a < bb) : (a > bb)) { buf[t] = bb; buf[ixj] = a; }
                }
            }
        }
    __syncthreads();
    unsigned long long key = buf[tid];
    float kx, ky, sc;
    unsigned idx;
    if (key != 0ULL) {
        unsigned ord = (unsigned)(key >> 32);
        sc = __uint_as_float(ord ^ 0x80000000u);
        idx = 0xFFFFFFFFu - (unsigned)(key & 0xFFFFFFFFu);
        kx = (float)(idx % W);
        ky = (float)(idx / W);
    } else {
        sc = -1.0f; idx = 0; kx = 0.0f; ky = 0.0f;
    }
    int bn = b * NKP + tid;
    out[bn * 2 + 0] = kx;
    out[bn * 2 + 1] = ky;
    out[B * NKP * 2 + bn] = sc;
    fidx[bn] = (int)idx;
    __syncthreads();
    unsigned* b32 = (unsigned*)buf;
    b32[tid] = (idx << 10) | (unsigned)tid;
    for (int k = 2; k <= 1024; k <<= 1)
        for (int j = k >> 1; j > 0; j >>= 1) {
            __syncthreads();
            int ixj = tid ^ j;
            if (ixj > tid) {
                unsigned a = b32[tid], bb = b32[ixj];
                if (((tid & k) == 0) ? (a > bb) : (a < bb)) { b32[tid] = bb; b32[ixj] = a; }
            }
        }
    __syncthreads();
    perm[b * NKP + tid] = (int)(b32[tid] & 1023u);
}

// ===== fused descriptor sampling; KPB kp/block; XCD-swizzled block order =====
__global__ __launch_bounds__(704) void sample_all(const float* __restrict__ d1,
                                                  const float* __restrict__ d2,
                                                  const float* __restrict__ cDa,
                                                  const float* __restrict__ d4,
                                                  const int* __restrict__ fidx,
                                                  const int* __restrict__ perm,
                                                  short* __restrict__ X) {
    __shared__ float ssum[KPB][12];
    int c = threadIdx.x;
    int wid = c >> 6, lane = c & 63;
    // XCD-aware swizzle: 1024 blocks, 8 XCDs -> each XCD owns 128 CONTIGUOUS
    // spatially-sorted 4-kp chunks, so row-line reuse stays inside one L2.
    int bid = blockIdx.x;
    int swz = ((bid & 7) << 7) | (bid >> 3);
    int b = swz >> 8;                 // 256 chunks per batch
    int g0 = (swz & 255) * KPB;

    const float* map; int h, w, s, C, cl;
    if (c < 64)       { map = d1;  h = 240; w = 320; s = 2;  cl = c;       C = 64; }
    else if (c < 192) { map = d2;  h = 120; w = 160; s = 4;  cl = c - 64;  C = 128; }
    else if (c < 448) { map = cDa; h = 60;  w = 80;  s = 8;  cl = c - 192; C = 256; }
    else              { map = d4;  h = 30;  w = 40;  s = 16; cl = c - 448; C = 256; }
    const float* plane = map + ((size_t)(b * C + cl)) * (h * w);

    int cols[KPB];
    float vals[KPB];
    float q0x[KPB], q0y[KPB], q1x[KPB], q1y[KPB];
    float ax[KPB], ay[KPB], bx[KPB], by[KPB];

    #pragma unroll
    for (int k = 0; k < KPB; ++k) {
        int col = (b << 10) | perm[(b << 10) + g0 + k];
        cols[k] = col;
        int idx = fidx[col];
        float kx = (float)(idx % W);
        float ky = (float)(idx / W);
        float kxs = kx - (float)s * 0.5f + 0.5f;
        float kys = ky - (float)s * 0.5f + 0.5f;
        float gx = kxs / (float)(w * s - 1) * 2.0f - 1.0f;
        float gy = kys / (float)(h * s - 1) * 2.0f - 1.0f;
        float x = (gx + 1.0f) * 0.5f * (float)(w - 1);
        float y = (gy + 1.0f) * 0.5f * (float)(h - 1);
        float x0f = floorf(x), y0f = floorf(y);
        int x0 = (int)x0f, y0 = (int)y0f;
        float wx1 = x - x0f, wy1 = y - y0f;
        float wx0 = 1.0f - wx1, wy0 = 1.0f - wy1;
        bool vx0 = (x0 >= 0) && (x0 < w);
        bool vx1 = (x0 + 1 >= 0) && (x0 + 1 < w);
        bool vy0 = (y0 >= 0) && (y0 < h);
        bool vy1 = (y0 + 1 >= 0) && (y0 + 1 < h);
        int xc0 = min(max(x0, 0), w - 1), xc1 = min(max(x0 + 1, 0), w - 1);
        int yc0 = min(max(y0, 0), h - 1), yc1 = min(max(y0 + 1, 0), h - 1);
        float w00 = (vx0 && vy0) ? wx0 * wy0 : 0.0f;
        float w01 = (vx1 && vy0) ? wx1 * wy0 : 0.0f;
        float w10 = (vx0 && vy1) ? wx0 * wy1 : 0.0f;
        float w11 = (vx1 && vy1) ? wx1 * wy1 : 0.0f;
        int xb = min(xc0, w - 2);
        float s0 = (xc0 == xb) ? 1.0f : 0.0f;
        float s1 = (xc1 == xb) ? 1.0f : 0.0f;
        ax[k] = w00 * s0 + w01 * s1;
        ay[k] = w00 * (1.0f - s0) + w01 * (1.0f - s1);
        bx[k] = w10 * s0 + w11 * s1;
        by[k] = w10 * (1.0f - s0) + w11 * (1.0f - s1);
        f2u q0 = *(const f2u*)(plane + yc0 * w + xb);
        f2u q1 = *(const f2u*)(plane + yc1 * w + xb);
        q0x[k] = q0.x; q0y[k] = q0.y;
        q1x[k] = q1.x; q1y[k] = q1.y;
    }
    #pragma unroll
    for (int k = 0; k < KPB; ++k)
        vals[k] = q0x[k] * ax[k] + q0y[k] * ay[k] + q1x[k] * bx[k] + q1y[k] * by[k];

    #pragma unroll
    for (int k = 0; k < KPB; ++k) {
        float r = vals[k] * vals[k];
        #pragma unroll
        for (int off = 32; off > 0; off >>= 1) r += __shfl_xor(r, off, 64);
        if (lane == 0) ssum[k][wid] = r;
    }
    __syncthreads();
    int wbeg, wcnt;
    if (c < 64)       { wbeg = 0; wcnt = 1; }
    else if (c < 192) { wbeg = 1; wcnt = 2; }
    else if (c < 448) { wbeg = 3; wcnt = 4; }
    else              { wbeg = 7; wcnt = 4; }
    #pragma unroll
    for (int k = 0; k < KPB; ++k) {
        float sum = 0.0f;
        for (int t = 0; t < wcnt; ++t) sum += ssum[k][wbeg + t];
        float denom = fmaxf(sqrtf(sum), 1e-12f);
        X[(size_t)cols[k] * KTOT + c] = f2bf(vals[k] / denom);
    }
}

// ===== GEMM (bf16 MFMA): out[256,4096] = Mw[256,704] * X^T + bias; bf16 inputs =====
__global__ __launch_bounds__(256) void gemm_mfma(const short* __restrict__ Mw,
                                                 const short* __restrict__ X,
                                                 const float* __restrict__ biasf,
                                                 float* __restrict__ out) {
    __shared__ short As[64 * 72];
    __shared__ short Bs[64 * 72];
    int tid = threadIdx.x;
    int lane = tid & 63, w = tid >> 6;
    int r = lane & 15, quad = lane >> 4;
    int rowBase = blockIdx.y * 64, colBase = blockIdx.x * 64;
    int sm = tid >> 2, skq = (tid & 3) << 4;   // 16 shorts (32B) per thread per tile

    const short* pa = Mw + (size_t)(rowBase + sm) * KTOT + skq;
    const short* pb = X + (size_t)(colBase + sm) * KTOT + skq;
    s8v a0 = *(const s8v*)(pa), a1 = *(const s8v*)(pa + 8);
    s8v b0 = *(const s8v*)(pb), b1 = *(const s8v*)(pb + 8);

    f4v acc[4];
    #pragma unroll
    for (int t = 0; t < 4; ++t) acc[t] = (f4v)0.0f;

    for (int kt = 0; kt < 11; ++kt) {
        __syncthreads();
        *(s8v*)&As[sm * 72 + skq + 0] = a0;
        *(s8v*)&As[sm * 72 + skq + 8] = a1;
        *(s8v*)&Bs[sm * 72 + skq + 0] = b0;
        *(s8v*)&Bs[sm * 72 + skq + 8] = b1;
        __syncthreads();
        if (kt < 10) {
            pa += 64; pb += 64;
            a0 = *(const s8v*)(pa); a1 = *(const s8v*)(pa + 8);
            b0 = *(const s8v*)(pb); b1 = *(const s8v*)(pb + 8);
        }
        #pragma unroll
        for (int kk = 0; kk < 2; ++kk) {
            int aoff = (w * 16 + r) * 72 + kk * 32 + quad * 8;
            s8v af = *(const s8v*)&As[aoff];
            #pragma unroll
            for (int t = 0; t < 4; ++t) {
                int boff = (t * 16 + r) * 72 + kk * 32 + quad * 8;
                s8v bf = *(const s8v*)&Bs[boff];
                acc[t] = __builtin_amdgcn_mfma_f32_16x16x32_bf16(af, bf, acc[t], 0, 0, 0);
            }
        }
    }
    #pragma unroll
    for (int t = 0; t < 4; ++t) {
        int colg = colBase + t * 16 + r;
        size_t obase = (size_t)(colg >> 10) * (256 * NKP) + (size_t)(colg & 1023);
        #pragma unroll
        for (int reg = 0; reg < 4; ++reg) {
            int row = rowBase + w * 16 + quad * 4 + reg;
            out[obase + (size_t)row * NKP] = acc[t][reg] + biasf[row];
        }
    }
}

// ================= launch =================
extern "C" void kernel_launch(void* const* d_in, const int* in_sizes, int n_in,
                              void* d_out, int out_size, void* d_ws, size_t ws_size,
                              hipStream_t stream) {
    const float* scores  = (const float*)d_in[0];
    const float* d1      = (const float*)d_in[1];
    const float* d2      = (const float*)d_in[2];
    const float* cDa     = (const float*)d_in[3];
    const float* d4      = (const float*)d_in[4];
    const float* lin0_w  = (const float*)d_in[5];
    const float* lin0_b  = (const float*)d_in[6];
    const float* lin1_w  = (const float*)d_in[7];
    const float* lin1_b  = (const float*)d_in[8];
    const float* lin2_w  = (const float*)d_in[9];
    const float* lin2_b  = (const float*)d_in[10];
    const float* merge_w = (const float*)d_in[11];
    const float* merge_b = (const float*)d_in[12];
    float* out = (float*)d_out;

    char* ws = (char*)d_ws;
    float* MASK = (float*)ws;                                          // BHW floats (nms phase)
    short* Xbuf = (short*)ws;                                          // aliases (post-topk); 5.77 MB
    unsigned long long* cand  = (unsigned long long*)(ws + 14745600);  // 524,288 B
    int* cnt                  = (int*)(ws + 15269888);                 // 1,024 B
    int* fidx                 = (int*)(ws + 15401984);                 // 16,384 B
    short* Mw                 = (short*)(ws + 15418368);               // 360,448 B (bf16)
    float* biasf              = (float*)(ws + 16139264);               // 1,024 B
    int* perm                 = (int*)(ws + 16140288);                 // 16,384 B

    dim3 tgrid(W / 32, H / 32, B);   // (20,15,4)

    fuse_all<<<705, 256, 0, stream>>>(merge_w, merge_b, lin0_w, lin0_b, lin1_w, lin1_b,
                                      lin2_w, lin2_b, Mw, biasf, cnt);
    nms1<<<tgrid, 256, 0, stream>>>(scores, MASK);
    nms2_compact<<<tgrid, 512, 0, stream>>>(scores, MASK, cand, cnt);
    topk<<<B, 1024, 0, stream>>>(cand, cnt, out, fidx, perm);
    sample_all<<<(B * NKP) / KPB, KTOT, 0, stream>>>(d1, d2, cDa, d4, fidx, perm, Xbuf);
    gemm_mfma<<<dim3(NCOL / 64, 256 / 64), 256, 0, stream>>>(Mw, Xbuf, biasf, out + B * NKP * 3);
}

// Round 6
// 353.429 us; speedup vs baseline: 1.1922x; 1.0035x over previous
//
#include <hip/hip_runtime.h>
#include <hip/hip_bf16.h>

#define B 4
#define H 480
#define W 640
#define HW (H*W)
#define BHW (B*H*W)
#define NKP 1024
#define THRESH 0.005f
#define CAP 16384
#define NCOL (B*NKP)
#define KTOT 704

typedef __attribute__((ext_vector_type(8))) short s8v;
typedef __attribute__((ext_vector_type(4))) float f4v;
typedef struct { float x, y; } __attribute__((aligned(4))) f2u;   // 4B-aligned pair load

__device__ __forceinline__ short f2bf(float f) {
    __hip_bfloat16 h = __float2bfloat16(f);
    return *(short*)&h;
}

__device__ __forceinline__ float max3f(float a, float b, float c) {
    return fmaxf(fmaxf(a, b), c);     // clang fuses to v_max3_f32
}
// 9-wide max as a depth-2 tree of v_max3_f32 (4 instrs vs 8-deep chain)
#define MAX9(A, base, str) \
    max3f(max3f((A)[(base)], (A)[(base)+(str)], (A)[(base)+2*(str)]), \
          max3f((A)[(base)+3*(str)], (A)[(base)+4*(str)], (A)[(base)+5*(str)]), \
          max3f((A)[(base)+6*(str)], (A)[(base)+7*(str)], (A)[(base)+8*(str)]))

// ================= fused weights + bias + counter zero (Mw bf16) =================
__global__ void fuse_all(const float* __restrict__ merge_w, const float* __restrict__ merge_b,
                         const float* __restrict__ lin0_w, const float* __restrict__ lin0_b,
                         const float* __restrict__ lin1_w, const float* __restrict__ lin1_b,
                         const float* __restrict__ lin2_w, const float* __restrict__ lin2_b,
                         short* __restrict__ Mw, float* __restrict__ biasf, int* __restrict__ cnt) {
    if (blockIdx.x == 704) {
        int o = threadIdx.x;
        if (o < 4) cnt[o * 64] = 0;
        float acc = merge_b[o];
        for (int k = 0; k < 64; ++k)  acc += merge_w[o * KTOT + k] * lin2_b[k];
        for (int k = 0; k < 128; ++k) acc += merge_w[o * KTOT + 64 + k] * lin1_b[k];
        for (int k = 0; k < 256; ++k) acc += merge_w[o * KTOT + 448 + k] * lin0_b[k];
        biasf[o] = acc;
        return;
    }
    int e = blockIdx.x * 256 + threadIdx.x;
    int o = e / KTOT;
    int j = e - o * KTOT;
    float acc = 0.0f;
    if (j < 64) {
        for (int k = 0; k < 64; ++k) acc += merge_w[o * KTOT + k] * lin2_w[k * 64 + j];
    } else if (j < 192) {
        int jj = j - 64;
        for (int k = 0; k < 128; ++k) acc += merge_w[o * KTOT + 64 + k] * lin1_w[k * 128 + jj];
    } else if (j < 448) {
        acc = merge_w[o * KTOT + j];
    } else {
        int jj = j - 448;
        for (int k = 0; k < 256; ++k) acc += merge_w[o * KTOT + 448 + k] * lin0_w[k * 256 + jj];
    }
    Mw[o * KTOT + j] = f2bf(acc);
}

// ================= NMS stage 1: mask0 = (S == pool9(S)) =================
__global__ __launch_bounds__(256) void nms1(const float* __restrict__ scores,
                                            float* __restrict__ mask) {
    __shared__ float tile[40][40];
    __shared__ float hm[40][32];
    int bz = blockIdx.z;
    int x0 = blockIdx.x * 32, y0 = blockIdx.y * 32;
    const float* sp = scores + bz * HW;
    for (int t = threadIdx.x; t < 1600; t += 256) {
        int ly = t / 40, lx = t - ly * 40;
        int gy = y0 - 4 + ly, gx = x0 - 4 + lx;
        tile[ly][lx] = (gy >= 0 && gy < H && gx >= 0 && gx < W) ? sp[gy * W + gx] : -INFINITY;
    }
    __syncthreads();
    for (int t = threadIdx.x; t < 1280; t += 256) {
        int ly = t >> 5, lx = t & 31;
        hm[ly][lx] = MAX9(&tile[ly][0], lx, 1);
    }
    __syncthreads();
    for (int t = threadIdx.x; t < 1024; t += 256) {
        int ly = t >> 5, lx = t & 31;
        float m = MAX9(&hm[0][0], ly * 32 + lx, 32);
        float s = tile[ly + 4][lx + 4];
        mask[bz * HW + (y0 + ly) * W + x0 + lx] = (s == m) ? 1.0f : 0.0f;
    }
}

// ===== NMS stage 2: remaining 4 pools (2 NMS iterations) fused in LDS + compaction =====
__global__ __launch_bounds__(512) void nms2_compact(const float* __restrict__ scores,
                                                    const float* __restrict__ mask0,
                                                    unsigned long long* __restrict__ cand,
                                                    int* __restrict__ cnt) {
    __shared__ float Sm[56 * 56];   // S on local [4,60)
    __shared__ float Mm[64 * 64];   // mask on local [0,64)
    __shared__ float Zm[56 * 56];   // Z on local [4,60)
    __shared__ float Tm[64 * 56];   // h-pass temp
    __shared__ int lcnt, gbase;
    int bz = blockIdx.z;
    int x0 = blockIdx.x * 32, y0 = blockIdx.y * 32;
    const float* sp = scores + bz * HW;
    const float* mp = mask0 + bz * HW;
    if (threadIdx.x == 0) lcnt = 0;
    for (int t = threadIdx.x; t < 4096; t += 512) {
        int ly = t >> 6, lx = t & 63;
        int gy = y0 - 16 + ly, gx = x0 - 16 + lx;
        Mm[t] = (gy >= 0 && gy < H && gx >= 0 && gx < W) ? mp[gy * W + gx] : 0.0f;
    }
    for (int t = threadIdx.x; t < 3136; t += 512) {
        int i = t / 56, j = t - i * 56;
        int gy = y0 - 12 + i, gx = x0 - 12 + j;
        Sm[t] = (gy >= 0 && gy < H && gx >= 0 && gx < W) ? sp[gy * W + gx] : -1.0f;
    }
    __syncthreads();
    for (int t = threadIdx.x; t < 3584; t += 512) {
        int i = t / 56, c = t - i * 56;
        Tm[i * 56 + c] = MAX9(Mm, i * 64 + c, 1);
    }
    __syncthreads();
    for (int t = threadIdx.x; t < 3136; t += 512) {
        int i = t / 56, c = t - i * 56;
        float m = MAX9(Tm, i * 56 + c, 56);
        Zm[t] = (m > 0.0f) ? -1.0f : Sm[t];
    }
    __syncthreads();
    for (int t = threadIdx.x; t < 2688; t += 512) {
        int i = t / 48, c = t - i * 48;
        Tm[i * 56 + c] = MAX9(Zm, i * 56 + c, 1);
    }
    __syncthreads();
    for (int t = threadIdx.x; t < 2304; t += 512) {
        int r = t / 48, c = t - r * 48;
        float m = MAX9(Tm, r * 56 + c, 56);
        float Zc = Zm[(r + 4) * 56 + c + 4];
        int mi = (r + 8) * 64 + c + 8;
        bool nm = (Zc == m) && (Zc >= 0.0f);
        Mm[mi] = (Mm[mi] != 0.0f || nm) ? 1.0f : 0.0f;
    }
    __syncthreads();
    for (int t = threadIdx.x; t < 1920; t += 512) {
        int r = t / 40, c = t - r * 40;
        Tm[r * 56 + c] = MAX9(Mm, (r + 8) * 64 + c + 8, 1);
    }
    __syncthreads();
    for (int t = threadIdx.x; t < 1600; t += 512) {
        int r = t / 40, c = t - r * 40;
        float m = MAX9(Tm, r * 56 + c, 56);
        int zi = (r + 8) * 56 + c + 8;
        Zm[zi] = (m > 0.0f) ? -1.0f : Sm[zi];
    }
    __syncthreads();
    for (int t = threadIdx.x; t < 1280; t += 512) {
        int r = t / 32, c = t & 31;
        Tm[r * 56 + c] = MAX9(Zm, (r + 8) * 56 + c + 8, 1);
    }
    __syncthreads();
    unsigned long long keys[2];
    int nl = 0;
    #pragma unroll
    for (int q = 0; q < 2; ++q) {
        int t = threadIdx.x + q * 512;
        int r3 = t >> 5, c = t & 31;
        float m = MAX9(Tm, r3 * 56 + c, 56);
        float Zc = Zm[(r3 + 12) * 56 + c + 12];
        bool fin = (Mm[(r3 + 16) * 64 + c + 16] != 0.0f) || ((Zc == m) && (Zc >= 0.0f));
        int gy = y0 + r3, gx = x0 + c;
        float sc = Sm[(r3 + 12) * 56 + c + 12];
        if (fin && gy >= 4 && gy < H - 4 && gx >= 4 && gx < W - 4 && sc > THRESH) {
            unsigned r = (unsigned)(gy * W + gx);
            unsigned bits = __float_as_uint(sc) | 0x80000000u;
            keys[nl++] = ((unsigned long long)bits << 32) |
                         (unsigned long long)(0xFFFFFFFFu - r);
        }
    }
    int lpos = 0;
    if (nl) lpos = atomicAdd(&lcnt, nl);
    __syncthreads();
    if (threadIdx.x == 0) gbase = (lcnt > 0) ? atomicAdd(&cnt[bz * 64], lcnt) : 0;
    __syncthreads();
    for (int j = 0; j < nl; ++j) {
        int p = gbase + lpos + j;
        if (p < CAP) cand[(size_t)bz * CAP + p] = keys[j];
    }
}

// ===== topk: TWO-LEVEL histogram select (22-bit prefix) + bitonic; emits spatial perm =====
__global__ __launch_bounds__(1024) void topk(const unsigned long long* __restrict__ cand,
                                             const int* __restrict__ cnt,
                                             float* __restrict__ out, int* __restrict__ fidx,
                                             int* __restrict__ perm) {
    __shared__ int hist[2048];
    __shared__ unsigned long long buf[4096];
    __shared__ int scnt, spiv1, spiv2, sabove;
    int b = blockIdx.x, tid = threadIdx.x;
    int m = cnt[b * 64]; if (m > CAP) m = CAP;
    const unsigned long long* cb = cand + (size_t)b * CAP;
    int target = (m < 1024) ? m : 1024;

    hist[tid] = 0; hist[tid + 1024] = 0;
    if (tid == 0) { scnt = 0; spiv1 = 2048; spiv2 = 0; sabove = 0; }
    __syncthreads();
    for (int i = tid; i < m; i += 1024)
        atomicAdd(&hist[(int)(cb[i] >> 53) & 0x7FF], 1);
    __syncthreads();
    for (int d = 1; d < 2048; d <<= 1) {
        int v0 = hist[tid] + ((tid + d < 2048) ? hist[tid + d] : 0);
        int v1 = hist[tid + 1024] + ((tid + 1024 + d < 2048) ? hist[tid + 1024 + d] : 0);
        __syncthreads();
        hist[tid] = v0; hist[tid + 1024] = v1;
        __syncthreads();
    }
    if (target > 0) {
        for (int t = tid; t < 2048; t += 1024) {
            int c = hist[t];
            int cn = (t < 2047) ? hist[t + 1] : 0;
            if (c >= target && cn < target) { spiv1 = t; sabove = cn; }
        }
    }
    __syncthreads();
    int piv1 = spiv1;
    int target2 = target - sabove;
    hist[tid] = 0; hist[tid + 1024] = 0;
    __syncthreads();
    for (int i = tid; i < m; i += 1024) {
        unsigned long long k = cb[i];
        if (((int)(k >> 53) & 0x7FF) == piv1)
            atomicAdd(&hist[(int)(k >> 42) & 0x7FF], 1);
    }
    __syncthreads();
    for (int d = 1; d < 2048; d <<= 1) {
        int v0 = hist[tid] + ((tid + d < 2048) ? hist[tid + d] : 0);
        int v1 = hist[tid + 1024] + ((tid + 1024 + d < 2048) ? hist[tid + 1024 + d] : 0);
        __syncthreads();
        hist[tid] = v0; hist[tid + 1024] = v1;
        __syncthreads();
    }
    if (target > 0) {
        for (int t = tid; t < 2048; t += 1024) {
            int c = hist[t];
            int cn = (t < 2047) ? hist[t + 1] : 0;
            if (c >= target2 && cn < target2) spiv2 = t;
        }
    }
    __syncthreads();
    int piv2 = spiv2;
    for (int i = tid; i < m; i += 1024) {
        unsigned long long k = cb[i];
        int b1 = (int)(k >> 53) & 0x7FF;
        bool sel = (target > 0) &&
                   (b1 > piv1 || (b1 == piv1 && (((int)(k >> 42) & 0x7FF) >= piv2)));
        if (sel) {
            int p = atomicAdd(&scnt, 1);
            if (p < 4096) buf[p] = k;
        }
    }
    __syncthreads();
    int sc_ = scnt; if (sc_ > 4096) sc_ = 4096;
    int ns = 1024; while (ns < sc_) ns <<= 1;
    for (int t = tid; t < ns; t += 1024) if (t >= sc_) buf[t] = 0ULL;
    __syncthreads();
    for (int k = 2; k <= ns; k <<= 1)
        for (int j = k >> 1; j > 0; j >>= 1) {
            __syncthreads();
            for (int t = tid; t < ns; t += 1024) {
                int ixj = t ^ j;
                if (ixj > t) {
                    unsigned long long a = buf[t], bb = buf[ixj];
                    if (((t & k) == 0) ? (a < bb) : (a > bb)) { buf[t] = bb; buf[ixj] = a; }
                }
            }
        }
    __syncthreads();
    unsigned long long key = buf[tid];
    float kx, ky, sc;
    unsigned idx;
    if (key != 0ULL) {
        unsigned ord = (unsigned)(key >> 32);
        sc = __uint_as_float(ord ^ 0x80000000u);
        idx = 0xFFFFFFFFu - (unsigned)(key & 0xFFFFFFFFu);
        kx = (float)(idx % W);
        ky = (float)(idx / W);
    } else {
        sc = -1.0f; idx = 0; kx = 0.0f; ky = 0.0f;
    }
    int bn = b * NKP + tid;
    out[bn * 2 + 0] = kx;
    out[bn * 2 + 1] = ky;
    out[B * NKP * 2 + bn] = sc;
    fidx[bn] = (int)idx;
    __syncthreads();
    unsigned* b32 = (unsigned*)buf;
    b32[tid] = (idx << 10) | (unsigned)tid;
    for (int k = 2; k <= 1024; k <<= 1)
        for (int j = k >> 1; j > 0; j >>= 1) {
            __syncthreads();
            int ixj = tid ^ j;
            if (ixj > tid) {
                unsigned a = b32[tid], bb = b32[ixj];
                if (((tid & k) == 0) ? (a > bb) : (a < bb)) { b32[tid] = bb; b32[ixj] = a; }
            }
        }
    __syncthreads();
    perm[b * NKP + tid] = (int)(b32[tid] & 1023u);
}

// ===== sample_all: wave-per-keypoint, barrier-free, XCD-swizzled =====
// grid = (1024 kp-chunks, 4 segments); block = 256 = 4 waves; wave w -> kp chunk*4+w.
// Lane owns C/64 channels (1/2/4/4); L2-norm is a pure in-wave shuffle tree.
__global__ __launch_bounds__(256) void sample_all(const float* __restrict__ d1,
                                                  const float* __restrict__ d2,
                                                  const float* __restrict__ cDa,
                                                  const float* __restrict__ d4,
                                                  const int* __restrict__ fidx,
                                                  const int* __restrict__ perm,
                                                  short* __restrict__ X) {
    int lane = threadIdx.x & 63;
    int wv = threadIdx.x >> 6;
    int seg = blockIdx.y;
    // XCD swizzle on chunk index (1024 % 8 == 0 -> bijective): each XCD owns
    // 128 contiguous spatially-sorted chunks per segment pass.
    int bid = blockIdx.x;
    int swz = ((bid & 7) << 7) | (bid >> 3);
    int b = swz >> 8;                  // 256 chunks per batch
    int g0 = ((swz & 255) << 2) + wv;  // kp slot within batch

    const float* map; int h, w, s, C, base, nset;
    if (seg == 0)      { map = d1;  h = 240; w = 320; s = 2;  C = 64;  base = 0;   nset = 1; }
    else if (seg == 1) { map = d2;  h = 120; w = 160; s = 4;  C = 128; base = 64;  nset = 2; }
    else if (seg == 2) { map = cDa; h = 60;  w = 80;  s = 8;  C = 256; base = 192; nset = 4; }
    else               { map = d4;  h = 30;  w = 40;  s = 16; C = 256; base = 448; nset = 4; }

    int col = (b << 10) | perm[(b << 10) + g0];
    int idx = fidx[col];
    float kx = (float)(idx % W);
    float ky = (float)(idx / W);
    float kxs = kx - (float)s * 0.5f + 0.5f;
    float kys = ky - (float)s * 0.5f + 0.5f;
    float gx = kxs / (float)(w * s - 1) * 2.0f - 1.0f;
    float gy = kys / (float)(h * s - 1) * 2.0f - 1.0f;
    float x = (gx + 1.0f) * 0.5f * (float)(w - 1);
    float y = (gy + 1.0f) * 0.5f * (float)(h - 1);
    float x0f = floorf(x), y0f = floorf(y);
    int x0 = (int)x0f, y0 = (int)y0f;
    float wx1 = x - x0f, wy1 = y - y0f;
    float wx0 = 1.0f - wx1, wy0 = 1.0f - wy1;
    bool vx0 = (x0 >= 0) && (x0 < w);
    bool vx1 = (x0 + 1 >= 0) && (x0 + 1 < w);
    bool vy0 = (y0 >= 0) && (y0 < h);
    bool vy1 = (y0 + 1 >= 0) && (y0 + 1 < h);
    int xc0 = min(max(x0, 0), w - 1), xc1 = min(max(x0 + 1, 0), w - 1);
    int yc0 = min(max(y0, 0), h - 1), yc1 = min(max(y0 + 1, 0), h - 1);
    float w00 = (vx0 && vy0) ? wx0 * wy0 : 0.0f;
    float w01 = (vx1 && vy0) ? wx1 * wy0 : 0.0f;
    float w10 = (vx0 && vy1) ? wx0 * wy1 : 0.0f;
    float w11 = (vx1 && vy1) ? wx1 * wy1 : 0.0f;
    int xb = min(xc0, w - 2);
    float s0 = (xc0 == xb) ? 1.0f : 0.0f;
    float s1 = (xc1 == xb) ? 1.0f : 0.0f;
    float ax = w00 * s0 + w01 * s1;
    float ay = w00 * (1.0f - s0) + w01 * (1.0f - s1);
    float bx = w10 * s0 + w11 * s1;
    float by = w10 * (1.0f - s0) + w11 * (1.0f - s1);

    size_t hw = (size_t)(h * w);
    const float* pb = map + ((size_t)b * C + lane) * hw;
    size_t off0 = (size_t)yc0 * w + xb;
    size_t off1 = (size_t)yc1 * w + xb;
    size_t cstr = hw << 6;   // 64 channel-planes

    f2u q0[4], q1[4];
    #pragma unroll
    for (int j = 0; j < 4; ++j) {
        if (j < nset) {
            const float* p = pb + (size_t)j * cstr;
            q0[j] = *(const f2u*)(p + off0);
            q1[j] = *(const f2u*)(p + off1);
        }
    }
    float vals[4];
    float r = 0.0f;
    #pragma unroll
    for (int j = 0; j < 4; ++j) {
        if (j < nset) {
            vals[j] = q0[j].x * ax + q0[j].y * ay + q1[j].x * bx + q1[j].y * by;
            r += vals[j] * vals[j];
        }
    }
    #pragma unroll
    for (int off = 32; off > 0; off >>= 1) r += __shfl_xor(r, off, 64);
    float denom = fmaxf(sqrtf(r), 1e-12f);
    float inv = 1.0f / denom;
    short* xp = X + (size_t)col * KTOT + base + lane;
    #pragma unroll
    for (int j = 0; j < 4; ++j) {
        if (j < nset) xp[j * 64] = f2bf(vals[j] * inv);
    }
}

// ===== GEMM (bf16 MFMA): out[256,4096] = Mw[256,704] * X^T + bias; bf16 inputs =====
__global__ __launch_bounds__(256) void gemm_mfma(const short* __restrict__ Mw,
                                                 const short* __restrict__ X,
                                                 const float* __restrict__ biasf,
                                                 float* __restrict__ out) {
    __shared__ short As[64 * 72];
    __shared__ short Bs[64 * 72];
    int tid = threadIdx.x;
    int lane = tid & 63, w = tid >> 6;
    int r = lane & 15, quad = lane >> 4;
    int rowBase = blockIdx.y * 64, colBase = blockIdx.x * 64;
    int sm = tid >> 2, skq = (tid & 3) << 4;   // 16 shorts (32B) per thread per tile

    const short* pa = Mw + (size_t)(rowBase + sm) * KTOT + skq;
    const short* pb = X + (size_t)(colBase + sm) * KTOT + skq;
    s8v a0 = *(const s8v*)(pa), a1 = *(const s8v*)(pa + 8);
    s8v b0 = *(const s8v*)(pb), b1 = *(const s8v*)(pb + 8);

    f4v acc[4];
    #pragma unroll
    for (int t = 0; t < 4; ++t) acc[t] = (f4v)0.0f;

    for (int kt = 0; kt < 11; ++kt) {
        __syncthreads();
        *(s8v*)&As[sm * 72 + skq + 0] = a0;
        *(s8v*)&As[sm * 72 + skq + 8] = a1;
        *(s8v*)&Bs[sm * 72 + skq + 0] = b0;
        *(s8v*)&Bs[sm * 72 + skq + 8] = b1;
        __syncthreads();
        if (kt < 10) {
            pa += 64; pb += 64;
            a0 = *(const s8v*)(pa); a1 = *(const s8v*)(pa + 8);
            b0 = *(const s8v*)(pb); b1 = *(const s8v*)(pb + 8);
        }
        #pragma unroll
        for (int kk = 0; kk < 2; ++kk) {
            int aoff = (w * 16 + r) * 72 + kk * 32 + quad * 8;
            s8v af = *(const s8v*)&As[aoff];
            #pragma unroll
            for (int t = 0; t < 4; ++t) {
                int boff = (t * 16 + r) * 72 + kk * 32 + quad * 8;
                s8v bf = *(const s8v*)&Bs[boff];
                acc[t] = __builtin_amdgcn_mfma_f32_16x16x32_bf16(af, bf, acc[t], 0, 0, 0);
            }
        }
    }
    #pragma unroll
    for (int t = 0; t < 4; ++t) {
        int colg = colBase + t * 16 + r;
        size_t obase = (size_t)(colg >> 10) * (256 * NKP) + (size_t)(colg & 1023);
        #pragma unroll
        for (int reg = 0; reg < 4; ++reg) {
            int row = rowBase + w * 16 + quad * 4 + reg;
            out[obase + (size_t)row * NKP] = acc[t][reg] + biasf[row];
        }
    }
}

// ================= launch =================
extern "C" void kernel_launch(void* const* d_in, const int* in_sizes, int n_in,
                              void* d_out, int out_size, void* d_ws, size_t ws_size,
                              hipStream_t stream) {
    const float* scores  = (const float*)d_in[0];
    const float* d1      = (const float*)d_in[1];
    const float* d2      = (const float*)d_in[2];
    const float* cDa     = (const float*)d_in[3];
    const float* d4      = (const float*)d_in[4];
    const float* lin0_w  = (const float*)d_in[5];
    const float* lin0_b  = (const float*)d_in[6];
    const float* lin1_w  = (const float*)d_in[7];
    const float* lin1_b  = (const float*)d_in[8];
    const float* lin2_w  = (const float*)d_in[9];
    const float* lin2_b  = (const float*)d_in[10];
    const float* merge_w = (const float*)d_in[11];
    const float* merge_b = (const float*)d_in[12];
    float* out = (float*)d_out;

    char* ws = (char*)d_ws;
    float* MASK = (float*)ws;                                          // BHW floats (nms phase)
    short* Xbuf = (short*)ws;                                          // aliases (post-topk); 5.77 MB
    unsigned long long* cand  = (unsigned long long*)(ws + 14745600);  // 524,288 B
    int* cnt                  = (int*)(ws + 15269888);                 // 1,024 B
    int* fidx                 = (int*)(ws + 15401984);                 // 16,384 B
    short* Mw                 = (short*)(ws + 15418368);               // 360,448 B (bf16)
    float* biasf              = (float*)(ws + 16139264);               // 1,024 B
    int* perm                 = (int*)(ws + 16140288);                 // 16,384 B

    dim3 tgrid(W / 32, H / 32, B);   // (20,15,4)

    fuse_all<<<705, 256, 0, stream>>>(merge_w, merge_b, lin0_w, lin0_b, lin1_w, lin1_b,
                                      lin2_w, lin2_b, Mw, biasf, cnt);
    nms1<<<tgrid, 256, 0, stream>>>(scores, MASK);
    nms2_compact<<<tgrid, 512, 0, stream>>>(scores, MASK, cand, cnt);
    topk<<<B, 1024, 0, stream>>>(cand, cnt, out, fidx, perm);
    sample_all<<<dim3(1024, 4), 256, 0, stream>>>(d1, d2, cDa, d4, fidx, perm, Xbuf);
    gemm_mfma<<<dim3(NCOL / 64, 256 / 64), 256, 0, stream>>>(Mw, Xbuf, biasf, out + B * NKP * 3);
}

// Round 7
// 352.860 us; speedup vs baseline: 1.1941x; 1.0016x over previous
//
#include <hip/hip_runtime.h>
#include <hip/hip_bf16.h>

#define B 4
#define H 480
#define W 640
#define HW (H*W)
#define BHW (B*H*W)
#define NKP 1024
#define THRESH 0.005f
#define CAP 16384
#define NCOL (B*NKP)
#define KTOT 704

typedef __attribute__((ext_vector_type(8))) short s8v;
typedef __attribute__((ext_vector_type(4))) float f4v;
typedef struct { float x, y; } __attribute__((aligned(4))) f2u;   // 4B-aligned pair load

__device__ __forceinline__ short f2bf(float f) {
    __hip_bfloat16 h = __float2bfloat16(f);
    return *(short*)&h;
}

__device__ __forceinline__ float max3f(float a, float b, float c) {
    return fmaxf(fmaxf(a, b), c);     // clang fuses to v_max3_f32
}
// 9-wide max as a depth-2 tree of v_max3_f32 (4 instrs vs 8-deep chain)
#define MAX9(A, base, str) \
    max3f(max3f((A)[(base)], (A)[(base)+(str)], (A)[(base)+2*(str)]), \
          max3f((A)[(base)+3*(str)], (A)[(base)+4*(str)], (A)[(base)+5*(str)]), \
          max3f((A)[(base)+6*(str)], (A)[(base)+7*(str)], (A)[(base)+8*(str)]))

// ================= fused weights + bias + counter zero (Mw bf16) =================
__global__ void fuse_all(const float* __restrict__ merge_w, const float* __restrict__ merge_b,
                         const float* __restrict__ lin0_w, const float* __restrict__ lin0_b,
                         const float* __restrict__ lin1_w, const float* __restrict__ lin1_b,
                         const float* __restrict__ lin2_w, const float* __restrict__ lin2_b,
                         short* __restrict__ Mw, float* __restrict__ biasf, int* __restrict__ cnt) {
    if (blockIdx.x == 704) {
        int o = threadIdx.x;
        if (o < 4) cnt[o * 64] = 0;
        float acc = merge_b[o];
        for (int k = 0; k < 64; ++k)  acc += merge_w[o * KTOT + k] * lin2_b[k];
        for (int k = 0; k < 128; ++k) acc += merge_w[o * KTOT + 64 + k] * lin1_b[k];
        for (int k = 0; k < 256; ++k) acc += merge_w[o * KTOT + 448 + k] * lin0_b[k];
        biasf[o] = acc;
        return;
    }
    int e = blockIdx.x * 256 + threadIdx.x;
    int o = e / KTOT;
    int j = e - o * KTOT;
    float acc = 0.0f;
    if (j < 64) {
        for (int k = 0; k < 64; ++k) acc += merge_w[o * KTOT + k] * lin2_w[k * 64 + j];
    } else if (j < 192) {
        int jj = j - 64;
        for (int k = 0; k < 128; ++k) acc += merge_w[o * KTOT + 64 + k] * lin1_w[k * 128 + jj];
    } else if (j < 448) {
        acc = merge_w[o * KTOT + j];
    } else {
        int jj = j - 448;
        for (int k = 0; k < 256; ++k) acc += merge_w[o * KTOT + 448 + k] * lin0_w[k * 256 + jj];
    }
    Mw[o * KTOT + j] = f2bf(acc);
}

// ===== transpose_d4: d4 [B][256][30][40] -> d4T [B][1200][256] (f32, exact) =====
__global__ __launch_bounds__(256) void transpose_d4(const float* __restrict__ d4,
                                                    float* __restrict__ d4T) {
    __shared__ float T[64][65];
    int b = blockIdx.z;
    int p0 = blockIdx.x * 64;   // pixel tile (19 tiles over 1200)
    int c0 = blockIdx.y * 64;   // channel tile (4 tiles over 256)
    for (int t = threadIdx.x; t < 4096; t += 256) {
        int ch = t >> 6, px = t & 63;            // px fast -> coalesced read
        int gp = p0 + px;
        if (gp < 1200)
            T[ch][px] = d4[((size_t)(b * 256 + c0 + ch)) * 1200 + gp];
    }
    __syncthreads();
    for (int t = threadIdx.x; t < 4096; t += 256) {
        int px = t >> 6, ch = t & 63;            // ch fast -> coalesced write
        int gp = p0 + px;
        if (gp < 1200)
            d4T[((size_t)(b * 1200 + gp)) * 256 + c0 + ch] = T[ch][px];
    }
}

// ================= NMS stage 1: mask0 = (S == pool9(S)) =================
__global__ __launch_bounds__(256) void nms1(const float* __restrict__ scores,
                                            float* __restrict__ mask) {
    __shared__ float tile[40][40];
    __shared__ float hm[40][32];
    int bz = blockIdx.z;
    int x0 = blockIdx.x * 32, y0 = blockIdx.y * 32;
    const float* sp = scores + bz * HW;
    for (int t = threadIdx.x; t < 1600; t += 256) {
        int ly = t / 40, lx = t - ly * 40;
        int gy = y0 - 4 + ly, gx = x0 - 4 + lx;
        tile[ly][lx] = (gy >= 0 && gy < H && gx >= 0 && gx < W) ? sp[gy * W + gx] : -INFINITY;
    }
    __syncthreads();
    for (int t = threadIdx.x; t < 1280; t += 256) {
        int ly = t >> 5, lx = t & 31;
        hm[ly][lx] = MAX9(&tile[ly][0], lx, 1);
    }
    __syncthreads();
    for (int t = threadIdx.x; t < 1024; t += 256) {
        int ly = t >> 5, lx = t & 31;
        float m = MAX9(&hm[0][0], ly * 32 + lx, 32);
        float s = tile[ly + 4][lx + 4];
        mask[bz * HW + (y0 + ly) * W + x0 + lx] = (s == m) ? 1.0f : 0.0f;
    }
}

// ===== NMS stage 2: remaining 4 pools (2 NMS iterations) fused in LDS + compaction =====
__global__ __launch_bounds__(512) void nms2_compact(const float* __restrict__ scores,
                                                    const float* __restrict__ mask0,
                                                    unsigned long long* __restrict__ cand,
                                                    int* __restrict__ cnt) {
    __shared__ float Sm[56 * 56];   // S on local [4,60)
    __shared__ float Mm[64 * 64];   // mask on local [0,64)
    __shared__ float Zm[56 * 56];   // Z on local [4,60)
    __shared__ float Tm[64 * 56];   // h-pass temp
    __shared__ int lcnt, gbase;
    int bz = blockIdx.z;
    int x0 = blockIdx.x * 32, y0 = blockIdx.y * 32;
    const float* sp = scores + bz * HW;
    const float* mp = mask0 + bz * HW;
    if (threadIdx.x == 0) lcnt = 0;
    for (int t = threadIdx.x; t < 4096; t += 512) {
        int ly = t >> 6, lx = t & 63;
        int gy = y0 - 16 + ly, gx = x0 - 16 + lx;
        Mm[t] = (gy >= 0 && gy < H && gx >= 0 && gx < W) ? mp[gy * W + gx] : 0.0f;
    }
    for (int t = threadIdx.x; t < 3136; t += 512) {
        int i = t / 56, j = t - i * 56;
        int gy = y0 - 12 + i, gx = x0 - 12 + j;
        Sm[t] = (gy >= 0 && gy < H && gx >= 0 && gx < W) ? sp[gy * W + gx] : -1.0f;
    }
    __syncthreads();
    for (int t = threadIdx.x; t < 3584; t += 512) {
        int i = t / 56, c = t - i * 56;
        Tm[i * 56 + c] = MAX9(Mm, i * 64 + c, 1);
    }
    __syncthreads();
    for (int t = threadIdx.x; t < 3136; t += 512) {
        int i = t / 56, c = t - i * 56;
        float m = MAX9(Tm, i * 56 + c, 56);
        Zm[t] = (m > 0.0f) ? -1.0f : Sm[t];
    }
    __syncthreads();
    for (int t = threadIdx.x; t < 2688; t += 512) {
        int i = t / 48, c = t - i * 48;
        Tm[i * 56 + c] = MAX9(Zm, i * 56 + c, 1);
    }
    __syncthreads();
    for (int t = threadIdx.x; t < 2304; t += 512) {
        int r = t / 48, c = t - r * 48;
        float m = MAX9(Tm, r * 56 + c, 56);
        float Zc = Zm[(r + 4) * 56 + c + 4];
        int mi = (r + 8) * 64 + c + 8;
        bool nm = (Zc == m) && (Zc >= 0.0f);
        Mm[mi] = (Mm[mi] != 0.0f || nm) ? 1.0f : 0.0f;
    }
    __syncthreads();
    for (int t = threadIdx.x; t < 1920; t += 512) {
        int r = t / 40, c = t - r * 40;
        Tm[r * 56 + c] = MAX9(Mm, (r + 8) * 64 + c + 8, 1);
    }
    __syncthreads();
    for (int t = threadIdx.x; t < 1600; t += 512) {
        int r = t / 40, c = t - r * 40;
        float m = MAX9(Tm, r * 56 + c, 56);
        int zi = (r + 8) * 56 + c + 8;
        Zm[zi] = (m > 0.0f) ? -1.0f : Sm[zi];
    }
    __syncthreads();
    for (int t = threadIdx.x; t < 1280; t += 512) {
        int r = t / 32, c = t & 31;
        Tm[r * 56 + c] = MAX9(Zm, (r + 8) * 56 + c + 8, 1);
    }
    __syncthreads();
    unsigned long long keys[2];
    int nl = 0;
    #pragma unroll
    for (int q = 0; q < 2; ++q) {
        int t = threadIdx.x + q * 512;
        int r3 = t >> 5, c = t & 31;
        float m = MAX9(Tm, r3 * 56 + c, 56);
        float Zc = Zm[(r3 + 12) * 56 + c + 12];
        bool fin = (Mm[(r3 + 16) * 64 + c + 16] != 0.0f) || ((Zc == m) && (Zc >= 0.0f));
        int gy = y0 + r3, gx = x0 + c;
        float sc = Sm[(r3 + 12) * 56 + c + 12];
        if (fin && gy >= 4 && gy < H - 4 && gx >= 4 && gx < W - 4 && sc > THRESH) {
            unsigned r = (unsigned)(gy * W + gx);
            unsigned bits = __float_as_uint(sc) | 0x80000000u;
            keys[nl++] = ((unsigned long long)bits << 32) |
                         (unsigned long long)(0xFFFFFFFFu - r);
        }
    }
    int lpos = 0;
    if (nl) lpos = atomicAdd(&lcnt, nl);
    __syncthreads();
    if (threadIdx.x == 0) gbase = (lcnt > 0) ? atomicAdd(&cnt[bz * 64], lcnt) : 0;
    __syncthreads();
    for (int j = 0; j < nl; ++j) {
        int p = gbase + lpos + j;
        if (p < CAP) cand[(size_t)bz * CAP + p] = keys[j];
    }
}

// ===== topk: TWO-LEVEL histogram select + bitonic; perm via LDS counting sort =====
__global__ __launch_bounds__(1024) void topk(const unsigned long long* __restrict__ cand,
                                             const int* __restrict__ cnt,
                                             float* __restrict__ out, int* __restrict__ fidx,
                                             int* __restrict__ perm) {
    __shared__ int hist[2048];
    __shared__ unsigned long long buf[4096];
    __shared__ int scnt, spiv1, spiv2, sabove;
    int b = blockIdx.x, tid = threadIdx.x;
    int m = cnt[b * 64]; if (m > CAP) m = CAP;
    const unsigned long long* cb = cand + (size_t)b * CAP;
    int target = (m < 1024) ? m : 1024;

    hist[tid] = 0; hist[tid + 1024] = 0;
    if (tid == 0) { scnt = 0; spiv1 = 2048; spiv2 = 0; sabove = 0; }
    __syncthreads();
    for (int i = tid; i < m; i += 1024)
        atomicAdd(&hist[(int)(cb[i] >> 53) & 0x7FF], 1);
    __syncthreads();
    for (int d = 1; d < 2048; d <<= 1) {
        int v0 = hist[tid] + ((tid + d < 2048) ? hist[tid + d] : 0);
        int v1 = hist[tid + 1024] + ((tid + 1024 + d < 2048) ? hist[tid + 1024 + d] : 0);
        __syncthreads();
        hist[tid] = v0; hist[tid + 1024] = v1;
        __syncthreads();
    }
    if (target > 0) {
        for (int t = tid; t < 2048; t += 1024) {
            int c = hist[t];
            int cn = (t < 2047) ? hist[t + 1] : 0;
            if (c >= target && cn < target) { spiv1 = t; sabove = cn; }
        }
    }
    __syncthreads();
    int piv1 = spiv1;
    int target2 = target - sabove;
    hist[tid] = 0; hist[tid + 1024] = 0;
    __syncthreads();
    for (int i = tid; i < m; i += 1024) {
        unsigned long long k = cb[i];
        if (((int)(k >> 53) & 0x7FF) == piv1)
            atomicAdd(&hist[(int)(k >> 42) & 0x7FF], 1);
    }
    __syncthreads();
    for (int d = 1; d < 2048; d <<= 1) {
        int v0 = hist[tid] + ((tid + d < 2048) ? hist[tid + d] : 0);
        int v1 = hist[tid + 1024] + ((tid + 1024 + d < 2048) ? hist[tid + 1024 + d] : 0);
        __syncthreads();
        hist[tid] = v0; hist[tid + 1024] = v1;
        __syncthreads();
    }
    if (target > 0) {
        for (int t = tid; t < 2048; t += 1024) {
            int c = hist[t];
            int cn = (t < 2047) ? hist[t + 1] : 0;
            if (c >= target2 && cn < target2) spiv2 = t;
        }
    }
    __syncthreads();
    int piv2 = spiv2;
    for (int i = tid; i < m; i += 1024) {
        unsigned long long k = cb[i];
        int b1 = (int)(k >> 53) & 0x7FF;
        bool sel = (target > 0) &&
                   (b1 > piv1 || (b1 == piv1 && (((int)(k >> 42) & 0x7FF) >= piv2)));
        if (sel) {
            int p = atomicAdd(&scnt, 1);
            if (p < 4096) buf[p] = k;
        }
    }
    __syncthreads();
    int sc_ = scnt; if (sc_ > 4096) sc_ = 4096;
    int ns = 1024; while (ns < sc_) ns <<= 1;
    for (int t = tid; t < ns; t += 1024) if (t >= sc_) buf[t] = 0ULL;
    __syncthreads();
    for (int k = 2; k <= ns; k <<= 1)
        for (int j = k >> 1; j > 0; j >>= 1) {
            __syncthreads();
            for (int t = tid; t < ns; t += 1024) {
                int ixj = t ^ j;
                if (ixj > t) {
                    unsigned long long a = buf[t], bb = buf[ixj];
                    if (((t & k) == 0) ? (a < bb) : (a > bb)) { buf[t] = bb; buf[ixj] = a; }
                }
            }
        }
    __syncthreads();
    unsigned long long key = buf[tid];
    float kx, ky, sc;
    unsigned idx;
    if (key != 0ULL) {
        unsigned ord = (unsigned)(key >> 32);
        sc = __uint_as_float(ord ^ 0x80000000u);
        idx = 0xFFFFFFFFu - (unsigned)(key & 0xFFFFFFFFu);
        kx = (float)(idx % W);
        ky = (float)(idx / W);
    } else {
        sc = -1.0f; idx = 0; kx = 0.0f; ky = 0.0f;
    }
    int bn = b * NKP + tid;
    out[bn * 2 + 0] = kx;
    out[bn * 2 + 1] = ky;
    out[B * NKP * 2 + bn] = sc;
    fidx[bn] = (int)idx;
    __syncthreads();
    // spatial perm via counting sort on pixel bucket (idx>>10 in [0,300)).
    // perm only orders sample processing; ANY permutation is value-correct.
    if (tid < 512) { hist[tid] = 0; hist[tid + 1024] = 0; }
    __syncthreads();
    int bucket = (int)(idx >> 10);
    atomicAdd(&hist[bucket], 1);
    __syncthreads();
    if (tid < 512) hist[512 + tid] = hist[tid];
    __syncthreads();
    for (int d = 1; d < 512; d <<= 1) {
        int v = 0;
        if (tid < 512) v = hist[512 + tid] + ((tid >= d) ? hist[512 + tid - d] : 0);
        __syncthreads();
        if (tid < 512) hist[512 + tid] = v;
        __syncthreads();
    }
    int intra = atomicAdd(&hist[1024 + bucket], 1);
    int pos = hist[512 + bucket] - hist[bucket] + intra;   // exclusive base + slot
    perm[b * NKP + pos] = tid;
}

// ===== sample_all: wave-per-keypoint, barrier-free; seg3 reads NHWC d4T =====
__global__ __launch_bounds__(256) void sample_all(const float* __restrict__ d1,
                                                  const float* __restrict__ d2,
                                                  const float* __restrict__ cDa,
                                                  const float* __restrict__ d4T,
                                                  const int* __restrict__ fidx,
                                                  const int* __restrict__ perm,
                                                  short* __restrict__ X) {
    int lane = threadIdx.x & 63;
    int wv = threadIdx.x >> 6;
    int seg = blockIdx.y;
    int bid = blockIdx.x;
    int swz = ((bid & 7) << 7) | (bid >> 3);
    int b = swz >> 8;                  // 256 chunks per batch
    int g0 = ((swz & 255) << 2) + wv;  // kp slot within batch

    const float* map; int h, w, s, C, base, nset;
    if (seg == 0)      { map = d1;  h = 240; w = 320; s = 2;  C = 64;  base = 0;   nset = 1; }
    else if (seg == 1) { map = d2;  h = 120; w = 160; s = 4;  C = 128; base = 64;  nset = 2; }
    else if (seg == 2) { map = cDa; h = 60;  w = 80;  s = 8;  C = 256; base = 192; nset = 4; }
    else               { map = d4T; h = 30;  w = 40;  s = 16; C = 256; base = 448; nset = 4; }

    int col = (b << 10) | perm[(b << 10) + g0];
    int idx = fidx[col];
    float kx = (float)(idx % W);
    float ky = (float)(idx / W);
    float kxs = kx - (float)s * 0.5f + 0.5f;
    float kys = ky - (float)s * 0.5f + 0.5f;
    float gx = kxs / (float)(w * s - 1) * 2.0f - 1.0f;
    float gy = kys / (float)(h * s - 1) * 2.0f - 1.0f;
    float x = (gx + 1.0f) * 0.5f * (float)(w - 1);
    float y = (gy + 1.0f) * 0.5f * (float)(h - 1);
    float x0f = floorf(x), y0f = floorf(y);
    int x0 = (int)x0f, y0 = (int)y0f;
    float wx1 = x - x0f, wy1 = y - y0f;
    float wx0 = 1.0f - wx1, wy0 = 1.0f - wy1;
    bool vx0 = (x0 >= 0) && (x0 < w);
    bool vx1 = (x0 + 1 >= 0) && (x0 + 1 < w);
    bool vy0 = (y0 >= 0) && (y0 < h);
    bool vy1 = (y0 + 1 >= 0) && (y0 + 1 < h);
    int xc0 = min(max(x0, 0), w - 1), xc1 = min(max(x0 + 1, 0), w - 1);
    int yc0 = min(max(y0, 0), h - 1), yc1 = min(max(y0 + 1, 0), h - 1);
    float w00 = (vx0 && vy0) ? wx0 * wy0 : 0.0f;
    float w01 = (vx1 && vy0) ? wx1 * wy0 : 0.0f;
    float w10 = (vx0 && vy1) ? wx0 * wy1 : 0.0f;
    float w11 = (vx1 && vy1) ? wx1 * wy1 : 0.0f;

    float vals[4];
    float r = 0.0f;
    if (seg == 3) {
        // NHWC: [b][px][256]; wave = 64 consecutive channels -> 256B coalesced taps
        const float* pt = d4T + ((size_t)b * 1200) * 256 + lane;
        size_t o00 = ((size_t)(yc0 * 40 + xc0)) << 8;
        size_t o01 = ((size_t)(yc0 * 40 + xc1)) << 8;
        size_t o10 = ((size_t)(yc1 * 40 + xc0)) << 8;
        size_t o11 = ((size_t)(yc1 * 40 + xc1)) << 8;
        float q00[4], q01[4], q10[4], q11[4];
        #pragma unroll
        for (int j = 0; j < 4; ++j) {
            q00[j] = pt[o00 + j * 64]; q01[j] = pt[o01 + j * 64];
            q10[j] = pt[o10 + j * 64]; q11[j] = pt[o11 + j * 64];
        }
        #pragma unroll
        for (int j = 0; j < 4; ++j) {
            vals[j] = q00[j] * w00 + q01[j] * w01 + q10[j] * w10 + q11[j] * w11;
            r += vals[j] * vals[j];
        }
    } else {
        int xb = min(xc0, w - 2);
        float s0 = (xc0 == xb) ? 1.0f : 0.0f;
        float s1 = (xc1 == xb) ? 1.0f : 0.0f;
        float ax = w00 * s0 + w01 * s1;
        float ay = w00 * (1.0f - s0) + w01 * (1.0f - s1);
        float bx = w10 * s0 + w11 * s1;
        float by = w10 * (1.0f - s0) + w11 * (1.0f - s1);
        size_t hw = (size_t)(h * w);
        const float* pb = map + ((size_t)b * C + lane) * hw;
        size_t off0 = (size_t)yc0 * w + xb;
        size_t off1 = (size_t)yc1 * w + xb;
        size_t cstr = hw << 6;   // 64 channel-planes
        f2u q0[4], q1[4];
        #pragma unroll
        for (int j = 0; j < 4; ++j) {
            if (j < nset) {
                const float* p = pb + (size_t)j * cstr;
                q0[j] = *(const f2u*)(p + off0);
                q1[j] = *(const f2u*)(p + off1);
            }
        }
        #pragma unroll
        for (int j = 0; j < 4; ++j) {
            if (j < nset) {
                vals[j] = q0[j].x * ax + q0[j].y * ay + q1[j].x * bx + q1[j].y * by;
                r += vals[j] * vals[j];
            }
        }
    }
    #pragma unroll
    for (int off = 32; off > 0; off >>= 1) r += __shfl_xor(r, off, 64);
    float denom = fmaxf(sqrtf(r), 1e-12f);
    float inv = 1.0f / denom;
    short* xp = X + (size_t)col * KTOT + base + lane;
    #pragma unroll
    for (int j = 0; j < 4; ++j) {
        if (j < nset) xp[j * 64] = f2bf(vals[j] * inv);
    }
}

// ===== GEMM (bf16 MFMA): out[256,4096] = Mw[256,704] * X^T + bias; bf16 inputs =====
__global__ __launch_bounds__(256) void gemm_mfma(const short* __restrict__ Mw,
                                                 const short* __restrict__ X,
                                                 const float* __restrict__ biasf,
                                                 float* __restrict__ out) {
    __shared__ short As[64 * 72];
    __shared__ short Bs[64 * 72];
    int tid = threadIdx.x;
    int lane = tid & 63, w = tid >> 6;
    int r = lane & 15, quad = lane >> 4;
    int rowBase = blockIdx.y * 64, colBase = blockIdx.x * 64;
    int sm = tid >> 2, skq = (tid & 3) << 4;   // 16 shorts (32B) per thread per tile

    const short* pa = Mw + (size_t)(rowBase + sm) * KTOT + skq;
    const short* pb = X + (size_t)(colBase + sm) * KTOT + skq;
    s8v a0 = *(const s8v*)(pa), a1 = *(const s8v*)(pa + 8);
    s8v b0 = *(const s8v*)(pb), b1 = *(const s8v*)(pb + 8);

    f4v acc[4];
    #pragma unroll
    for (int t = 0; t < 4; ++t) acc[t] = (f4v)0.0f;

    for (int kt = 0; kt < 11; ++kt) {
        __syncthreads();
        *(s8v*)&As[sm * 72 + skq + 0] = a0;
        *(s8v*)&As[sm * 72 + skq + 8] = a1;
        *(s8v*)&Bs[sm * 72 + skq + 0] = b0;
        *(s8v*)&Bs[sm * 72 + skq + 8] = b1;
        __syncthreads();
        if (kt < 10) {
            pa += 64; pb += 64;
            a0 = *(const s8v*)(pa); a1 = *(const s8v*)(pa + 8);
            b0 = *(const s8v*)(pb); b1 = *(const s8v*)(pb + 8);
        }
        #pragma unroll
        for (int kk = 0; kk < 2; ++kk) {
            int aoff = (w * 16 + r) * 72 + kk * 32 + quad * 8;
            s8v af = *(const s8v*)&As[aoff];
            #pragma unroll
            for (int t = 0; t < 4; ++t) {
                int boff = (t * 16 + r) * 72 + kk * 32 + quad * 8;
                s8v bf = *(const s8v*)&Bs[boff];
                acc[t] = __builtin_amdgcn_mfma_f32_16x16x32_bf16(af, bf, acc[t], 0, 0, 0);
            }
        }
    }
    #pragma unroll
    for (int t = 0; t < 4; ++t) {
        int colg = colBase + t * 16 + r;
        size_t obase = (size_t)(colg >> 10) * (256 * NKP) + (size_t)(colg & 1023);
        #pragma unroll
        for (int reg = 0; reg < 4; ++reg) {
            int row = rowBase + w * 16 + quad * 4 + reg;
            out[obase + (size_t)row * NKP] = acc[t][reg] + biasf[row];
        }
    }
}

// ================= launch =================
extern "C" void kernel_launch(void* const* d_in, const int* in_sizes, int n_in,
                              void* d_out, int out_size, void* d_ws, size_t ws_size,
                              hipStream_t stream) {
    const float* scores  = (const float*)d_in[0];
    const float* d1      = (const float*)d_in[1];
    const float* d2      = (const float*)d_in[2];
    const float* cDa     = (const float*)d_in[3];
    const float* d4      = (const float*)d_in[4];
    const float* lin0_w  = (const float*)d_in[5];
    const float* lin0_b  = (const float*)d_in[6];
    const float* lin1_w  = (const float*)d_in[7];
    const float* lin1_b  = (const float*)d_in[8];
    const float* lin2_w  = (const float*)d_in[9];
    const float* lin2_b  = (const float*)d_in[10];
    const float* merge_w = (const float*)d_in[11];
    const float* merge_b = (const float*)d_in[12];
    float* out = (float*)d_out;

    char* ws = (char*)d_ws;
    float* MASK = (float*)ws;                                          // 4.9 MB (nms phase)
    short* Xbuf = (short*)ws;                                          // 5.77 MB (post-topk; aliases MASK)
    float* d4T  = (float*)(ws + 6291456);                              // 4,915,200 B (free gap)
    unsigned long long* cand  = (unsigned long long*)(ws + 14745600);  // 524,288 B
    int* cnt                  = (int*)(ws + 15269888);                 // 1,024 B
    int* fidx                 = (int*)(ws + 15401984);                 // 16,384 B
    short* Mw                 = (short*)(ws + 15418368);               // 360,448 B (bf16)
    float* biasf              = (float*)(ws + 16139264);               // 1,024 B
    int* perm                 = (int*)(ws + 16140288);                 // 16,384 B

    dim3 tgrid(W / 32, H / 32, B);   // (20,15,4)

    fuse_all<<<705, 256, 0, stream>>>(merge_w, merge_b, lin0_w, lin0_b, lin1_w, lin1_b,
                                      lin2_w, lin2_b, Mw, biasf, cnt);
    transpose_d4<<<dim3(19, 4, 4), 256, 0, stream>>>(d4, d4T);
    nms1<<<tgrid, 256, 0, stream>>>(scores, MASK);
    nms2_compact<<<tgrid, 512, 0, stream>>>(scores, MASK, cand, cnt);
    topk<<<B, 1024, 0, stream>>>(cand, cnt, out, fidx, perm);
    sample_all<<<dim3(1024, 4), 256, 0, stream>>>(d1, d2, cDa, d4T, fidx, perm, Xbuf);
    gemm_mfma<<<dim3(NCOL / 64, 256 / 64), 256, 0, stream>>>(Mw, Xbuf, biasf, out + B * NKP * 3);
}

// Round 8
// 312.196 us; speedup vs baseline: 1.3496x; 1.1303x over previous
//
#include <hip/hip_runtime.h>
#include <hip/hip_bf16.h>

#define B 4
#define H 480
#define W 640
#define HW (H*W)
#define BHW (B*H*W)
#define NKP 1024
#define THRESH 0.005f
#define CAP 16384
#define NCOL (B*NKP)
#define KTOT 704

typedef __attribute__((ext_vector_type(8))) short s8v;
typedef __attribute__((ext_vector_type(4))) float f4v;
typedef struct { float x, y; } __attribute__((aligned(4))) f2u;   // 4B-aligned pair load

__device__ __forceinline__ short f2bf(float f) {
    __hip_bfloat16 h = __float2bfloat16(f);
    return *(short*)&h;
}

__device__ __forceinline__ float max3f(float a, float b, float c) {
    return fmaxf(fmaxf(a, b), c);     // clang fuses to v_max3_f32
}
// 9-wide max as a depth-2 tree of v_max3_f32 (4 instrs vs 8-deep chain)
#define MAX9(A, base, str) \
    max3f(max3f((A)[(base)], (A)[(base)+(str)], (A)[(base)+2*(str)]), \
          max3f((A)[(base)+3*(str)], (A)[(base)+4*(str)], (A)[(base)+5*(str)]), \
          max3f((A)[(base)+6*(str)], (A)[(base)+7*(str)], (A)[(base)+8*(str)]))

// ===== fuse_w: Mw[256,704] weight fold; block=(64 cols x 4 K-slice waves) =====
// grid = (11 col-groups, 256 rows). Coalesced lin*_w reads, broadcast merge_w row.
__global__ __launch_bounds__(256) void fuse_w(const float* __restrict__ merge_w,
                                              const float* __restrict__ lin0_w,
                                              const float* __restrict__ lin1_w,
                                              const float* __restrict__ lin2_w,
                                              short* __restrict__ Mw) {
    __shared__ float red[4][64];
    int lane = threadIdx.x & 63;
    int wv = threadIdx.x >> 6;
    int jb = blockIdx.x;           // 0..10
    int o = blockIdx.y;            // 0..255
    int j = jb * 64 + lane;
    const float* mwr = merge_w + (size_t)o * KTOT;

    if (jb >= 3 && jb <= 6) {      // cols 192..447: pure copy
        if (wv == 0) Mw[(size_t)o * KTOT + j] = f2bf(mwr[j]);
        return;
    }
    float acc = 0.0f;
    if (jb == 0) {                 // K=64, slice 16/wave
        int k0 = wv * 16;
        #pragma unroll
        for (int k = 0; k < 16; ++k)
            acc += mwr[k0 + k] * lin2_w[(k0 + k) * 64 + lane];
    } else if (jb <= 2) {          // K=128, slice 32/wave
        int jj = (jb - 1) * 64 + lane;
        int k0 = wv * 32;
        #pragma unroll
        for (int k = 0; k < 32; ++k)
            acc += mwr[64 + k0 + k] * lin1_w[(k0 + k) * 128 + jj];
    } else {                       // jb 7..10: K=256, slice 64/wave
        int jj = (jb - 7) * 64 + lane;
        int k0 = wv * 64;
        #pragma unroll
        for (int k = 0; k < 64; ++k)
            acc += mwr[448 + k0 + k] * lin0_w[(k0 + k) * 256 + jj];
    }
    red[wv][lane] = acc;
    __syncthreads();
    if (wv == 0) {
        float t = red[0][lane] + red[1][lane] + red[2][lane] + red[3][lane];
        Mw[(size_t)o * KTOT + j] = f2bf(t);
    }
}

// ===== fuse_bias: biasf[256] via wave-per-row shuffle reduce; zeroes cnt =====
__global__ __launch_bounds__(256) void fuse_bias(const float* __restrict__ merge_w,
                                                 const float* __restrict__ merge_b,
                                                 const float* __restrict__ lin0_b,
                                                 const float* __restrict__ lin1_b,
                                                 const float* __restrict__ lin2_b,
                                                 float* __restrict__ biasf,
                                                 int* __restrict__ cnt) {
    int lane = threadIdx.x & 63;
    int wv = threadIdx.x >> 6;
    int o = blockIdx.x * 4 + wv;
    if (blockIdx.x == 0 && threadIdx.x < 4) cnt[threadIdx.x * 64] = 0;
    const float* mwr = merge_w + (size_t)o * KTOT;
    float acc = 0.0f;
    #pragma unroll
    for (int i = 0; i < 11; ++i) {
        int k = i * 64 + lane;
        float c;
        if (k < 64) c = lin2_b[k];
        else if (k < 192) c = lin1_b[k - 64];
        else if (k < 448) c = 0.0f;
        else c = lin0_b[k - 448];
        acc += mwr[k] * c;
    }
    #pragma unroll
    for (int off = 32; off > 0; off >>= 1) acc += __shfl_xor(acc, off, 64);
    if (lane == 0) biasf[o] = merge_b[o] + acc;
}

// ===== transpose_d4: d4 [B][256][30][40] -> d4T [B][1200][256] (f32, exact) =====
__global__ __launch_bounds__(256) void transpose_d4(const float* __restrict__ d4,
                                                    float* __restrict__ d4T) {
    __shared__ float T[64][65];
    int b = blockIdx.z;
    int p0 = blockIdx.x * 64;   // pixel tile (19 tiles over 1200)
    int c0 = blockIdx.y * 64;   // channel tile (4 tiles over 256)
    for (int t = threadIdx.x; t < 4096; t += 256) {
        int ch = t >> 6, px = t & 63;            // px fast -> coalesced read
        int gp = p0 + px;
        if (gp < 1200)
            T[ch][px] = d4[((size_t)(b * 256 + c0 + ch)) * 1200 + gp];
    }
    __syncthreads();
    for (int t = threadIdx.x; t < 4096; t += 256) {
        int px = t >> 6, ch = t & 63;            // ch fast -> coalesced write
        int gp = p0 + px;
        if (gp < 1200)
            d4T[((size_t)(b * 1200 + gp)) * 256 + c0 + ch] = T[ch][px];
    }
}

// ================= NMS stage 1: mask0 = (S == pool9(S)) =================
__global__ __launch_bounds__(256) void nms1(const float* __restrict__ scores,
                                            float* __restrict__ mask) {
    __shared__ float tile[40][40];
    __shared__ float hm[40][32];
    int bz = blockIdx.z;
    int x0 = blockIdx.x * 32, y0 = blockIdx.y * 32;
    const float* sp = scores + bz * HW;
    for (int t = threadIdx.x; t < 1600; t += 256) {
        int ly = t / 40, lx = t - ly * 40;
        int gy = y0 - 4 + ly, gx = x0 - 4 + lx;
        tile[ly][lx] = (gy >= 0 && gy < H && gx >= 0 && gx < W) ? sp[gy * W + gx] : -INFINITY;
    }
    __syncthreads();
    for (int t = threadIdx.x; t < 1280; t += 256) {
        int ly = t >> 5, lx = t & 31;
        hm[ly][lx] = MAX9(&tile[ly][0], lx, 1);
    }
    __syncthreads();
    for (int t = threadIdx.x; t < 1024; t += 256) {
        int ly = t >> 5, lx = t & 31;
        float m = MAX9(&hm[0][0], ly * 32 + lx, 32);
        float s = tile[ly + 4][lx + 4];
        mask[bz * HW + (y0 + ly) * W + x0 + lx] = (s == m) ? 1.0f : 0.0f;
    }
}

// ===== NMS stage 2: remaining 4 pools (2 NMS iterations) fused in LDS + compaction =====
__global__ __launch_bounds__(512) void nms2_compact(const float* __restrict__ scores,
                                                    const float* __restrict__ mask0,
                                                    unsigned long long* __restrict__ cand,
                                                    int* __restrict__ cnt) {
    __shared__ float Sm[56 * 56];   // S on local [4,60)
    __shared__ float Mm[64 * 64];   // mask on local [0,64)
    __shared__ float Zm[56 * 56];   // Z on local [4,60)
    __shared__ float Tm[64 * 56];   // h-pass temp
    __shared__ int lcnt, gbase;
    int bz = blockIdx.z;
    int x0 = blockIdx.x * 32, y0 = blockIdx.y * 32;
    const float* sp = scores + bz * HW;
    const float* mp = mask0 + bz * HW;
    if (threadIdx.x == 0) lcnt = 0;
    for (int t = threadIdx.x; t < 4096; t += 512) {
        int ly = t >> 6, lx = t & 63;
        int gy = y0 - 16 + ly, gx = x0 - 16 + lx;
        Mm[t] = (gy >= 0 && gy < H && gx >= 0 && gx < W) ? mp[gy * W + gx] : 0.0f;
    }
    for (int t = threadIdx.x; t < 3136; t += 512) {
        int i = t / 56, j = t - i * 56;
        int gy = y0 - 12 + i, gx = x0 - 12 + j;
        Sm[t] = (gy >= 0 && gy < H && gx >= 0 && gx < W) ? sp[gy * W + gx] : -1.0f;
    }
    __syncthreads();
    for (int t = threadIdx.x; t < 3584; t += 512) {
        int i = t / 56, c = t - i * 56;
        Tm[i * 56 + c] = MAX9(Mm, i * 64 + c, 1);
    }
    __syncthreads();
    for (int t = threadIdx.x; t < 3136; t += 512) {
        int i = t / 56, c = t - i * 56;
        float m = MAX9(Tm, i * 56 + c, 56);
        Zm[t] = (m > 0.0f) ? -1.0f : Sm[t];
    }
    __syncthreads();
    for (int t = threadIdx.x; t < 2688; t += 512) {
        int i = t / 48, c = t - i * 48;
        Tm[i * 56 + c] = MAX9(Zm, i * 56 + c, 1);
    }
    __syncthreads();
    for (int t = threadIdx.x; t < 2304; t += 512) {
        int r = t / 48, c = t - r * 48;
        float m = MAX9(Tm, r * 56 + c, 56);
        float Zc = Zm[(r + 4) * 56 + c + 4];
        int mi = (r + 8) * 64 + c + 8;
        bool nm = (Zc == m) && (Zc >= 0.0f);
        Mm[mi] = (Mm[mi] != 0.0f || nm) ? 1.0f : 0.0f;
    }
    __syncthreads();
    for (int t = threadIdx.x; t < 1920; t += 512) {
        int r = t / 40, c = t - r * 40;
        Tm[r * 56 + c] = MAX9(Mm, (r + 8) * 64 + c + 8, 1);
    }
    __syncthreads();
    for (int t = threadIdx.x; t < 1600; t += 512) {
        int r = t / 40, c = t - r * 40;
        float m = MAX9(Tm, r * 56 + c, 56);
        int zi = (r + 8) * 56 + c + 8;
        Zm[zi] = (m > 0.0f) ? -1.0f : Sm[zi];
    }
    __syncthreads();
    for (int t = threadIdx.x; t < 1280; t += 512) {
        int r = t / 32, c = t & 31;
        Tm[r * 56 + c] = MAX9(Zm, (r + 8) * 56 + c + 8, 1);
    }
    __syncthreads();
    unsigned long long keys[2];
    int nl = 0;
    #pragma unroll
    for (int q = 0; q < 2; ++q) {
        int t = threadIdx.x + q * 512;
        int r3 = t >> 5, c = t & 31;
        float m = MAX9(Tm, r3 * 56 + c, 56);
        float Zc = Zm[(r3 + 12) * 56 + c + 12];
        bool fin = (Mm[(r3 + 16) * 64 + c + 16] != 0.0f) || ((Zc == m) && (Zc >= 0.0f));
        int gy = y0 + r3, gx = x0 + c;
        float sc = Sm[(r3 + 12) * 56 + c + 12];
        if (fin && gy >= 4 && gy < H - 4 && gx >= 4 && gx < W - 4 && sc > THRESH) {
            unsigned r = (unsigned)(gy * W + gx);
            unsigned bits = __float_as_uint(sc) | 0x80000000u;
            keys[nl++] = ((unsigned long long)bits << 32) |
                         (unsigned long long)(0xFFFFFFFFu - r);
        }
    }
    int lpos = 0;
    if (nl) lpos = atomicAdd(&lcnt, nl);
    __syncthreads();
    if (threadIdx.x == 0) gbase = (lcnt > 0) ? atomicAdd(&cnt[bz * 64], lcnt) : 0;
    __syncthreads();
    for (int j = 0; j < nl; ++j) {
        int p = gbase + lpos + j;
        if (p < CAP) cand[(size_t)bz * CAP + p] = keys[j];
    }
}

// ===== topk: TWO-LEVEL histogram select + bitonic; perm via LDS counting sort =====
__global__ __launch_bounds__(1024) void topk(const unsigned long long* __restrict__ cand,
                                             const int* __restrict__ cnt,
                                             float* __restrict__ out, int* __restrict__ fidx,
                                             int* __restrict__ perm) {
    __shared__ int hist[2048];
    __shared__ unsigned long long buf[4096];
    __shared__ int scnt, spiv1, spiv2, sabove;
    int b = blockIdx.x, tid = threadIdx.x;
    int m = cnt[b * 64]; if (m > CAP) m = CAP;
    const unsigned long long* cb = cand + (size_t)b * CAP;
    int target = (m < 1024) ? m : 1024;

    hist[tid] = 0; hist[tid + 1024] = 0;
    if (tid == 0) { scnt = 0; spiv1 = 2048; spiv2 = 0; sabove = 0; }
    __syncthreads();
    for (int i = tid; i < m; i += 1024)
        atomicAdd(&hist[(int)(cb[i] >> 53) & 0x7FF], 1);
    __syncthreads();
    for (int d = 1; d < 2048; d <<= 1) {
        int v0 = hist[tid] + ((tid + d < 2048) ? hist[tid + d] : 0);
        int v1 = hist[tid + 1024] + ((tid + 1024 + d < 2048) ? hist[tid + 1024 + d] : 0);
        __syncthreads();
        hist[tid] = v0; hist[tid + 1024] = v1;
        __syncthreads();
    }
    if (target > 0) {
        for (int t = tid; t < 2048; t += 1024) {
            int c = hist[t];
            int cn = (t < 2047) ? hist[t + 1] : 0;
            if (c >= target && cn < target) { spiv1 = t; sabove = cn; }
        }
    }
    __syncthreads();
    int piv1 = spiv1;
    int target2 = target - sabove;
    hist[tid] = 0; hist[tid + 1024] = 0;
    __syncthreads();
    for (int i = tid; i < m; i += 1024) {
        unsigned long long k = cb[i];
        if (((int)(k >> 53) & 0x7FF) == piv1)
            atomicAdd(&hist[(int)(k >> 42) & 0x7FF], 1);
    }
    __syncthreads();
    for (int d = 1; d < 2048; d <<= 1) {
        int v0 = hist[tid] + ((tid + d < 2048) ? hist[tid + d] : 0);
        int v1 = hist[tid + 1024] + ((tid + 1024 + d < 2048) ? hist[tid + 1024 + d] : 0);
        __syncthreads();
        hist[tid] = v0; hist[tid + 1024] = v1;
        __syncthreads();
    }
    if (target > 0) {
        for (int t = tid; t < 2048; t += 1024) {
            int c = hist[t];
            int cn = (t < 2047) ? hist[t + 1] : 0;
            if (c >= target2 && cn < target2) spiv2 = t;
        }
    }
    __syncthreads();
    int piv2 = spiv2;
    for (int i = tid; i < m; i += 1024) {
        unsigned long long k = cb[i];
        int b1 = (int)(k >> 53) & 0x7FF;
        bool sel = (target > 0) &&
                   (b1 > piv1 || (b1 == piv1 && (((int)(k >> 42) & 0x7FF) >= piv2)));
        if (sel) {
            int p = atomicAdd(&scnt, 1);
            if (p < 4096) buf[p] = k;
        }
    }
    __syncthreads();
    int sc_ = scnt; if (sc_ > 4096) sc_ = 4096;
    int ns = 1024; while (ns < sc_) ns <<= 1;
    for (int t = tid; t < ns; t += 1024) if (t >= sc_) buf[t] = 0ULL;
    __syncthreads();
    for (int k = 2; k <= ns; k <<= 1)
        for (int j = k >> 1; j > 0; j >>= 1) {
            __syncthreads();
            for (int t = tid; t < ns; t += 1024) {
                int ixj = t ^ j;
                if (ixj > t) {
                    unsigned long long a = buf[t], bb = buf[ixj];
                    if (((t & k) == 0) ? (a < bb) : (a > bb)) { buf[t] = bb; buf[ixj] = a; }
                }
            }
        }
    __syncthreads();
    unsigned long long key = buf[tid];
    float kx, ky, sc;
    unsigned idx;
    if (key != 0ULL) {
        unsigned ord = (unsigned)(key >> 32);
        sc = __uint_as_float(ord ^ 0x80000000u);
        idx = 0xFFFFFFFFu - (unsigned)(key & 0xFFFFFFFFu);
        kx = (float)(idx % W);
        ky = (float)(idx / W);
    } else {
        sc = -1.0f; idx = 0; kx = 0.0f; ky = 0.0f;
    }
    int bn = b * NKP + tid;
    out[bn * 2 + 0] = kx;
    out[bn * 2 + 1] = ky;
    out[B * NKP * 2 + bn] = sc;
    fidx[bn] = (int)idx;
    __syncthreads();
    // spatial perm via counting sort on pixel bucket (idx>>10 in [0,300)).
    if (tid < 512) { hist[tid] = 0; hist[tid + 1024] = 0; }
    __syncthreads();
    int bucket = (int)(idx >> 10);
    atomicAdd(&hist[bucket], 1);
    __syncthreads();
    if (tid < 512) hist[512 + tid] = hist[tid];
    __syncthreads();
    for (int d = 1; d < 512; d <<= 1) {
        int v = 0;
        if (tid < 512) v = hist[512 + tid] + ((tid >= d) ? hist[512 + tid - d] : 0);
        __syncthreads();
        if (tid < 512) hist[512 + tid] = v;
        __syncthreads();
    }
    int intra = atomicAdd(&hist[1024 + bucket], 1);
    int pos = hist[512 + bucket] - hist[bucket] + intra;   // exclusive base + slot
    perm[b * NKP + pos] = tid;
}

// ===== sample_all: wave-per-keypoint, barrier-free; seg3 reads NHWC d4T =====
__global__ __launch_bounds__(256) void sample_all(const float* __restrict__ d1,
                                                  const float* __restrict__ d2,
                                                  const float* __restrict__ cDa,
                                                  const float* __restrict__ d4T,
                                                  const int* __restrict__ fidx,
                                                  const int* __restrict__ perm,
                                                  short* __restrict__ X) {
    int lane = threadIdx.x & 63;
    int wv = threadIdx.x >> 6;
    int seg = blockIdx.y;
    int bid = blockIdx.x;
    int swz = ((bid & 7) << 7) | (bid >> 3);
    int b = swz >> 8;                  // 256 chunks per batch
    int g0 = ((swz & 255) << 2) + wv;  // kp slot within batch

    const float* map; int h, w, s, C, base, nset;
    if (seg == 0)      { map = d1;  h = 240; w = 320; s = 2;  C = 64;  base = 0;   nset = 1; }
    else if (seg == 1) { map = d2;  h = 120; w = 160; s = 4;  C = 128; base = 64;  nset = 2; }
    else if (seg == 2) { map = cDa; h = 60;  w = 80;  s = 8;  C = 256; base = 192; nset = 4; }
    else               { map = d4T; h = 30;  w = 40;  s = 16; C = 256; base = 448; nset = 4; }

    int col = (b << 10) | perm[(b << 10) + g0];
    int idx = fidx[col];
    float kx = (float)(idx % W);
    float ky = (float)(idx / W);
    float kxs = kx - (float)s * 0.5f + 0.5f;
    float kys = ky - (float)s * 0.5f + 0.5f;
    float gx = kxs / (float)(w * s - 1) * 2.0f - 1.0f;
    float gy = kys / (float)(h * s - 1) * 2.0f - 1.0f;
    float x = (gx + 1.0f) * 0.5f * (float)(w - 1);
    float y = (gy + 1.0f) * 0.5f * (float)(h - 1);
    float x0f = floorf(x), y0f = floorf(y);
    int x0 = (int)x0f, y0 = (int)y0f;
    float wx1 = x - x0f, wy1 = y - y0f;
    float wx0 = 1.0f - wx1, wy0 = 1.0f - wy1;
    bool vx0 = (x0 >= 0) && (x0 < w);
    bool vx1 = (x0 + 1 >= 0) && (x0 + 1 < w);
    bool vy0 = (y0 >= 0) && (y0 < h);
    bool vy1 = (y0 + 1 >= 0) && (y0 + 1 < h);
    int xc0 = min(max(x0, 0), w - 1), xc1 = min(max(x0 + 1, 0), w - 1);
    int yc0 = min(max(y0, 0), h - 1), yc1 = min(max(y0 + 1, 0), h - 1);
    float w00 = (vx0 && vy0) ? wx0 * wy0 : 0.0f;
    float w01 = (vx1 && vy0) ? wx1 * wy0 : 0.0f;
    float w10 = (vx0 && vy1) ? wx0 * wy1 : 0.0f;
    float w11 = (vx1 && vy1) ? wx1 * wy1 : 0.0f;

    float vals[4];
    float r = 0.0f;
    if (seg == 3) {
        const float* pt = d4T + ((size_t)b * 1200) * 256 + lane;
        size_t o00 = ((size_t)(yc0 * 40 + xc0)) << 8;
        size_t o01 = ((size_t)(yc0 * 40 + xc1)) << 8;
        size_t o10 = ((size_t)(yc1 * 40 + xc0)) << 8;
        size_t o11 = ((size_t)(yc1 * 40 + xc1)) << 8;
        float q00[4], q01[4], q10[4], q11[4];
        #pragma unroll
        for (int j = 0; j < 4; ++j) {
            q00[j] = pt[o00 + j * 64]; q01[j] = pt[o01 + j * 64];
            q10[j] = pt[o10 + j * 64]; q11[j] = pt[o11 + j * 64];
        }
        #pragma unroll
        for (int j = 0; j < 4; ++j) {
            vals[j] = q00[j] * w00 + q01[j] * w01 + q10[j] * w10 + q11[j] * w11;
            r += vals[j] * vals[j];
        }
    } else {
        int xb = min(xc0, w - 2);
        float s0 = (xc0 == xb) ? 1.0f : 0.0f;
        float s1 = (xc1 == xb) ? 1.0f : 0.0f;
        float ax = w00 * s0 + w01 * s1;
        float ay = w00 * (1.0f - s0) + w01 * (1.0f - s1);
        float bx = w10 * s0 + w11 * s1;
        float by = w10 * (1.0f - s0) + w11 * (1.0f - s1);
        size_t hw = (size_t)(h * w);
        const float* pb = map + ((size_t)b * C + lane) * hw;
        size_t off0 = (size_t)yc0 * w + xb;
        size_t off1 = (size_t)yc1 * w + xb;
        size_t cstr = hw << 6;   // 64 channel-planes
        f2u q0[4], q1[4];
        #pragma unroll
        for (int j = 0; j < 4; ++j) {
            if (j < nset) {
                const float* p = pb + (size_t)j * cstr;
                q0[j] = *(const f2u*)(p + off0);
                q1[j] = *(const f2u*)(p + off1);
            }
        }
        #pragma unroll
        for (int j = 0; j < 4; ++j) {
            if (j < nset) {
                vals[j] = q0[j].x * ax + q0[j].y * ay + q1[j].x * bx + q1[j].y * by;
                r += vals[j] * vals[j];
            }
        }
    }
    #pragma unroll
    for (int off = 32; off > 0; off >>= 1) r += __shfl_xor(r, off, 64);
    float denom = fmaxf(sqrtf(r), 1e-12f);
    float inv = 1.0f / denom;
    short* xp = X + (size_t)col * KTOT + base + lane;
    #pragma unroll
    for (int j = 0; j < 4; ++j) {
        if (j < nset) xp[j * 64] = f2bf(vals[j] * inv);
    }
}

// ===== GEMM (bf16 MFMA): out[256,4096] = Mw[256,704] * X^T + bias; bf16 inputs =====
__global__ __launch_bounds__(256) void gemm_mfma(const short* __restrict__ Mw,
                                                 const short* __restrict__ X,
                                                 const float* __restrict__ biasf,
                                                 float* __restrict__ out) {
    __shared__ short As[64 * 72];
    __shared__ short Bs[64 * 72];
    int tid = threadIdx.x;
    int lane = tid & 63, w = tid >> 6;
    int r = lane & 15, quad = lane >> 4;
    int rowBase = blockIdx.y * 64, colBase = blockIdx.x * 64;
    int sm = tid >> 2, skq = (tid & 3) << 4;   // 16 shorts (32B) per thread per tile

    const short* pa = Mw + (size_t)(rowBase + sm) * KTOT + skq;
    const short* pb = X + (size_t)(colBase + sm) * KTOT + skq;
    s8v a0 = *(const s8v*)(pa), a1 = *(const s8v*)(pa + 8);
    s8v b0 = *(const s8v*)(pb), b1 = *(const s8v*)(pb + 8);

    f4v acc[4];
    #pragma unroll
    for (int t = 0; t < 4; ++t) acc[t] = (f4v)0.0f;

    for (int kt = 0; kt < 11; ++kt) {
        __syncthreads();
        *(s8v*)&As[sm * 72 + skq + 0] = a0;
        *(s8v*)&As[sm * 72 + skq + 8] = a1;
        *(s8v*)&Bs[sm * 72 + skq + 0] = b0;
        *(s8v*)&Bs[sm * 72 + skq + 8] = b1;
        __syncthreads();
        if (kt < 10) {
            pa += 64; pb += 64;
            a0 = *(const s8v*)(pa); a1 = *(const s8v*)(pa + 8);
            b0 = *(const s8v*)(pb); b1 = *(const s8v*)(pb + 8);
        }
        #pragma unroll
        for (int kk = 0; kk < 2; ++kk) {
            int aoff = (w * 16 + r) * 72 + kk * 32 + quad * 8;
            s8v af = *(const s8v*)&As[aoff];
            #pragma unroll
            for (int t = 0; t < 4; ++t) {
                int boff = (t * 16 + r) * 72 + kk * 32 + quad * 8;
                s8v bf = *(const s8v*)&Bs[boff];
                acc[t] = __builtin_amdgcn_mfma_f32_16x16x32_bf16(af, bf, acc[t], 0, 0, 0);
            }
        }
    }
    #pragma unroll
    for (int t = 0; t < 4; ++t) {
        int colg = colBase + t * 16 + r;
        size_t obase = (size_t)(colg >> 10) * (256 * NKP) + (size_t)(colg & 1023);
        #pragma unroll
        for (int reg = 0; reg < 4; ++reg) {
            int row = rowBase + w * 16 + quad * 4 + reg;
            out[obase + (size_t)row * NKP] = acc[t][reg] + biasf[row];
        }
    }
}

// ================= launch =================
extern "C" void kernel_launch(void* const* d_in, const int* in_sizes, int n_in,
                              void* d_out, int out_size, void* d_ws, size_t ws_size,
                              hipStream_t stream) {
    const float* scores  = (const float*)d_in[0];
    const float* d1      = (const float*)d_in[1];
    const float* d2      = (const float*)d_in[2];
    const float* cDa     = (const float*)d_in[3];
    const float* d4      = (const float*)d_in[4];
    const float* lin0_w  = (const float*)d_in[5];
    const float* lin0_b  = (const float*)d_in[6];
    const float* lin1_w  = (const float*)d_in[7];
    const float* lin1_b  = (const float*)d_in[8];
    const float* lin2_w  = (const float*)d_in[9];
    const float* lin2_b  = (const float*)d_in[10];
    const float* merge_w = (const float*)d_in[11];
    const float* merge_b = (const float*)d_in[12];
    float* out = (float*)d_out;

    char* ws = (char*)d_ws;
    float* MASK = (float*)ws;                                          // 4.9 MB (nms phase)
    short* Xbuf = (short*)ws;                                          // 5.77 MB (post-topk; aliases MASK)
    float* d4T  = (float*)(ws + 6291456);                              // 4,915,200 B (free gap)
    unsigned long long* cand  = (unsigned long long*)(ws + 14745600);  // 524,288 B
    int* cnt                  = (int*)(ws + 15269888);                 // 1,024 B
    int* fidx                 = (int*)(ws + 15401984);                 // 16,384 B
    short* Mw                 = (short*)(ws + 15418368);               // 360,448 B (bf16)
    float* biasf              = (float*)(ws + 16139264);               // 1,024 B
    int* perm                 = (int*)(ws + 16140288);                 // 16,384 B

    dim3 tgrid(W / 32, H / 32, B);   // (20,15,4)

    fuse_w<<<dim3(11, 256), 256, 0, stream>>>(merge_w, lin0_w, lin1_w, lin2_w, Mw);
    fuse_bias<<<64, 256, 0, stream>>>(merge_w, merge_b, lin0_b, lin1_b, lin2_b, biasf, cnt);
    transpose_d4<<<dim3(19, 4, 4), 256, 0, stream>>>(d4, d4T);
    nms1<<<tgrid, 256, 0, stream>>>(scores, MASK);
    nms2_compact<<<tgrid, 512, 0, stream>>>(scores, MASK, cand, cnt);
    topk<<<B, 1024, 0, stream>>>(cand, cnt, out, fidx, perm);
    sample_all<<<dim3(1024, 4), 256, 0, stream>>>(d1, d2, cDa, d4T, fidx, perm, Xbuf);
    gemm_mfma<<<dim3(NCOL / 64, 256 / 64), 256, 0, stream>>>(Mw, Xbuf, biasf, out + B * NKP * 3);
}

// Round 9
// 310.166 us; speedup vs baseline: 1.3585x; 1.0065x over previous
//
#include <hip/hip_runtime.h>
#include <hip/hip_bf16.h>

#define B 4
#define H 480
#define W 640
#define HW (H*W)
#define BHW (B*H*W)
#define NKP 1024
#define THRESH 0.005f
#define CAP 16384
#define NCOL (B*NKP)
#define KTOT 704

typedef __attribute__((ext_vector_type(8))) short s8v;
typedef __attribute__((ext_vector_type(4))) float f4v;
typedef struct { float x, y; } __attribute__((aligned(4))) f2u;   // 4B-aligned pair load

__device__ __forceinline__ short f2bf(float f) {
    __hip_bfloat16 h = __float2bfloat16(f);
    return *(short*)&h;
}

__device__ __forceinline__ float max3f(float a, float b, float c) {
    return fmaxf(fmaxf(a, b), c);     // clang fuses to v_max3_f32
}
// 9-wide max as a depth-2 tree of v_max3_f32 (4 instrs vs 8-deep chain)
#define MAX9(A, base, str) \
    max3f(max3f((A)[(base)], (A)[(base)+(str)], (A)[(base)+2*(str)]), \
          max3f((A)[(base)+3*(str)], (A)[(base)+4*(str)], (A)[(base)+5*(str)]), \
          max3f((A)[(base)+6*(str)], (A)[(base)+7*(str)], (A)[(base)+8*(str)]))

// ===== fuse_w: Mw[256,704] weight fold; block=(64 cols x 4 K-slice waves) =====
__global__ __launch_bounds__(256) void fuse_w(const float* __restrict__ merge_w,
                                              const float* __restrict__ lin0_w,
                                              const float* __restrict__ lin1_w,
                                              const float* __restrict__ lin2_w,
                                              short* __restrict__ Mw) {
    __shared__ float red[4][64];
    int lane = threadIdx.x & 63;
    int wv = threadIdx.x >> 6;
    int jb = blockIdx.x;           // 0..10
    int o = blockIdx.y;            // 0..255
    int j = jb * 64 + lane;
    const float* mwr = merge_w + (size_t)o * KTOT;

    if (jb >= 3 && jb <= 6) {      // cols 192..447: pure copy
        if (wv == 0) Mw[(size_t)o * KTOT + j] = f2bf(mwr[j]);
        return;
    }
    float acc = 0.0f;
    if (jb == 0) {                 // K=64, slice 16/wave
        int k0 = wv * 16;
        #pragma unroll
        for (int k = 0; k < 16; ++k)
            acc += mwr[k0 + k] * lin2_w[(k0 + k) * 64 + lane];
    } else if (jb <= 2) {          // K=128, slice 32/wave
        int jj = (jb - 1) * 64 + lane;
        int k0 = wv * 32;
        #pragma unroll
        for (int k = 0; k < 32; ++k)
            acc += mwr[64 + k0 + k] * lin1_w[(k0 + k) * 128 + jj];
    } else {                       // jb 7..10: K=256, slice 64/wave
        int jj = (jb - 7) * 64 + lane;
        int k0 = wv * 64;
        #pragma unroll
        for (int k = 0; k < 64; ++k)
            acc += mwr[448 + k0 + k] * lin0_w[(k0 + k) * 256 + jj];
    }
    red[wv][lane] = acc;
    __syncthreads();
    if (wv == 0) {
        float t = red[0][lane] + red[1][lane] + red[2][lane] + red[3][lane];
        Mw[(size_t)o * KTOT + j] = f2bf(t);
    }
}

// ===== fuse_bias: biasf[256] via wave-per-row shuffle reduce; zeroes cnt =====
__global__ __launch_bounds__(256) void fuse_bias(const float* __restrict__ merge_w,
                                                 const float* __restrict__ merge_b,
                                                 const float* __restrict__ lin0_b,
                                                 const float* __restrict__ lin1_b,
                                                 const float* __restrict__ lin2_b,
                                                 float* __restrict__ biasf,
                                                 int* __restrict__ cnt) {
    int lane = threadIdx.x & 63;
    int wv = threadIdx.x >> 6;
    int o = blockIdx.x * 4 + wv;
    if (blockIdx.x == 0 && threadIdx.x < 4) cnt[threadIdx.x * 64] = 0;
    const float* mwr = merge_w + (size_t)o * KTOT;
    float acc = 0.0f;
    #pragma unroll
    for (int i = 0; i < 11; ++i) {
        int k = i * 64 + lane;
        float c;
        if (k < 64) c = lin2_b[k];
        else if (k < 192) c = lin1_b[k - 64];
        else if (k < 448) c = 0.0f;
        else c = lin0_b[k - 448];
        acc += mwr[k] * c;
    }
    #pragma unroll
    for (int off = 32; off > 0; off >>= 1) acc += __shfl_xor(acc, off, 64);
    if (lane == 0) biasf[o] = merge_b[o] + acc;
}

// ===== transpose_d4: d4 [B][256][30][40] -> d4T [B][1200][256] (f32, exact) =====
__global__ __launch_bounds__(256) void transpose_d4(const float* __restrict__ d4,
                                                    float* __restrict__ d4T) {
    __shared__ float T[64][65];
    int b = blockIdx.z;
    int p0 = blockIdx.x * 64;   // pixel tile (19 tiles over 1200)
    int c0 = blockIdx.y * 64;   // channel tile (4 tiles over 256)
    for (int t = threadIdx.x; t < 4096; t += 256) {
        int ch = t >> 6, px = t & 63;            // px fast -> coalesced read
        int gp = p0 + px;
        if (gp < 1200)
            T[ch][px] = d4[((size_t)(b * 256 + c0 + ch)) * 1200 + gp];
    }
    __syncthreads();
    for (int t = threadIdx.x; t < 4096; t += 256) {
        int px = t >> 6, ch = t & 63;            // ch fast -> coalesced write
        int gp = p0 + px;
        if (gp < 1200)
            d4T[((size_t)(b * 1200 + gp)) * 256 + c0 + ch] = T[ch][px];
    }
}

// ===== nms_fused: mask0 recomputed in-LDS (nms1 folded in) + 4 pools + compaction =====
// S72 = scores tile with 20-halo; mask0 = (S == pool9(S)) computed locally.
// Pad = -1.0f is exact: scores >= 0 and every in-bounds 9x9 window contains its
// own center, so the max never comes from the pad (equivalent to -inf here).
__global__ __launch_bounds__(512) void nms_fused(const float* __restrict__ scores,
                                                 unsigned long long* __restrict__ cand,
                                                 int* __restrict__ cnt) {
    __shared__ float S72[72 * 72];   // scores, local (i,j) = global (y0-20+i, x0-20+j)
    __shared__ float T72[72 * 64];   // H-pass temp (stride 64); later reused as Tm (stride 56)
    __shared__ float Mm[64 * 64];    // mask on local [0,64) = global y0-16..y0+47
    __shared__ float Zm[56 * 56];    // Z on local [4,60) of the 56-tile
    __shared__ int lcnt, gbase;
    int bz = blockIdx.z;
    int x0 = blockIdx.x * 32, y0 = blockIdx.y * 32;
    const float* sp = scores + bz * HW;
    if (threadIdx.x == 0) lcnt = 0;
    for (int t = threadIdx.x; t < 5184; t += 512) {
        int i = t / 72, j = t - i * 72;
        int gy = y0 - 20 + i, gx = x0 - 20 + j;
        S72[t] = (gy >= 0 && gy < H && gx >= 0 && gx < W) ? sp[gy * W + gx] : -1.0f;
    }
    __syncthreads();
    // mask0 H-pass: 72 rows x 64 cols (col c -> S72 cols c..c+8)
    for (int t = threadIdx.x; t < 4608; t += 512) {
        int i = t >> 6, c = t & 63;
        T72[i * 64 + c] = MAX9(S72, i * 72 + c, 1);
    }
    __syncthreads();
    // mask0 V-pass + compare: Mm[r][c], global (y0-16+r, x0-16+c)
    for (int t = threadIdx.x; t < 4096; t += 512) {
        int r = t >> 6, c = t & 63;
        float m = MAX9(T72, r * 64 + c, 64);
        float s = S72[(r + 4) * 72 + c + 4];
        int gy = y0 - 16 + r, gx = x0 - 16 + c;
        Mm[t] = (gy >= 0 && gy < H && gx >= 0 && gx < W && s == m) ? 1.0f : 0.0f;
    }
    __syncthreads();
    float* Tm = T72;   // reuse (consumed above; barrier-separated)
    for (int t = threadIdx.x; t < 3584; t += 512) {
        int i = t / 56, c = t - i * 56;
        Tm[i * 56 + c] = MAX9(Mm, i * 64 + c, 1);
    }
    __syncthreads();
    for (int t = threadIdx.x; t < 3136; t += 512) {
        int i = t / 56, j = t - i * 56;
        float m = MAX9(Tm, i * 56 + j, 56);
        Zm[t] = (m > 0.0f) ? -1.0f : S72[(i + 8) * 72 + (j + 8)];
    }
    __syncthreads();
    for (int t = threadIdx.x; t < 2688; t += 512) {
        int i = t / 48, c = t - i * 48;
        Tm[i * 56 + c] = MAX9(Zm, i * 56 + c, 1);
    }
    __syncthreads();
    for (int t = threadIdx.x; t < 2304; t += 512) {
        int r = t / 48, c = t - r * 48;
        float m = MAX9(Tm, r * 56 + c, 56);
        float Zc = Zm[(r + 4) * 56 + c + 4];
        int mi = (r + 8) * 64 + c + 8;
        bool nm = (Zc == m) && (Zc >= 0.0f);
        Mm[mi] = (Mm[mi] != 0.0f || nm) ? 1.0f : 0.0f;
    }
    __syncthreads();
    for (int t = threadIdx.x; t < 1920; t += 512) {
        int r = t / 40, c = t - r * 40;
        Tm[r * 56 + c] = MAX9(Mm, (r + 8) * 64 + c + 8, 1);
    }
    __syncthreads();
    for (int t = threadIdx.x; t < 1600; t += 512) {
        int r = t / 40, c = t - r * 40;
        float m = MAX9(Tm, r * 56 + c, 56);
        int zi = (r + 8) * 56 + c + 8;
        Zm[zi] = (m > 0.0f) ? -1.0f : S72[(r + 16) * 72 + (c + 16)];
    }
    __syncthreads();
    for (int t = threadIdx.x; t < 1280; t += 512) {
        int r = t / 32, c = t & 31;
        Tm[r * 56 + c] = MAX9(Zm, (r + 8) * 56 + c + 8, 1);
    }
    __syncthreads();
    unsigned long long keys[2];
    int nl = 0;
    #pragma unroll
    for (int q = 0; q < 2; ++q) {
        int t = threadIdx.x + q * 512;
        int r3 = t >> 5, c = t & 31;
        float m = MAX9(Tm, r3 * 56 + c, 56);
        float Zc = Zm[(r3 + 12) * 56 + c + 12];
        bool fin = (Mm[(r3 + 16) * 64 + c + 16] != 0.0f) || ((Zc == m) && (Zc >= 0.0f));
        int gy = y0 + r3, gx = x0 + c;
        float sc = S72[(r3 + 20) * 72 + (c + 20)];
        if (fin && gy >= 4 && gy < H - 4 && gx >= 4 && gx < W - 4 && sc > THRESH) {
            unsigned r = (unsigned)(gy * W + gx);
            unsigned bits = __float_as_uint(sc) | 0x80000000u;
            keys[nl++] = ((unsigned long long)bits << 32) |
                         (unsigned long long)(0xFFFFFFFFu - r);
        }
    }
    int lpos = 0;
    if (nl) lpos = atomicAdd(&lcnt, nl);
    __syncthreads();
    if (threadIdx.x == 0) gbase = (lcnt > 0) ? atomicAdd(&cnt[bz * 64], lcnt) : 0;
    __syncthreads();
    for (int j = 0; j < nl; ++j) {
        int p = gbase + lpos + j;
        if (p < CAP) cand[(size_t)bz * CAP + p] = keys[j];
    }
}

// ===== topk: TWO-LEVEL histogram select + bitonic; perm via LDS counting sort =====
__global__ __launch_bounds__(1024) void topk(const unsigned long long* __restrict__ cand,
                                             const int* __restrict__ cnt,
                                             float* __restrict__ out, int* __restrict__ fidx,
                                             int* __restrict__ perm) {
    __shared__ int hist[2048];
    __shared__ unsigned long long buf[4096];
    __shared__ int scnt, spiv1, spiv2, sabove;
    int b = blockIdx.x, tid = threadIdx.x;
    int m = cnt[b * 64]; if (m > CAP) m = CAP;
    const unsigned long long* cb = cand + (size_t)b * CAP;
    int target = (m < 1024) ? m : 1024;

    hist[tid] = 0; hist[tid + 1024] = 0;
    if (tid == 0) { scnt = 0; spiv1 = 2048; spiv2 = 0; sabove = 0; }
    __syncthreads();
    for (int i = tid; i < m; i += 1024)
        atomicAdd(&hist[(int)(cb[i] >> 53) & 0x7FF], 1);
    __syncthreads();
    for (int d = 1; d < 2048; d <<= 1) {
        int v0 = hist[tid] + ((tid + d < 2048) ? hist[tid + d] : 0);
        int v1 = hist[tid + 1024] + ((tid + 1024 + d < 2048) ? hist[tid + 1024 + d] : 0);
        __syncthreads();
        hist[tid] = v0; hist[tid + 1024] = v1;
        __syncthreads();
    }
    if (target > 0) {
        for (int t = tid; t < 2048; t += 1024) {
            int c = hist[t];
            int cn = (t < 2047) ? hist[t + 1] : 0;
            if (c >= target && cn < target) { spiv1 = t; sabove = cn; }
        }
    }
    __syncthreads();
    int piv1 = spiv1;
    int target2 = target - sabove;
    hist[tid] = 0; hist[tid + 1024] = 0;
    __syncthreads();
    for (int i = tid; i < m; i += 1024) {
        unsigned long long k = cb[i];
        if (((int)(k >> 53) & 0x7FF) == piv1)
            atomicAdd(&hist[(int)(k >> 42) & 0x7FF], 1);
    }
    __syncthreads();
    for (int d = 1; d < 2048; d <<= 1) {
        int v0 = hist[tid] + ((tid + d < 2048) ? hist[tid + d] : 0);
        int v1 = hist[tid + 1024] + ((tid + 1024 + d < 2048) ? hist[tid + 1024 + d] : 0);
        __syncthreads();
        hist[tid] = v0; hist[tid + 1024] = v1;
        __syncthreads();
    }
    if (target > 0) {
        for (int t = tid; t < 2048; t += 1024) {
            int c = hist[t];
            int cn = (t < 2047) ? hist[t + 1] : 0;
            if (c >= target2 && cn < target2) spiv2 = t;
        }
    }
    __syncthreads();
    int piv2 = spiv2;
    for (int i = tid; i < m; i += 1024) {
        unsigned long long k = cb[i];
        int b1 = (int)(k >> 53) & 0x7FF;
        bool sel = (target > 0) &&
                   (b1 > piv1 || (b1 == piv1 && (((int)(k >> 42) & 0x7FF) >= piv2)));
        if (sel) {
            int p = atomicAdd(&scnt, 1);
            if (p < 4096) buf[p] = k;
        }
    }
    __syncthreads();
    int sc_ = scnt; if (sc_ > 4096) sc_ = 4096;
    int ns = 1024; while (ns < sc_) ns <<= 1;
    for (int t = tid; t < ns; t += 1024) if (t >= sc_) buf[t] = 0ULL;
    __syncthreads();
    for (int k = 2; k <= ns; k <<= 1)
        for (int j = k >> 1; j > 0; j >>= 1) {
            __syncthreads();
            for (int t = tid; t < ns; t += 1024) {
                int ixj = t ^ j;
                if (ixj > t) {
                    unsigned long long a = buf[t], bb = buf[ixj];
                    if (((t & k) == 0) ? (a < bb) : (a > bb)) { buf[t] = bb; buf[ixj] = a; }
                }
            }
        }
    __syncthreads();
    unsigned long long key = buf[tid];
    float kx, ky, sc;
    unsigned idx;
    if (key != 0ULL) {
        unsigned ord = (unsigned)(key >> 32);
        sc = __uint_as_float(ord ^ 0x80000000u);
        idx = 0xFFFFFFFFu - (unsigned)(key & 0xFFFFFFFFu);
        kx = (float)(idx % W);
        ky = (float)(idx / W);
    } else {
        sc = -1.0f; idx = 0; kx = 0.0f; ky = 0.0f;
    }
    int bn = b * NKP + tid;
    out[bn * 2 + 0] = kx;
    out[bn * 2 + 1] = ky;
    out[B * NKP * 2 + bn] = sc;
    fidx[bn] = (int)idx;
    __syncthreads();
    // spatial perm via counting sort on pixel bucket (idx>>10 in [0,300)).
    if (tid < 512) { hist[tid] = 0; hist[tid + 1024] = 0; }
    __syncthreads();
    int bucket = (int)(idx >> 10);
    atomicAdd(&hist[bucket], 1);
    __syncthreads();
    if (tid < 512) hist[512 + tid] = hist[tid];
    __syncthreads();
    for (int d = 1; d < 512; d <<= 1) {
        int v = 0;
        if (tid < 512) v = hist[512 + tid] + ((tid >= d) ? hist[512 + tid - d] : 0);
        __syncthreads();
        if (tid < 512) hist[512 + tid] = v;
        __syncthreads();
    }
    int intra = atomicAdd(&hist[1024 + bucket], 1);
    int pos = hist[512 + bucket] - hist[bucket] + intra;   // exclusive base + slot
    perm[b * NKP + pos] = tid;
}

// ===== sample_all: wave-per-keypoint, barrier-free; seg3 reads NHWC d4T =====
__global__ __launch_bounds__(256) void sample_all(const float* __restrict__ d1,
                                                  const float* __restrict__ d2,
                                                  const float* __restrict__ cDa,
                                                  const float* __restrict__ d4T,
                                                  const int* __restrict__ fidx,
                                                  const int* __restrict__ perm,
                                                  short* __restrict__ X) {
    int lane = threadIdx.x & 63;
    int wv = threadIdx.x >> 6;
    int seg = blockIdx.y;
    int bid = blockIdx.x;
    int swz = ((bid & 7) << 7) | (bid >> 3);
    int b = swz >> 8;                  // 256 chunks per batch
    int g0 = ((swz & 255) << 2) + wv;  // kp slot within batch

    const float* map; int h, w, s, C, base, nset;
    if (seg == 0)      { map = d1;  h = 240; w = 320; s = 2;  C = 64;  base = 0;   nset = 1; }
    else if (seg == 1) { map = d2;  h = 120; w = 160; s = 4;  C = 128; base = 64;  nset = 2; }
    else if (seg == 2) { map = cDa; h = 60;  w = 80;  s = 8;  C = 256; base = 192; nset = 4; }
    else               { map = d4T; h = 30;  w = 40;  s = 16; C = 256; base = 448; nset = 4; }

    int col = (b << 10) | perm[(b << 10) + g0];
    int idx = fidx[col];
    float kx = (float)(idx % W);
    float ky = (float)(idx / W);
    float kxs = kx - (float)s * 0.5f + 0.5f;
    float kys = ky - (float)s * 0.5f + 0.5f;
    float gx = kxs / (float)(w * s - 1) * 2.0f - 1.0f;
    float gy = kys / (float)(h * s - 1) * 2.0f - 1.0f;
    float x = (gx + 1.0f) * 0.5f * (float)(w - 1);
    float y = (gy + 1.0f) * 0.5f * (float)(h - 1);
    float x0f = floorf(x), y0f = floorf(y);
    int x0 = (int)x0f, y0 = (int)y0f;
    float wx1 = x - x0f, wy1 = y - y0f;
    float wx0 = 1.0f - wx1, wy0 = 1.0f - wy1;
    bool vx0 = (x0 >= 0) && (x0 < w);
    bool vx1 = (x0 + 1 >= 0) && (x0 + 1 < w);
    bool vy0 = (y0 >= 0) && (y0 < h);
    bool vy1 = (y0 + 1 >= 0) && (y0 + 1 < h);
    int xc0 = min(max(x0, 0), w - 1), xc1 = min(max(x0 + 1, 0), w - 1);
    int yc0 = min(max(y0, 0), h - 1), yc1 = min(max(y0 + 1, 0), h - 1);
    float w00 = (vx0 && vy0) ? wx0 * wy0 : 0.0f;
    float w01 = (vx1 && vy0) ? wx1 * wy0 : 0.0f;
    float w10 = (vx0 && vy1) ? wx0 * wy1 : 0.0f;
    float w11 = (vx1 && vy1) ? wx1 * wy1 : 0.0f;

    float vals[4];
    float r = 0.0f;
    if (seg == 3) {
        const float* pt = d4T + ((size_t)b * 1200) * 256 + lane;
        size_t o00 = ((size_t)(yc0 * 40 + xc0)) << 8;
        size_t o01 = ((size_t)(yc0 * 40 + xc1)) << 8;
        size_t o10 = ((size_t)(yc1 * 40 + xc0)) << 8;
        size_t o11 = ((size_t)(yc1 * 40 + xc1)) << 8;
        float q00[4], q01[4], q10[4], q11[4];
        #pragma unroll
        for (int j = 0; j < 4; ++j) {
            q00[j] = pt[o00 + j * 64]; q01[j] = pt[o01 + j * 64];
            q10[j] = pt[o10 + j * 64]; q11[j] = pt[o11 + j * 64];
        }
        #pragma unroll
        for (int j = 0; j < 4; ++j) {
            vals[j] = q00[j] * w00 + q01[j] * w01 + q10[j] * w10 + q11[j] * w11;
            r += vals[j] * vals[j];
        }
    } else {
        int xb = min(xc0, w - 2);
        float s0 = (xc0 == xb) ? 1.0f : 0.0f;
        float s1 = (xc1 == xb) ? 1.0f : 0.0f;
        float ax = w00 * s0 + w01 * s1;
        float ay = w00 * (1.0f - s0) + w01 * (1.0f - s1);
        float bx = w10 * s0 + w11 * s1;
        float by = w10 * (1.0f - s0) + w11 * (1.0f - s1);
        size_t hw = (size_t)(h * w);
        const float* pb = map + ((size_t)b * C + lane) * hw;
        size_t off0 = (size_t)yc0 * w + xb;
        size_t off1 = (size_t)yc1 * w + xb;
        size_t cstr = hw << 6;   // 64 channel-planes
        f2u q0[4], q1[4];
        #pragma unroll
        for (int j = 0; j < 4; ++j) {
            if (j < nset) {
                const float* p = pb + (size_t)j * cstr;
                q0[j] = *(const f2u*)(p + off0);
                q1[j] = *(const f2u*)(p + off1);
            }
        }
        #pragma unroll
        for (int j = 0; j < 4; ++j) {
            if (j < nset) {
                vals[j] = q0[j].x * ax + q0[j].y * ay + q1[j].x * bx + q1[j].y * by;
                r += vals[j] * vals[j];
            }
        }
    }
    #pragma unroll
    for (int off = 32; off > 0; off >>= 1) r += __shfl_xor(r, off, 64);
    float denom = fmaxf(sqrtf(r), 1e-12f);
    float inv = 1.0f / denom;
    short* xp = X + (size_t)col * KTOT + base + lane;
    #pragma unroll
    for (int j = 0; j < 4; ++j) {
        if (j < nset) xp[j * 64] = f2bf(vals[j] * inv);
    }
}

// ===== GEMM (bf16 MFMA): out[256,4096] = Mw[256,704] * X^T + bias; bf16 inputs =====
__global__ __launch_bounds__(256) void gemm_mfma(const short* __restrict__ Mw,
                                                 const short* __restrict__ X,
                                                 const float* __restrict__ biasf,
                                                 float* __restrict__ out) {
    __shared__ short As[64 * 72];
    __shared__ short Bs[64 * 72];
    int tid = threadIdx.x;
    int lane = tid & 63, w = tid >> 6;
    int r = lane & 15, quad = lane >> 4;
    int rowBase = blockIdx.y * 64, colBase = blockIdx.x * 64;
    int sm = tid >> 2, skq = (tid & 3) << 4;   // 16 shorts (32B) per thread per tile

    const short* pa = Mw + (size_t)(rowBase + sm) * KTOT + skq;
    const short* pb = X + (size_t)(colBase + sm) * KTOT + skq;
    s8v a0 = *(const s8v*)(pa), a1 = *(const s8v*)(pa + 8);
    s8v b0 = *(const s8v*)(pb), b1 = *(const s8v*)(pb + 8);

    f4v acc[4];
    #pragma unroll
    for (int t = 0; t < 4; ++t) acc[t] = (f4v)0.0f;

    for (int kt = 0; kt < 11; ++kt) {
        __syncthreads();
        *(s8v*)&As[sm * 72 + skq + 0] = a0;
        *(s8v*)&As[sm * 72 + skq + 8] = a1;
        *(s8v*)&Bs[sm * 72 + skq + 0] = b0;
        *(s8v*)&Bs[sm * 72 + skq + 8] = b1;
        __syncthreads();
        if (kt < 10) {
            pa += 64; pb += 64;
            a0 = *(const s8v*)(pa); a1 = *(const s8v*)(pa + 8);
            b0 = *(const s8v*)(pb); b1 = *(const s8v*)(pb + 8);
        }
        #pragma unroll
        for (int kk = 0; kk < 2; ++kk) {
            int aoff = (w * 16 + r) * 72 + kk * 32 + quad * 8;
            s8v af = *(const s8v*)&As[aoff];
            #pragma unroll
            for (int t = 0; t < 4; ++t) {
                int boff = (t * 16 + r) * 72 + kk * 32 + quad * 8;
                s8v bf = *(const s8v*)&Bs[boff];
                acc[t] = __builtin_amdgcn_mfma_f32_16x16x32_bf16(af, bf, acc[t], 0, 0, 0);
            }
        }
    }
    #pragma unroll
    for (int t = 0; t < 4; ++t) {
        int colg = colBase + t * 16 + r;
        size_t obase = (size_t)(colg >> 10) * (256 * NKP) + (size_t)(colg & 1023);
        #pragma unroll
        for (int reg = 0; reg < 4; ++reg) {
            int row = rowBase + w * 16 + quad * 4 + reg;
            out[obase + (size_t)row * NKP] = acc[t][reg] + biasf[row];
        }
    }
}

// ================= launch =================
extern "C" void kernel_launch(void* const* d_in, const int* in_sizes, int n_in,
                              void* d_out, int out_size, void* d_ws, size_t ws_size,
                              hipStream_t stream) {
    const float* scores  = (const float*)d_in[0];
    const float* d1      = (const float*)d_in[1];
    const float* d2      = (const float*)d_in[2];
    const float* cDa     = (const float*)d_in[3];
    const float* d4      = (const float*)d_in[4];
    const float* lin0_w  = (const float*)d_in[5];
    const float* lin0_b  = (const float*)d_in[6];
    const float* lin1_w  = (const float*)d_in[7];
    const float* lin1_b  = (const float*)d_in[8];
    const float* lin2_w  = (const float*)d_in[9];
    const float* lin2_b  = (const float*)d_in[10];
    const float* merge_w = (const float*)d_in[11];
    const float* merge_b = (const float*)d_in[12];
    float* out = (float*)d_out;

    char* ws = (char*)d_ws;
    short* Xbuf = (short*)ws;                                          // 5.77 MB
    float* d4T  = (float*)(ws + 6291456);                              // 4,915,200 B
    unsigned long long* cand  = (unsigned long long*)(ws + 14745600);  // 524,288 B
    int* cnt                  = (int*)(ws + 15269888);                 // 1,024 B
    int* fidx                 = (int*)(ws + 15401984);                 // 16,384 B
    short* Mw                 = (short*)(ws + 15418368);               // 360,448 B (bf16)
    float* biasf              = (float*)(ws + 16139264);               // 1,024 B
    int* perm                 = (int*)(ws + 16140288);                 // 16,384 B

    dim3 tgrid(W / 32, H / 32, B);   // (20,15,4)

    fuse_w<<<dim3(11, 256), 256, 0, stream>>>(merge_w, lin0_w, lin1_w, lin2_w, Mw);
    fuse_bias<<<64, 256, 0, stream>>>(merge_w, merge_b, lin0_b, lin1_b, lin2_b, biasf, cnt);
    transpose_d4<<<dim3(19, 4, 4), 256, 0, stream>>>(d4, d4T);
    nms_fused<<<tgrid, 512, 0, stream>>>(scores, cand, cnt);
    topk<<<B, 1024, 0, stream>>>(cand, cnt, out, fidx, perm);
    sample_all<<<dim3(1024, 4), 256, 0, stream>>>(d1, d2, cDa, d4T, fidx, perm, Xbuf);
    gemm_mfma<<<dim3(NCOL / 64, 256 / 64), 256, 0, stream>>>(Mw, Xbuf, biasf, out + B * NKP * 3);
}